// Round 5
// baseline (1317.581 us; speedup 1.0000x reference)
//
#include <hip/hip_runtime.h>

#define N_NODES   32000
#define N_EDGES   512000
#define IN_CH     128
#define HID       256
#define HEADS     8
#define D_HEAD    32
#define N_LAYERS  4
#define N_GRAPHS  64

typedef unsigned short u16;
typedef __bf16 bf16x8 __attribute__((ext_vector_type(8)));
typedef float f32x4 __attribute__((ext_vector_type(4)));
typedef unsigned short u16x8 __attribute__((ext_vector_type(8)));

__device__ __forceinline__ u16 f2bf(float x) {
    union { float f; unsigned int u; } v; v.f = x;
    unsigned int r = v.u + 0x7FFFu + ((v.u >> 16) & 1u);  // round-to-nearest-even
    return (u16)(r >> 16);
}
__device__ __forceinline__ float bf2f(u16 b) {
    union { unsigned int u; float f; } v; v.u = ((unsigned int)b) << 16;
    return v.f;
}

// async global->LDS, 16B per lane; lds base must be wave-uniform (HW: base + lane*16)
__device__ __forceinline__ void gll16(const u16* g, u16* l) {
    __builtin_amdgcn_global_load_lds(
        (const __attribute__((address_space(1))) unsigned int*)g,
        (__attribute__((address_space(3))) unsigned int*)l, 16, 0, 0);
}

// ---------------------------------------------------------------- CSR build
__global__ __launch_bounds__(256) void count_kernel(const int* __restrict__ ei,
                                                    int* __restrict__ deg) {
    int e = blockIdx.x * 256 + threadIdx.x;
    if (e < N_EDGES) atomicAdd(&deg[ei[N_EDGES + e]], 1);
}

__global__ __launch_bounds__(256) void scan_kernel(const int* __restrict__ deg,
                                                   int* __restrict__ indptr,
                                                   int* __restrict__ cursor) {
    __shared__ int wsum[4];
    __shared__ int carry_s;
    __shared__ int total_s;
    int tid = threadIdx.x;
    int lane = tid & 63, wave = tid >> 6;
    if (tid == 0) carry_s = 0;
    __syncthreads();
    for (int base = 0; base < N_NODES; base += 256) {
        int i = base + tid;
        int v = (i < N_NODES) ? deg[i] : 0;
        int x = v;
        #pragma unroll
        for (int off = 1; off < 64; off <<= 1) {
            int t = __shfl_up(x, off, 64);
            if (lane >= off) x += t;
        }
        if (lane == 63) wsum[wave] = x;
        __syncthreads();
        if (tid == 0) {
            int s = 0;
            #pragma unroll
            for (int w = 0; w < 4; ++w) { int t = wsum[w]; wsum[w] = s; s += t; }
            total_s = s;
        }
        __syncthreads();
        int excl = carry_s + wsum[wave] + x - v;
        if (i < N_NODES) { indptr[i] = excl; cursor[i] = excl; }
        __syncthreads();
        if (tid == 0) carry_s += total_s;
        __syncthreads();
    }
    if (tid == 0) indptr[N_NODES] = carry_s;
}

__global__ __launch_bounds__(256) void scatter_kernel(const int* __restrict__ ei,
                                                      int* __restrict__ cursor,
                                                      int* __restrict__ ssrc) {
    int e = blockIdx.x * 256 + threadIdx.x;
    if (e < N_EDGES) {
        int dst = ei[N_EDGES + e];
        int pos = atomicAdd(&cursor[dst], 1);
        ssrc[pos] = ei[e];
    }
}

// ---------------------------------------------------------------- conversions
__global__ __launch_bounds__(256) void tob16_kernel(const float* __restrict__ src,
                                                    u16* __restrict__ dst, int n) {
    int i = blockIdx.x * 256 + threadIdx.x;
    if (i < n) dst[i] = f2bf(src[i]);
}

__global__ __launch_bounds__(256) void split_kernel(const float* __restrict__ src,
                                                    u16* __restrict__ hi,
                                                    u16* __restrict__ lo, int n) {
    int i = blockIdx.x * 256 + threadIdx.x;
    if (i >= n) return;
    float x = src[i];
    u16 h = f2bf(x);
    hi[i] = h;
    lo[i] = f2bf(x - bf2f(h));
}

// builds wcat[l][1024][256] = concat(wq,wk,wv,wskip) rows, split into hi/lo
__global__ __launch_bounds__(256) void wcat_kernel(const float* __restrict__ wq,
                                                   const float* __restrict__ wk,
                                                   const float* __restrict__ wv,
                                                   const float* __restrict__ ws,
                                                   u16* __restrict__ hi,
                                                   u16* __restrict__ lo) {
    int i = blockIdx.x * 256 + threadIdx.x;  // 4*1024*256 = 1048576 total
    int l = i >> 18;
    int rem = i & 262143;
    int r = rem >> 8, c = rem & 255;
    int seg = r >> 8, rr = r & 255;
    const float* w = seg == 0 ? wq : seg == 1 ? wk : seg == 2 ? wv : ws;
    float x = w[(size_t)l * 65536 + rr * 256 + c];
    u16 h = f2bf(x);
    hi[i] = h;
    lo[i] = f2bf(x - bf2f(h));
}

__global__ __launch_bounds__(256) void bcat_kernel(const float* __restrict__ bq,
                                                   const float* __restrict__ bk,
                                                   const float* __restrict__ bv,
                                                   const float* __restrict__ bs,
                                                   float* __restrict__ bcat) {
    int i = blockIdx.x * 256 + threadIdx.x;  // 4096
    int l = i >> 10, r = i & 1023;
    int seg = r >> 8, rr = r & 255;
    const float* b = seg == 0 ? bq : seg == 1 ? bk : seg == 2 ? bv : bs;
    bcat[i] = b[l * 256 + rr];
}

// ---------------------------------------------------------------- pe MLP stage 1
__global__ __launch_bounds__(256) void pe1_kernel(const float* __restrict__ lpe,
                                                  const float* __restrict__ w1,
                                                  const float* __restrict__ b1,
                                                  u16* __restrict__ t1b) {
    __shared__ float l[16];
    int n = blockIdx.x, j = threadIdx.x;
    if (j < 16) l[j] = lpe[n * 16 + j];
    __syncthreads();
    float s = b1[j];
    #pragma unroll
    for (int kk = 0; kk < 16; ++kk) s += l[kk] * w1[j * 16 + kk];
    t1b[(size_t)n * HID + j] = f2bf(fmaxf(s, 0.0f));
}

// ---------------------------------------------------------------- MFMA GEMM
// C[M x N] = A_bf16[M x K] @ (Whi + Wlo)[N x K]^T + bias, f32 accumulate.
// BM=BN=128, BK=64, 4 waves (2x2), each wave 64x64 (4x4 frags of 16x16x32).
// Staging via global_load_lds width-16: LDS dest lane-linear, XOR swizzle applied
// to the SOURCE row (involution r <-> (r&120)|((r^kc)&7)); read side unchanged.
// MODE 0: C0[row*256+col] = val;  MODE 1: C0 += val;
// MODE 2 (QKVS, N=1024): col<256 -> qf (f32); 256..767 -> khv head-sliced bf16;
//                        >=768 -> skipb (f32)
template <int MODE>
__global__ __launch_bounds__(256) void mgemm(const u16* __restrict__ A,
                                             const u16* __restrict__ Wh,
                                             const u16* __restrict__ Wl,
                                             const float* __restrict__ bias,
                                             int K,
                                             float* __restrict__ C0,
                                             float* __restrict__ qf,
                                             u16* __restrict__ khv,
                                             float* __restrict__ skipb) {
    __shared__ __align__(16) u16 sA[128 * 64];
    __shared__ __align__(16) u16 sWh[128 * 64];
    __shared__ __align__(16) u16 sWl[128 * 64];
    const int tid = threadIdx.x;
    const int l = tid & 63, wid = tid >> 6;
    const int wm = wid >> 1, wn = wid & 1;
    const int lr = l & 15, lc = l >> 4;
    const int r0 = blockIdx.x * 128;
    const int c0 = blockIdx.y * 128;

    f32x4 acc[4][4];
    #pragma unroll
    for (int m = 0; m < 4; ++m)
        #pragma unroll
        for (int n = 0; n < 4; ++n) acc[m][n] = (f32x4){0.f, 0.f, 0.f, 0.f};

    for (int k0 = 0; k0 < K; k0 += 64) {
        // stage 3 tiles of 1024 16B-chunks each; chunk c = kc*128 + s holds
        // global row (s&120)|((s^kc)&7). 4 iters x 4 waves x 64 lanes.
        #pragma unroll
        for (int j = 0; j < 4; ++j) {
            int kc = j * 2 + (wid >> 1);
            int s  = (wid & 1) * 64 + l;
            int r  = (s & 120) | ((s ^ kc) & 7);
            int cb = (j * 256 + wid * 64) * 8;      // u16 index of wave-uniform dest
            const u16* ga = A  + (size_t)(r0 + r) * K + k0 + kc * 8;
            const u16* gh = Wh + (size_t)(c0 + r) * K + k0 + kc * 8;
            const u16* gl = Wl + (size_t)(c0 + r) * K + k0 + kc * 8;
            gll16(ga, sA  + cb);
            gll16(gh, sWh + cb);
            gll16(gl, sWl + cb);
        }
        __syncthreads();
        #pragma unroll
        for (int kk = 0; kk < 2; ++kk) {
            const int kc = kk * 4 + lc;
            bf16x8 a[4], wh[4], wl[4];
            #pragma unroll
            for (int m = 0; m < 4; ++m) {
                int r = wm * 64 + m * 16 + lr;
                a[m] = *reinterpret_cast<const bf16x8*>(
                    &sA[(kc * 128 + (r & 120) + ((r ^ kc) & 7)) * 8]);
            }
            #pragma unroll
            for (int n = 0; n < 4; ++n) {
                int r = wn * 64 + n * 16 + lr;
                int off = (kc * 128 + (r & 120) + ((r ^ kc) & 7)) * 8;
                wh[n] = *reinterpret_cast<const bf16x8*>(&sWh[off]);
                wl[n] = *reinterpret_cast<const bf16x8*>(&sWl[off]);
            }
            #pragma unroll
            for (int m = 0; m < 4; ++m)
                #pragma unroll
                for (int n = 0; n < 4; ++n) {
                    acc[m][n] = __builtin_amdgcn_mfma_f32_16x16x32_bf16(a[m], wh[n], acc[m][n], 0, 0, 0);
                    acc[m][n] = __builtin_amdgcn_mfma_f32_16x16x32_bf16(a[m], wl[n], acc[m][n], 0, 0, 0);
                }
        }
        __syncthreads();
    }

    #pragma unroll
    for (int n = 0; n < 4; ++n) {
        int col = c0 + wn * 64 + n * 16 + lr;
        float bv = bias[col];
        #pragma unroll
        for (int m = 0; m < 4; ++m) {
            int rowb = r0 + wm * 64 + m * 16 + lc * 4;
            #pragma unroll
            for (int i = 0; i < 4; ++i) {
                float val = acc[m][n][i] + bv;
                int row = rowb + i;
                if (MODE == 0) {
                    C0[(size_t)row * 256 + col] = val;
                } else if (MODE == 1) {
                    C0[(size_t)row * 256 + col] += val;
                } else {
                    if (c0 < 256) {
                        qf[(size_t)row * 256 + col] = val;
                    } else if (c0 < 512) {
                        int cc = col - 256, hh = cc >> 5, ch = cc & 31;
                        khv[((size_t)hh * N_NODES + row) * 64 + ch] = f2bf(val);
                    } else if (c0 < 768) {
                        int cc = col - 512, hh = cc >> 5, ch = cc & 31;
                        khv[((size_t)hh * N_NODES + row) * 64 + 32 + ch] = f2bf(val);
                    } else {
                        skipb[(size_t)row * 256 + (col - 768)] = val;
                    }
                }
            }
        }
    }
}

// ---------------------------------------------------------------- LayerNorm -> bf16
__global__ __launch_bounds__(256) void ln_kernel(const float* __restrict__ h,
                                                 const float* __restrict__ gw,
                                                 const float* __restrict__ bw,
                                                 u16* __restrict__ xnb) {
    int lane = threadIdx.x & 63, wave = threadIdx.x >> 6;
    int node = blockIdx.x * 4 + wave;
    float4 v = ((const float4*)(h + (size_t)node * HID))[lane];
    float s = v.x + v.y + v.z + v.w;
    #pragma unroll
    for (int off = 32; off; off >>= 1) s += __shfl_xor(s, off, 64);
    float mu = s * (1.0f / HID);
    float dx = v.x - mu, dy = v.y - mu, dz = v.z - mu, dw = v.w - mu;
    float q = dx * dx + dy * dy + dz * dz + dw * dw;
    #pragma unroll
    for (int off = 32; off; off >>= 1) q += __shfl_xor(q, off, 64);
    float inv = rsqrtf(q * (1.0f / HID) + 1e-5f);
    int c = lane * 4;
    float o0 = dx * inv * gw[c + 0] + bw[c + 0];
    float o1 = dy * inv * gw[c + 1] + bw[c + 1];
    float o2 = dz * inv * gw[c + 2] + bw[c + 2];
    float o3 = dw * inv * gw[c + 3] + bw[c + 3];
    uint2 pk;
    pk.x = (unsigned int)f2bf(o0) | ((unsigned int)f2bf(o1) << 16);
    pk.y = (unsigned int)f2bf(o2) | ((unsigned int)f2bf(o3) << 16);
    *reinterpret_cast<uint2*>(xnb + (size_t)node * HID + c) = pk;
}

// ---------------------------------------------------------------- fused edge attention
// one wave per (node, head); head = blockIdx.x % 8 -> XCD affinity (per-head
// khv slice = 4MB = one XCD's L2). One edge per 4-lane group -> 16 edges/iter,
// every lane does both the QK dot (8 fma) and the PV accumulate (8 fma).
__global__ __launch_bounds__(256) void agg_kernel(const float* __restrict__ q,
                                                  const u16* __restrict__ khv,
                                                  const int* __restrict__ indptr,
                                                  const int* __restrict__ ssrc,
                                                  float* __restrict__ outb) {
    const float scale = 0.17677669529663687f;  // 1/sqrt(32)
    const int lane = threadIdx.x & 63, wave = threadIdx.x >> 6;
    const int h = blockIdx.x & 7;
    const int n = (blockIdx.x >> 3) * 4 + wave;
    const int j = lane & 3;    // channel quad (8 ch) within head
    const int jj = lane >> 2;  // edge slot 0..15

    const float* qp = q + (size_t)n * HID + h * 32 + j * 8;
    f32x4 q0 = *reinterpret_cast<const f32x4*>(qp);
    f32x4 q1 = *reinterpret_cast<const f32x4*>(qp + 4);
    float qv[8];
    #pragma unroll
    for (int i = 0; i < 4; ++i) { qv[i] = q0[i] * scale; qv[4 + i] = q1[i] * scale; }

    const int s0 = indptr[n], s1 = indptr[n + 1];
    const u16* base = khv + (size_t)h * N_NODES * 64 + j * 8;
    float acc[8] = {0.f, 0.f, 0.f, 0.f, 0.f, 0.f, 0.f, 0.f};
    float ssum = 0.f;

    for (int e0 = s0; e0 < s1; e0 += 16) {
        int e = e0 + jj;
        bool valid = e < s1;
        int ee = valid ? e : (s1 - 1);
        int src = __builtin_nontemporal_load(&ssrc[ee]);
        const u16* row = base + (size_t)src * 64;
        u16x8 k8 = *reinterpret_cast<const u16x8*>(row);
        u16x8 v8 = *reinterpret_cast<const u16x8*>(row + 32);
        float prod = 0.f;
        #pragma unroll
        for (int i = 0; i < 8; ++i) prod += qv[i] * bf2f(k8[i]);
        prod += __shfl_xor(prod, 1, 64);
        prod += __shfl_xor(prod, 2, 64);
        float p = valid ? __expf(prod) : 0.f;
        ssum += p;
        #pragma unroll
        for (int i = 0; i < 8; ++i) acc[i] += p * bf2f(v8[i]);
    }

    // reduce over the 16 edge slots (lane bits 2..5)
    #pragma unroll
    for (int d = 4; d <= 32; d <<= 1) {
        ssum += __shfl_xor(ssum, d, 64);
        #pragma unroll
        for (int i = 0; i < 8; ++i) acc[i] += __shfl_xor(acc[i], d, 64);
    }
    if (jj == 0) {
        float inv = 1.0f / fmaxf(ssum, 1e-16f);
        float* op = outb + (size_t)n * HID + h * 32 + j * 8;
        f32x4 o0 = {acc[0] * inv, acc[1] * inv, acc[2] * inv, acc[3] * inv};
        f32x4 o1 = {acc[4] * inv, acc[5] * inv, acc[6] * inv, acc[7] * inv};
        __builtin_nontemporal_store(o0, (f32x4*)op);
        __builtin_nontemporal_store(o1, (f32x4*)(op + 4));
    }
}

// ------------------------------------------- beta gate + relu + residual (+ next LN)
template <bool DO_LN>
__global__ __launch_bounds__(256) void beta_kernel(const float* __restrict__ outb,
                                                   const float* __restrict__ skipb,
                                                   const float* __restrict__ wb,
                                                   const float* __restrict__ gw,
                                                   const float* __restrict__ bw,
                                                   float* __restrict__ h,
                                                   u16* __restrict__ xnb) {
    int lane = threadIdx.x & 63, wave = threadIdx.x >> 6;
    int node = blockIdx.x * 4 + wave;
    int c = lane * 4;
    float4 o  = ((const float4*)(outb  + (size_t)node * HID))[lane];
    float4 sk = ((const float4*)(skipb + (size_t)node * HID))[lane];
    float acc = o.x * wb[c + 0] + o.y * wb[c + 1] + o.z * wb[c + 2] + o.w * wb[c + 3]
              + sk.x * wb[HID + c + 0] + sk.y * wb[HID + c + 1]
              + sk.z * wb[HID + c + 2] + sk.w * wb[HID + c + 3]
              + (o.x - sk.x) * wb[2 * HID + c + 0] + (o.y - sk.y) * wb[2 * HID + c + 1]
              + (o.z - sk.z) * wb[2 * HID + c + 2] + (o.w - sk.w) * wb[2 * HID + c + 3];
    #pragma unroll
    for (int off = 32; off; off >>= 1) acc += __shfl_xor(acc, off, 64);
    float beta = 1.0f / (1.0f + __expf(-acc));
    float4 r = ((const float4*)(h + (size_t)node * HID))[lane];
    float4 out;
    out.x = fmaxf(beta * sk.x + (1.0f - beta) * o.x, 0.0f) + r.x;
    out.y = fmaxf(beta * sk.y + (1.0f - beta) * o.y, 0.0f) + r.y;
    out.z = fmaxf(beta * sk.z + (1.0f - beta) * o.z, 0.0f) + r.z;
    out.w = fmaxf(beta * sk.w + (1.0f - beta) * o.w, 0.0f) + r.w;
    ((float4*)(h + (size_t)node * HID))[lane] = out;

    if (DO_LN) {
        float s = out.x + out.y + out.z + out.w;
        #pragma unroll
        for (int off = 32; off; off >>= 1) s += __shfl_xor(s, off, 64);
        float mu = s * (1.0f / HID);
        float dx = out.x - mu, dy = out.y - mu, dz = out.z - mu, dw = out.w - mu;
        float qq = dx * dx + dy * dy + dz * dz + dw * dw;
        #pragma unroll
        for (int off = 32; off; off >>= 1) qq += __shfl_xor(qq, off, 64);
        float inv = rsqrtf(qq * (1.0f / HID) + 1e-5f);
        float o0 = dx * inv * gw[c + 0] + bw[c + 0];
        float o1 = dy * inv * gw[c + 1] + bw[c + 1];
        float o2 = dz * inv * gw[c + 2] + bw[c + 2];
        float o3 = dw * inv * gw[c + 3] + bw[c + 3];
        uint2 pk;
        pk.x = (unsigned int)f2bf(o0) | ((unsigned int)f2bf(o1) << 16);
        pk.y = (unsigned int)f2bf(o2) | ((unsigned int)f2bf(o3) << 16);
        *reinterpret_cast<uint2*>(xnb + (size_t)node * HID + c) = pk;
    }
}

// ---------------------------------------------------------------- pooling + final MLP
__global__ __launch_bounds__(128) void bounds_kernel(const int* __restrict__ batch,
                                                     int* __restrict__ gstart) {
    int g = threadIdx.x;
    if (g > N_GRAPHS) return;
    int lo = 0, hi = N_NODES;
    while (lo < hi) { int mid = (lo + hi) >> 1; if (batch[mid] < g) lo = mid + 1; else hi = mid; }
    gstart[g] = lo;
}

__global__ __launch_bounds__(256) void pool_kernel(const float* __restrict__ h,
                                                   const int* __restrict__ gstart,
                                                   float* __restrict__ xg) {
    int g = blockIdx.x, t = threadIdx.x;
    int s = gstart[g], e = gstart[g + 1];
    float acc = 0.0f;
    for (int i = s; i < e; ++i) acc += h[(size_t)i * HID + t];
    float cnt = (float)(e - s);
    xg[(size_t)g * HID + t] = acc / fmaxf(cnt, 1.0f);
}

__global__ __launch_bounds__(256) void mlp_kernel(const float* __restrict__ xg,
                                                  const float* __restrict__ w1,
                                                  const float* __restrict__ b1,
                                                  const float* __restrict__ w2,
                                                  const float* __restrict__ b2,
                                                  float* __restrict__ out) {
    __shared__ float xr[256];
    __shared__ float red[256];
    int g = blockIdx.x, t = threadIdx.x;
    xr[t] = xg[(size_t)g * HID + t];
    __syncthreads();
    float s = b1[t];
    #pragma unroll 4
    for (int kk = 0; kk < 256; ++kk) s += xr[kk] * w1[t * 256 + kk];
    s = fmaxf(s, 0.0f);
    red[t] = s * w2[t];
    __syncthreads();
    for (int off = 128; off; off >>= 1) {
        if (t < off) red[t] += red[t + off];
        __syncthreads();
    }
    if (t == 0) out[g] = red[0] + b2[0];
}

// ---------------------------------------------------------------- host
extern "C" void kernel_launch(void* const* d_in, const int* in_sizes, int n_in,
                              void* d_out, int out_size, void* d_ws, size_t ws_size,
                              hipStream_t stream) {
    const float* x      = (const float*)d_in[0];
    const float* lpe    = (const float*)d_in[1];
    const float* pe_w1  = (const float*)d_in[2];
    const float* pe_b1  = (const float*)d_in[3];
    const float* pe_w2  = (const float*)d_in[4];
    const float* pe_b2  = (const float*)d_in[5];
    const float* emb_w  = (const float*)d_in[6];
    const float* emb_b  = (const float*)d_in[7];
    const float* ln_g   = (const float*)d_in[8];
    const float* ln_b   = (const float*)d_in[9];
    const float* wq     = (const float*)d_in[10];
    const float* bq     = (const float*)d_in[11];
    const float* wk     = (const float*)d_in[12];
    const float* bk     = (const float*)d_in[13];
    const float* wv     = (const float*)d_in[14];
    const float* bv     = (const float*)d_in[15];
    const float* wskip  = (const float*)d_in[16];
    const float* bskip  = (const float*)d_in[17];
    const float* wbeta  = (const float*)d_in[18];
    const float* mlp_w1 = (const float*)d_in[19];
    const float* mlp_b1 = (const float*)d_in[20];
    const float* mlp_w2 = (const float*)d_in[21];
    const float* mlp_b2 = (const float*)d_in[22];
    const int*   eidx   = (const int*)d_in[23];
    const int*   batch  = (const int*)d_in[24];

    char* w = (char*)d_ws;
    const size_t NH = (size_t)N_NODES * HID;
    float* h     = (float*)w;           w += NH * 4;
    float* qf    = (float*)w;           w += NH * 4;
    float* skipb = (float*)w;           w += NH * 4;
    float* outb  = (float*)w;           w += NH * 4;
    float* xg    = (float*)w;           w += (size_t)N_GRAPHS * HID * 4;
    u16* xnb     = (u16*)w;             w += NH * 2;
    u16* khv     = (u16*)w;             w += (size_t)HEADS * N_NODES * 64 * 2;
    u16* xb      = (u16*)w;             w += (size_t)N_NODES * IN_CH * 2;
    u16* t1b     = (u16*)w;             w += NH * 2;
    u16* ehi     = (u16*)w;             w += 32768 * 2;
    u16* elo     = (u16*)w;             w += 32768 * 2;
    u16* p2hi    = (u16*)w;             w += 65536 * 2;
    u16* p2lo    = (u16*)w;             w += 65536 * 2;
    u16* wchi    = (u16*)w;             w += 1048576 * 2;
    u16* wclo    = (u16*)w;             w += 1048576 * 2;
    float* bcat  = (float*)w;           w += 4096 * 4;
    int* deg     = (int*)w;             w += N_NODES * 4;
    int* indptr  = (int*)w;             w += (N_NODES + 1) * 4;
    int* cursor  = (int*)w;             w += N_NODES * 4;
    int* ssrc    = (int*)w;             w += N_EDGES * 4;
    int* gstart  = (int*)w;             w += (N_GRAPHS + 1) * 4;

    // weight conversions (every call; deterministic)
    split_kernel<<<128, 256, 0, stream>>>(emb_w, ehi, elo, 32768);
    split_kernel<<<256, 256, 0, stream>>>(pe_w2, p2hi, p2lo, 65536);
    wcat_kernel<<<4096, 256, 0, stream>>>(wq, wk, wv, wskip, wchi, wclo);
    bcat_kernel<<<16, 256, 0, stream>>>(bq, bk, bv, bskip, bcat);
    tob16_kernel<<<16000, 256, 0, stream>>>(x, xb, N_NODES * IN_CH);

    // CSR by destination
    hipMemsetAsync(deg, 0, N_NODES * sizeof(int), stream);
    count_kernel<<<(N_EDGES + 255) / 256, 256, 0, stream>>>(eidx, deg);
    scan_kernel<<<1, 256, 0, stream>>>(deg, indptr, cursor);
    scatter_kernel<<<(N_EDGES + 255) / 256, 256, 0, stream>>>(eidx, cursor, ssrc);

    // h = x@emb_w^T + emb_b + pe_mlp(lpe)
    pe1_kernel<<<N_NODES, 256, 0, stream>>>(lpe, pe_w1, pe_b1, t1b);
    mgemm<0><<<dim3(250, 2), 256, 0, stream>>>(xb, ehi, elo, emb_b, IN_CH, h, nullptr, nullptr, nullptr);
    mgemm<1><<<dim3(250, 2), 256, 0, stream>>>(t1b, p2hi, p2lo, pe_b2, HID, h, nullptr, nullptr, nullptr);

    ln_kernel<<<N_NODES / 4, 256, 0, stream>>>(h, ln_g, ln_b, xnb);
    for (int l = 0; l < N_LAYERS; ++l) {
        mgemm<2><<<dim3(250, 8), 256, 0, stream>>>(xnb, wchi + (size_t)l * 262144,
                                                   wclo + (size_t)l * 262144,
                                                   bcat + l * 1024, HID,
                                                   nullptr, qf, khv, skipb);
        agg_kernel<<<(N_NODES / 4) * 8, 256, 0, stream>>>(qf, khv, indptr, ssrc, outb);
        if (l < N_LAYERS - 1) {
            beta_kernel<true><<<N_NODES / 4, 256, 0, stream>>>(
                outb, skipb, wbeta + l * 3 * HID,
                ln_g + (l + 1) * HID, ln_b + (l + 1) * HID, h, xnb);
        } else {
            beta_kernel<false><<<N_NODES / 4, 256, 0, stream>>>(
                outb, skipb, wbeta + l * 3 * HID, nullptr, nullptr, h, nullptr);
        }
    }

    bounds_kernel<<<1, 128, 0, stream>>>(batch, gstart);
    pool_kernel<<<N_GRAPHS, 256, 0, stream>>>(h, gstart, xg);
    mlp_kernel<<<N_GRAPHS, 256, 0, stream>>>(xg, mlp_w1, mlp_b1, mlp_w2, mlp_b2, (float*)d_out);
}

// Round 6
// 1131.544 us; speedup vs baseline: 1.1644x; 1.1644x over previous
//
#include <hip/hip_runtime.h>

#define N_NODES   32000
#define N_EDGES   512000
#define IN_CH     128
#define HID       256
#define HEADS     8
#define D_HEAD    32
#define N_LAYERS  4
#define N_GRAPHS  64

typedef unsigned short u16;
typedef __bf16 bf16x8 __attribute__((ext_vector_type(8)));
typedef float f32x4 __attribute__((ext_vector_type(4)));
typedef unsigned short u16x8 __attribute__((ext_vector_type(8)));

__device__ __forceinline__ u16 f2bf(float x) {
    union { float f; unsigned int u; } v; v.f = x;
    unsigned int r = v.u + 0x7FFFu + ((v.u >> 16) & 1u);  // round-to-nearest-even
    return (u16)(r >> 16);
}
__device__ __forceinline__ float bf2f(u16 b) {
    union { unsigned int u; float f; } v; v.u = ((unsigned int)b) << 16;
    return v.f;
}

// async global->LDS, 16B per lane; lds dest = wave-uniform base + lane*16
__device__ __forceinline__ void gll16(const u16* g, u16* l) {
    __builtin_amdgcn_global_load_lds(
        (const __attribute__((address_space(1))) unsigned int*)g,
        (__attribute__((address_space(3))) unsigned int*)l, 16, 0, 0);
}

// ---------------------------------------------------------------- CSR build
__global__ __launch_bounds__(256) void count_kernel(const int* __restrict__ ei,
                                                    int* __restrict__ deg) {
    int e = blockIdx.x * 256 + threadIdx.x;
    if (e < N_EDGES) atomicAdd(&deg[ei[N_EDGES + e]], 1);
}

__global__ __launch_bounds__(256) void scan_kernel(const int* __restrict__ deg,
                                                   int* __restrict__ indptr,
                                                   int* __restrict__ cursor) {
    __shared__ int wsum[4];
    __shared__ int carry_s;
    __shared__ int total_s;
    int tid = threadIdx.x;
    int lane = tid & 63, wave = tid >> 6;
    if (tid == 0) carry_s = 0;
    __syncthreads();
    for (int base = 0; base < N_NODES; base += 256) {
        int i = base + tid;
        int v = (i < N_NODES) ? deg[i] : 0;
        int x = v;
        #pragma unroll
        for (int off = 1; off < 64; off <<= 1) {
            int t = __shfl_up(x, off, 64);
            if (lane >= off) x += t;
        }
        if (lane == 63) wsum[wave] = x;
        __syncthreads();
        if (tid == 0) {
            int s = 0;
            #pragma unroll
            for (int w = 0; w < 4; ++w) { int t = wsum[w]; wsum[w] = s; s += t; }
            total_s = s;
        }
        __syncthreads();
        int excl = carry_s + wsum[wave] + x - v;
        if (i < N_NODES) { indptr[i] = excl; cursor[i] = excl; }
        __syncthreads();
        if (tid == 0) carry_s += total_s;
        __syncthreads();
    }
    if (tid == 0) indptr[N_NODES] = carry_s;
}

__global__ __launch_bounds__(256) void scatter_kernel(const int* __restrict__ ei,
                                                      int* __restrict__ cursor,
                                                      int* __restrict__ ssrc) {
    int e = blockIdx.x * 256 + threadIdx.x;
    if (e < N_EDGES) {
        int dst = ei[N_EDGES + e];
        int pos = atomicAdd(&cursor[dst], 1);
        ssrc[pos] = ei[e];
    }
}

// ---------------------------------------------------------------- conversions
__global__ __launch_bounds__(256) void tob16_kernel(const float* __restrict__ src,
                                                    u16* __restrict__ dst, int n) {
    int i = blockIdx.x * 256 + threadIdx.x;
    if (i < n) dst[i] = f2bf(src[i]);
}

__global__ __launch_bounds__(256) void split_kernel(const float* __restrict__ src,
                                                    u16* __restrict__ hi,
                                                    u16* __restrict__ lo, int n) {
    int i = blockIdx.x * 256 + threadIdx.x;
    if (i >= n) return;
    float x = src[i];
    u16 h = f2bf(x);
    hi[i] = h;
    lo[i] = f2bf(x - bf2f(h));
}

// builds wcat[l][1024][256] = concat(wq,wk,wv,wskip) rows, split into hi/lo
__global__ __launch_bounds__(256) void wcat_kernel(const float* __restrict__ wq,
                                                   const float* __restrict__ wk,
                                                   const float* __restrict__ wv,
                                                   const float* __restrict__ ws,
                                                   u16* __restrict__ hi,
                                                   u16* __restrict__ lo) {
    int i = blockIdx.x * 256 + threadIdx.x;  // 4*1024*256 = 1048576 total
    int l = i >> 18;
    int rem = i & 262143;
    int r = rem >> 8, c = rem & 255;
    int seg = r >> 8, rr = r & 255;
    const float* w = seg == 0 ? wq : seg == 1 ? wk : seg == 2 ? wv : ws;
    float x = w[(size_t)l * 65536 + rr * 256 + c];
    u16 h = f2bf(x);
    hi[i] = h;
    lo[i] = f2bf(x - bf2f(h));
}

__global__ __launch_bounds__(256) void bcat_kernel(const float* __restrict__ bq,
                                                   const float* __restrict__ bk,
                                                   const float* __restrict__ bv,
                                                   const float* __restrict__ bs,
                                                   float* __restrict__ bcat) {
    int i = blockIdx.x * 256 + threadIdx.x;  // 4096
    int l = i >> 10, r = i & 1023;
    int seg = r >> 8, rr = r & 255;
    const float* b = seg == 0 ? bq : seg == 1 ? bk : seg == 2 ? bv : bs;
    bcat[i] = b[l * 256 + rr];
}

// ---------------------------------------------------------------- pe MLP stage 1
__global__ __launch_bounds__(256) void pe1_kernel(const float* __restrict__ lpe,
                                                  const float* __restrict__ w1,
                                                  const float* __restrict__ b1,
                                                  u16* __restrict__ t1b) {
    __shared__ float l[16];
    int n = blockIdx.x, j = threadIdx.x;
    if (j < 16) l[j] = lpe[n * 16 + j];
    __syncthreads();
    float s = b1[j];
    #pragma unroll
    for (int kk = 0; kk < 16; ++kk) s += l[kk] * w1[j * 16 + kk];
    t1b[(size_t)n * HID + j] = f2bf(fmaxf(s, 0.0f));
}

// ---------------------------------------------------------------- MFMA GEMM
// C[M x N] = A_bf16[M x K] @ (Whi + Wlo)[N x K]^T + bias, f32 accumulate.
// BM=BN=128, BK=64, 4 waves (2x2), each wave 64x64 (4x4 frags of 16x16x32).
// LDS layout row-major with column XOR swizzle: chunk(r,kc) at index r*8+(kc^(r&7)).
// Staging via global_load_lds w16: dest lane-linear; source col permuted per lane
// ((l&7)^(l>>3)) -> each 8-lane group reads one 128B row segment (coalesced).
// MODE 0: C0[row*256+col] = val;  MODE 1: C0 += val;
// MODE 2 (QKVS, N=1024): col<256 -> qf (f32); 256..767 -> khv head-sliced bf16;
//                        >=768 -> skipb (f32)
template <int MODE>
__global__ __launch_bounds__(256) void mgemm(const u16* __restrict__ A,
                                             const u16* __restrict__ Wh,
                                             const u16* __restrict__ Wl,
                                             const float* __restrict__ bias,
                                             int K,
                                             float* __restrict__ C0,
                                             float* __restrict__ qf,
                                             u16* __restrict__ khv,
                                             float* __restrict__ skipb) {
    __shared__ __align__(16) u16 sA[128 * 64];
    __shared__ __align__(16) u16 sWh[128 * 64];
    __shared__ __align__(16) u16 sWl[128 * 64];
    const int tid = threadIdx.x;
    const int l = tid & 63, wid = tid >> 6;
    const int wm = wid >> 1, wn = wid & 1;
    const int lr = l & 15, lc = l >> 4;
    const int r0 = blockIdx.x * 128;
    const int c0 = blockIdx.y * 128;

    f32x4 acc[4][4];
    #pragma unroll
    for (int m = 0; m < 4; ++m)
        #pragma unroll
        for (int n = 0; n < 4; ++n) acc[m][n] = (f32x4){0.f, 0.f, 0.f, 0.f};

    const int sr = l >> 3;                 // row within 8-row group
    const int skc = (l & 7) ^ sr;          // swizzled source column chunk
    for (int k0 = 0; k0 < K; k0 += 64) {
        #pragma unroll
        for (int j = 0; j < 4; ++j) {
            int r = j * 32 + wid * 8 + sr;
            int cb = (j * 256 + wid * 64) * 8;   // u16 idx of wave-uniform dest
            const u16* ga = A  + (size_t)(r0 + r) * K + k0 + skc * 8;
            const u16* gh = Wh + (size_t)(c0 + r) * K + k0 + skc * 8;
            const u16* gl = Wl + (size_t)(c0 + r) * K + k0 + skc * 8;
            gll16(ga, sA  + cb);
            gll16(gh, sWh + cb);
            gll16(gl, sWl + cb);
        }
        __syncthreads();
        #pragma unroll
        for (int kk = 0; kk < 2; ++kk) {
            const int kc = kk * 4 + lc;
            bf16x8 a[4], wh[4], wl[4];
            #pragma unroll
            for (int m = 0; m < 4; ++m) {
                int r = wm * 64 + m * 16 + lr;
                a[m] = *reinterpret_cast<const bf16x8*>(
                    &sA[r * 64 + ((kc ^ (r & 7)) * 8)]);
            }
            #pragma unroll
            for (int n = 0; n < 4; ++n) {
                int r = wn * 64 + n * 16 + lr;
                int off = r * 64 + ((kc ^ (r & 7)) * 8);
                wh[n] = *reinterpret_cast<const bf16x8*>(&sWh[off]);
                wl[n] = *reinterpret_cast<const bf16x8*>(&sWl[off]);
            }
            #pragma unroll
            for (int m = 0; m < 4; ++m)
                #pragma unroll
                for (int n = 0; n < 4; ++n) {
                    acc[m][n] = __builtin_amdgcn_mfma_f32_16x16x32_bf16(a[m], wh[n], acc[m][n], 0, 0, 0);
                    acc[m][n] = __builtin_amdgcn_mfma_f32_16x16x32_bf16(a[m], wl[n], acc[m][n], 0, 0, 0);
                }
        }
        __syncthreads();
    }

    #pragma unroll
    for (int n = 0; n < 4; ++n) {
        int col = c0 + wn * 64 + n * 16 + lr;
        float bv = bias[col];
        #pragma unroll
        for (int m = 0; m < 4; ++m) {
            int rowb = r0 + wm * 64 + m * 16 + lc * 4;
            #pragma unroll
            for (int i = 0; i < 4; ++i) {
                float val = acc[m][n][i] + bv;
                int row = rowb + i;
                if (MODE == 0) {
                    C0[(size_t)row * 256 + col] = val;
                } else if (MODE == 1) {
                    C0[(size_t)row * 256 + col] += val;
                } else {
                    if (c0 < 256) {
                        qf[(size_t)row * 256 + col] = val;
                    } else if (c0 < 512) {
                        int cc = col - 256, hh = cc >> 5, ch = cc & 31;
                        khv[((size_t)hh * N_NODES + row) * 64 + ch] = f2bf(val);
                    } else if (c0 < 768) {
                        int cc = col - 512, hh = cc >> 5, ch = cc & 31;
                        khv[((size_t)hh * N_NODES + row) * 64 + 32 + ch] = f2bf(val);
                    } else {
                        skipb[(size_t)row * 256 + (col - 768)] = val;
                    }
                }
            }
        }
    }
}

// ---------------------------------------------------------------- LayerNorm -> bf16
__global__ __launch_bounds__(256) void ln_kernel(const float* __restrict__ h,
                                                 const float* __restrict__ gw,
                                                 const float* __restrict__ bw,
                                                 u16* __restrict__ xnb) {
    int lane = threadIdx.x & 63, wave = threadIdx.x >> 6;
    int node = blockIdx.x * 4 + wave;
    float4 v = ((const float4*)(h + (size_t)node * HID))[lane];
    float s = v.x + v.y + v.z + v.w;
    #pragma unroll
    for (int off = 32; off; off >>= 1) s += __shfl_xor(s, off, 64);
    float mu = s * (1.0f / HID);
    float dx = v.x - mu, dy = v.y - mu, dz = v.z - mu, dw = v.w - mu;
    float q = dx * dx + dy * dy + dz * dz + dw * dw;
    #pragma unroll
    for (int off = 32; off; off >>= 1) q += __shfl_xor(q, off, 64);
    float inv = rsqrtf(q * (1.0f / HID) + 1e-5f);
    int c = lane * 4;
    float o0 = dx * inv * gw[c + 0] + bw[c + 0];
    float o1 = dy * inv * gw[c + 1] + bw[c + 1];
    float o2 = dz * inv * gw[c + 2] + bw[c + 2];
    float o3 = dw * inv * gw[c + 3] + bw[c + 3];
    uint2 pk;
    pk.x = (unsigned int)f2bf(o0) | ((unsigned int)f2bf(o1) << 16);
    pk.y = (unsigned int)f2bf(o2) | ((unsigned int)f2bf(o3) << 16);
    *reinterpret_cast<uint2*>(xnb + (size_t)node * HID + c) = pk;
}

// ---------------------------------------------------------------- fused edge attention
// one 4-lane group per (node, head): lane owns 8 channels for the entire edge
// walk -> NO cross-slot epilogue reduction. head = blockIdx % 8 keeps per-head
// khv slice (4MB) XCD-L2-resident. Depth-1 software pipeline on k/v rows.
__global__ __launch_bounds__(256) void agg_kernel(const float* __restrict__ q,
                                                  const u16* __restrict__ khv,
                                                  const int* __restrict__ indptr,
                                                  const int* __restrict__ ssrc,
                                                  float* __restrict__ outb) {
    const float scale = 0.17677669529663687f;  // 1/sqrt(32)
    const int tid = threadIdx.x;
    const int g = tid >> 2;     // group 0..63 = node within block
    const int j = tid & 3;      // channel quad (8 ch) within head
    const int h = blockIdx.x & 7;
    const int n = (blockIdx.x >> 3) * 64 + g;

    const float* qp = q + (size_t)n * HID + h * 32 + j * 8;
    f32x4 q0 = *reinterpret_cast<const f32x4*>(qp);
    f32x4 q1 = *reinterpret_cast<const f32x4*>(qp + 4);
    float qv[8];
    #pragma unroll
    for (int i = 0; i < 4; ++i) { qv[i] = q0[i] * scale; qv[4 + i] = q1[i] * scale; }

    const int s0 = indptr[n], s1 = indptr[n + 1];
    const u16* base = khv + (size_t)h * N_NODES * 64 + j * 8;
    float acc[8] = {0.f, 0.f, 0.f, 0.f, 0.f, 0.f, 0.f, 0.f};
    float ssum = 0.f;

    if (s0 < s1) {
        int src = __builtin_nontemporal_load(&ssrc[s0]);
        const u16* rp = base + (size_t)src * 64;
        u16x8 k8 = *reinterpret_cast<const u16x8*>(rp);
        u16x8 v8 = *reinterpret_cast<const u16x8*>(rp + 32);
        for (int e = s0; e < s1; ++e) {
            int en = (e + 1 < s1) ? e + 1 : s1 - 1;
            int srcn = __builtin_nontemporal_load(&ssrc[en]);
            const u16* rpn = base + (size_t)srcn * 64;
            u16x8 kn = *reinterpret_cast<const u16x8*>(rpn);
            u16x8 vn = *reinterpret_cast<const u16x8*>(rpn + 32);
            float prod = 0.f;
            #pragma unroll
            for (int i = 0; i < 8; ++i) prod += qv[i] * bf2f(k8[i]);
            prod += __shfl_xor(prod, 1, 64);
            prod += __shfl_xor(prod, 2, 64);
            float p = __expf(prod);
            ssum += p;
            #pragma unroll
            for (int i = 0; i < 8; ++i) acc[i] += p * bf2f(v8[i]);
            k8 = kn; v8 = vn;
        }
    }

    float inv = 1.0f / fmaxf(ssum, 1e-16f);
    float* op = outb + (size_t)n * HID + h * 32 + j * 8;
    f32x4 o0 = {acc[0] * inv, acc[1] * inv, acc[2] * inv, acc[3] * inv};
    f32x4 o1 = {acc[4] * inv, acc[5] * inv, acc[6] * inv, acc[7] * inv};
    __builtin_nontemporal_store(o0, (f32x4*)op);
    __builtin_nontemporal_store(o1, (f32x4*)(op + 4));
}

// ------------------------------------------- beta gate + relu + residual (+ next LN)
template <bool DO_LN>
__global__ __launch_bounds__(256) void beta_kernel(const float* __restrict__ outb,
                                                   const float* __restrict__ skipb,
                                                   const float* __restrict__ wb,
                                                   const float* __restrict__ gw,
                                                   const float* __restrict__ bw,
                                                   float* __restrict__ h,
                                                   u16* __restrict__ xnb) {
    int lane = threadIdx.x & 63, wave = threadIdx.x >> 6;
    int node = blockIdx.x * 4 + wave;
    int c = lane * 4;
    float4 o  = ((const float4*)(outb  + (size_t)node * HID))[lane];
    float4 sk = ((const float4*)(skipb + (size_t)node * HID))[lane];
    float acc = o.x * wb[c + 0] + o.y * wb[c + 1] + o.z * wb[c + 2] + o.w * wb[c + 3]
              + sk.x * wb[HID + c + 0] + sk.y * wb[HID + c + 1]
              + sk.z * wb[HID + c + 2] + sk.w * wb[HID + c + 3]
              + (o.x - sk.x) * wb[2 * HID + c + 0] + (o.y - sk.y) * wb[2 * HID + c + 1]
              + (o.z - sk.z) * wb[2 * HID + c + 2] + (o.w - sk.w) * wb[2 * HID + c + 3];
    #pragma unroll
    for (int off = 32; off; off >>= 1) acc += __shfl_xor(acc, off, 64);
    float beta = 1.0f / (1.0f + __expf(-acc));
    float4 r = ((const float4*)(h + (size_t)node * HID))[lane];
    float4 out;
    out.x = fmaxf(beta * sk.x + (1.0f - beta) * o.x, 0.0f) + r.x;
    out.y = fmaxf(beta * sk.y + (1.0f - beta) * o.y, 0.0f) + r.y;
    out.z = fmaxf(beta * sk.z + (1.0f - beta) * o.z, 0.0f) + r.z;
    out.w = fmaxf(beta * sk.w + (1.0f - beta) * o.w, 0.0f) + r.w;
    ((float4*)(h + (size_t)node * HID))[lane] = out;

    if (DO_LN) {
        float s = out.x + out.y + out.z + out.w;
        #pragma unroll
        for (int off = 32; off; off >>= 1) s += __shfl_xor(s, off, 64);
        float mu = s * (1.0f / HID);
        float dx = out.x - mu, dy = out.y - mu, dz = out.z - mu, dw = out.w - mu;
        float qq = dx * dx + dy * dy + dz * dz + dw * dw;
        #pragma unroll
        for (int off = 32; off; off >>= 1) qq += __shfl_xor(qq, off, 64);
        float inv = rsqrtf(qq * (1.0f / HID) + 1e-5f);
        float o0 = dx * inv * gw[c + 0] + bw[c + 0];
        float o1 = dy * inv * gw[c + 1] + bw[c + 1];
        float o2 = dz * inv * gw[c + 2] + bw[c + 2];
        float o3 = dw * inv * gw[c + 3] + bw[c + 3];
        uint2 pk;
        pk.x = (unsigned int)f2bf(o0) | ((unsigned int)f2bf(o1) << 16);
        pk.y = (unsigned int)f2bf(o2) | ((unsigned int)f2bf(o3) << 16);
        *reinterpret_cast<uint2*>(xnb + (size_t)node * HID + c) = pk;
    }
}

// ---------------------------------------------------------------- pooling + final MLP
__global__ __launch_bounds__(128) void bounds_kernel(const int* __restrict__ batch,
                                                     int* __restrict__ gstart) {
    int g = threadIdx.x;
    if (g > N_GRAPHS) return;
    int lo = 0, hi = N_NODES;
    while (lo < hi) { int mid = (lo + hi) >> 1; if (batch[mid] < g) lo = mid + 1; else hi = mid; }
    gstart[g] = lo;
}

__global__ __launch_bounds__(256) void pool_kernel(const float* __restrict__ h,
                                                   const int* __restrict__ gstart,
                                                   float* __restrict__ xg) {
    int g = blockIdx.x, t = threadIdx.x;
    int s = gstart[g], e = gstart[g + 1];
    float acc = 0.0f;
    for (int i = s; i < e; ++i) acc += h[(size_t)i * HID + t];
    float cnt = (float)(e - s);
    xg[(size_t)g * HID + t] = acc / fmaxf(cnt, 1.0f);
}

__global__ __launch_bounds__(256) void mlp_kernel(const float* __restrict__ xg,
                                                  const float* __restrict__ w1,
                                                  const float* __restrict__ b1,
                                                  const float* __restrict__ w2,
                                                  const float* __restrict__ b2,
                                                  float* __restrict__ out) {
    __shared__ float xr[256];
    __shared__ float red[256];
    int g = blockIdx.x, t = threadIdx.x;
    xr[t] = xg[(size_t)g * HID + t];
    __syncthreads();
    float s = b1[t];
    #pragma unroll 4
    for (int kk = 0; kk < 256; ++kk) s += xr[kk] * w1[t * 256 + kk];
    s = fmaxf(s, 0.0f);
    red[t] = s * w2[t];
    __syncthreads();
    for (int off = 128; off; off >>= 1) {
        if (t < off) red[t] += red[t + off];
        __syncthreads();
    }
    if (t == 0) out[g] = red[0] + b2[0];
}

// ---------------------------------------------------------------- host
extern "C" void kernel_launch(void* const* d_in, const int* in_sizes, int n_in,
                              void* d_out, int out_size, void* d_ws, size_t ws_size,
                              hipStream_t stream) {
    const float* x      = (const float*)d_in[0];
    const float* lpe    = (const float*)d_in[1];
    const float* pe_w1  = (const float*)d_in[2];
    const float* pe_b1  = (const float*)d_in[3];
    const float* pe_w2  = (const float*)d_in[4];
    const float* pe_b2  = (const float*)d_in[5];
    const float* emb_w  = (const float*)d_in[6];
    const float* emb_b  = (const float*)d_in[7];
    const float* ln_g   = (const float*)d_in[8];
    const float* ln_b   = (const float*)d_in[9];
    const float* wq     = (const float*)d_in[10];
    const float* bq     = (const float*)d_in[11];
    const float* wk     = (const float*)d_in[12];
    const float* bk     = (const float*)d_in[13];
    const float* wv     = (const float*)d_in[14];
    const float* bv     = (const float*)d_in[15];
    const float* wskip  = (const float*)d_in[16];
    const float* bskip  = (const float*)d_in[17];
    const float* wbeta  = (const float*)d_in[18];
    const float* mlp_w1 = (const float*)d_in[19];
    const float* mlp_b1 = (const float*)d_in[20];
    const float* mlp_w2 = (const float*)d_in[21];
    const float* mlp_b2 = (const float*)d_in[22];
    const int*   eidx   = (const int*)d_in[23];
    const int*   batch  = (const int*)d_in[24];

    char* w = (char*)d_ws;
    const size_t NH = (size_t)N_NODES * HID;
    float* h     = (float*)w;           w += NH * 4;
    float* qf    = (float*)w;           w += NH * 4;
    float* skipb = (float*)w;           w += NH * 4;
    float* outb  = (float*)w;           w += NH * 4;
    float* xg    = (float*)w;           w += (size_t)N_GRAPHS * HID * 4;
    u16* xnb     = (u16*)w;             w += NH * 2;
    u16* khv     = (u16*)w;             w += (size_t)HEADS * N_NODES * 64 * 2;
    u16* xb      = (u16*)w;             w += (size_t)N_NODES * IN_CH * 2;
    u16* t1b     = (u16*)w;             w += NH * 2;
    u16* ehi     = (u16*)w;             w += 32768 * 2;
    u16* elo     = (u16*)w;             w += 32768 * 2;
    u16* p2hi    = (u16*)w;             w += 65536 * 2;
    u16* p2lo    = (u16*)w;             w += 65536 * 2;
    u16* wchi    = (u16*)w;             w += 1048576 * 2;
    u16* wclo    = (u16*)w;             w += 1048576 * 2;
    float* bcat  = (float*)w;           w += 4096 * 4;
    int* deg     = (int*)w;             w += N_NODES * 4;
    int* indptr  = (int*)w;             w += (N_NODES + 1) * 4;
    int* cursor  = (int*)w;             w += N_NODES * 4;
    int* ssrc    = (int*)w;             w += N_EDGES * 4;
    int* gstart  = (int*)w;             w += (N_GRAPHS + 1) * 4;

    // weight conversions (every call; deterministic)
    split_kernel<<<128, 256, 0, stream>>>(emb_w, ehi, elo, 32768);
    split_kernel<<<256, 256, 0, stream>>>(pe_w2, p2hi, p2lo, 65536);
    wcat_kernel<<<4096, 256, 0, stream>>>(wq, wk, wv, wskip, wchi, wclo);
    bcat_kernel<<<16, 256, 0, stream>>>(bq, bk, bv, bskip, bcat);
    tob16_kernel<<<16000, 256, 0, stream>>>(x, xb, N_NODES * IN_CH);

    // CSR by destination
    hipMemsetAsync(deg, 0, N_NODES * sizeof(int), stream);
    count_kernel<<<(N_EDGES + 255) / 256, 256, 0, stream>>>(eidx, deg);
    scan_kernel<<<1, 256, 0, stream>>>(deg, indptr, cursor);
    scatter_kernel<<<(N_EDGES + 255) / 256, 256, 0, stream>>>(eidx, cursor, ssrc);

    // h = x@emb_w^T + emb_b + pe_mlp(lpe)
    pe1_kernel<<<N_NODES, 256, 0, stream>>>(lpe, pe_w1, pe_b1, t1b);
    mgemm<0><<<dim3(250, 2), 256, 0, stream>>>(xb, ehi, elo, emb_b, IN_CH, h, nullptr, nullptr, nullptr);
    mgemm<1><<<dim3(250, 2), 256, 0, stream>>>(t1b, p2hi, p2lo, pe_b2, HID, h, nullptr, nullptr, nullptr);

    ln_kernel<<<N_NODES / 4, 256, 0, stream>>>(h, ln_g, ln_b, xnb);
    for (int l = 0; l < N_LAYERS; ++l) {
        mgemm<2><<<dim3(250, 8), 256, 0, stream>>>(xnb, wchi + (size_t)l * 262144,
                                                   wclo + (size_t)l * 262144,
                                                   bcat + l * 1024, HID,
                                                   nullptr, qf, khv, skipb);
        agg_kernel<<<(N_NODES / 64) * 8, 256, 0, stream>>>(qf, khv, indptr, ssrc, outb);
        if (l < N_LAYERS - 1) {
            beta_kernel<true><<<N_NODES / 4, 256, 0, stream>>>(
                outb, skipb, wbeta + l * 3 * HID,
                ln_g + (l + 1) * HID, ln_b + (l + 1) * HID, h, xnb);
        } else {
            beta_kernel<false><<<N_NODES / 4, 256, 0, stream>>>(
                outb, skipb, wbeta + l * 3 * HID, nullptr, nullptr, h, nullptr);
        }
    }

    bounds_kernel<<<1, 128, 0, stream>>>(batch, gstart);
    pool_kernel<<<N_GRAPHS, 256, 0, stream>>>(h, gstart, xg);
    mlp_kernel<<<N_GRAPHS, 256, 0, stream>>>(xg, mlp_w1, mlp_b1, mlp_w2, mlp_b2, (float*)d_out);
}

// Round 7
// 1022.544 us; speedup vs baseline: 1.2885x; 1.1066x over previous
//
#include <hip/hip_runtime.h>

#define N_NODES   32000
#define N_EDGES   512000
#define IN_CH     128
#define HID       256
#define HEADS     8
#define D_HEAD    32
#define N_LAYERS  4
#define N_GRAPHS  64
#define P_CHUNK   16

typedef unsigned short u16;
typedef __bf16 bf16x8 __attribute__((ext_vector_type(8)));
typedef float f32x4 __attribute__((ext_vector_type(4)));
typedef unsigned short u16x8 __attribute__((ext_vector_type(8)));

__device__ __forceinline__ u16 f2bf(float x) {
    union { float f; unsigned int u; } v; v.f = x;
    unsigned int r = v.u + 0x7FFFu + ((v.u >> 16) & 1u);  // round-to-nearest-even
    return (u16)(r >> 16);
}
__device__ __forceinline__ float bf2f(u16 b) {
    union { unsigned int u; float f; } v; v.u = ((unsigned int)b) << 16;
    return v.f;
}

// async global->LDS, 16B per lane; lds dest = wave-uniform base + lane*16
__device__ __forceinline__ void gll16(const u16* g, u16* l) {
    __builtin_amdgcn_global_load_lds(
        (const __attribute__((address_space(1))) unsigned int*)g,
        (__attribute__((address_space(3))) unsigned int*)l, 16, 0, 0);
}

// ---------------------------------------------------------------- CSR build
__global__ __launch_bounds__(256) void count_kernel(const int* __restrict__ ei,
                                                    int* __restrict__ deg) {
    int e = blockIdx.x * 256 + threadIdx.x;
    if (e < N_EDGES) atomicAdd(&deg[ei[N_EDGES + e]], 1);
}

__global__ __launch_bounds__(256) void scan_kernel(const int* __restrict__ deg,
                                                   int* __restrict__ indptr,
                                                   int* __restrict__ cursor) {
    __shared__ int wsum[4];
    __shared__ int carry_s;
    __shared__ int total_s;
    int tid = threadIdx.x;
    int lane = tid & 63, wave = tid >> 6;
    if (tid == 0) carry_s = 0;
    __syncthreads();
    for (int base = 0; base < N_NODES; base += 256) {
        int i = base + tid;
        int v = (i < N_NODES) ? deg[i] : 0;
        int x = v;
        #pragma unroll
        for (int off = 1; off < 64; off <<= 1) {
            int t = __shfl_up(x, off, 64);
            if (lane >= off) x += t;
        }
        if (lane == 63) wsum[wave] = x;
        __syncthreads();
        if (tid == 0) {
            int s = 0;
            #pragma unroll
            for (int w = 0; w < 4; ++w) { int t = wsum[w]; wsum[w] = s; s += t; }
            total_s = s;
        }
        __syncthreads();
        int excl = carry_s + wsum[wave] + x - v;
        if (i < N_NODES) { indptr[i] = excl; cursor[i] = excl; }
        __syncthreads();
        if (tid == 0) carry_s += total_s;
        __syncthreads();
    }
    if (tid == 0) indptr[N_NODES] = carry_s;
}

__global__ __launch_bounds__(256) void scatter_kernel(const int* __restrict__ ei,
                                                      int* __restrict__ cursor,
                                                      int* __restrict__ ssrc) {
    int e = blockIdx.x * 256 + threadIdx.x;
    if (e < N_EDGES) {
        int dst = ei[N_EDGES + e];
        int pos = atomicAdd(&cursor[dst], 1);
        ssrc[pos] = ei[e];
    }
}

// ---------------------------------------------------------------- conversions
__global__ __launch_bounds__(256) void tob16_kernel(const float* __restrict__ src,
                                                    u16* __restrict__ dst, int n) {
    int i = blockIdx.x * 256 + threadIdx.x;
    if (i < n) dst[i] = f2bf(src[i]);
}

__global__ __launch_bounds__(256) void split_kernel(const float* __restrict__ src,
                                                    u16* __restrict__ hi,
                                                    u16* __restrict__ lo, int n) {
    int i = blockIdx.x * 256 + threadIdx.x;
    if (i >= n) return;
    float x = src[i];
    u16 h = f2bf(x);
    hi[i] = h;
    lo[i] = f2bf(x - bf2f(h));
}

// builds wcat[l][1024][256] = concat(wq,wk,wv,wskip) rows, split into hi/lo
__global__ __launch_bounds__(256) void wcat_kernel(const float* __restrict__ wq,
                                                   const float* __restrict__ wk,
                                                   const float* __restrict__ wv,
                                                   const float* __restrict__ ws,
                                                   u16* __restrict__ hi,
                                                   u16* __restrict__ lo) {
    int i = blockIdx.x * 256 + threadIdx.x;  // 4*1024*256 = 1048576 total
    int l = i >> 18;
    int rem = i & 262143;
    int r = rem >> 8, c = rem & 255;
    int seg = r >> 8, rr = r & 255;
    const float* w = seg == 0 ? wq : seg == 1 ? wk : seg == 2 ? wv : ws;
    float x = w[(size_t)l * 65536 + rr * 256 + c];
    u16 h = f2bf(x);
    hi[i] = h;
    lo[i] = f2bf(x - bf2f(h));
}

__global__ __launch_bounds__(256) void bcat_kernel(const float* __restrict__ bq,
                                                   const float* __restrict__ bk,
                                                   const float* __restrict__ bv,
                                                   const float* __restrict__ bs,
                                                   float* __restrict__ bcat) {
    int i = blockIdx.x * 256 + threadIdx.x;  // 4096
    int l = i >> 10, r = i & 1023;
    int seg = r >> 8, rr = r & 255;
    const float* b = seg == 0 ? bq : seg == 1 ? bk : seg == 2 ? bv : bs;
    bcat[i] = b[l * 256 + rr];
}

// ---------------------------------------------------------------- pe MLP stage 1
__global__ __launch_bounds__(256) void pe1_kernel(const float* __restrict__ lpe,
                                                  const float* __restrict__ w1,
                                                  const float* __restrict__ b1,
                                                  u16* __restrict__ t1b) {
    __shared__ float l[16];
    int n = blockIdx.x, j = threadIdx.x;
    if (j < 16) l[j] = lpe[n * 16 + j];
    __syncthreads();
    float s = b1[j];
    #pragma unroll
    for (int kk = 0; kk < 16; ++kk) s += l[kk] * w1[j * 16 + kk];
    t1b[(size_t)n * HID + j] = f2bf(fmaxf(s, 0.0f));
}

// ---------------------------------------------------------------- MFMA GEMM
// C[M x N] = A_bf16[M x K] @ (Whi + Wlo)[N x K]^T + bias, f32 accumulate.
// BM=BN=128, BK=64, 4 waves (2x2), each wave 64x64 (4x4 frags of 16x16x32).
// LDS layout row-major with column XOR swizzle: chunk(r,kc) at index r*8+(kc^(r&7)).
// Staging via global_load_lds w16: dest lane-linear; source col permuted per lane
// ((l&7)^(l>>3)) -> each 8-lane group reads one 128B row segment (coalesced).
// MODE 0: C0[row*256+col] = val;  MODE 1: C0 += val;
// MODE 2 (QKVS, N=1024): col<256 -> qf (f32); 256..767 -> khv head-sliced bf16;
//                        >=768 -> skipb (f32)
template <int MODE>
__global__ __launch_bounds__(256) void mgemm(const u16* __restrict__ A,
                                             const u16* __restrict__ Wh,
                                             const u16* __restrict__ Wl,
                                             const float* __restrict__ bias,
                                             int K,
                                             float* __restrict__ C0,
                                             float* __restrict__ qf,
                                             u16* __restrict__ khv,
                                             float* __restrict__ skipb) {
    __shared__ __align__(16) u16 sA[128 * 64];
    __shared__ __align__(16) u16 sWh[128 * 64];
    __shared__ __align__(16) u16 sWl[128 * 64];
    const int tid = threadIdx.x;
    const int l = tid & 63, wid = tid >> 6;
    const int wm = wid >> 1, wn = wid & 1;
    const int lr = l & 15, lc = l >> 4;
    const int r0 = blockIdx.x * 128;
    const int c0 = blockIdx.y * 128;

    f32x4 acc[4][4];
    #pragma unroll
    for (int m = 0; m < 4; ++m)
        #pragma unroll
        for (int n = 0; n < 4; ++n) acc[m][n] = (f32x4){0.f, 0.f, 0.f, 0.f};

    const int sr = l >> 3;                 // row within 8-row group
    const int skc = (l & 7) ^ sr;          // swizzled source column chunk
    for (int k0 = 0; k0 < K; k0 += 64) {
        #pragma unroll
        for (int j = 0; j < 4; ++j) {
            int r = j * 32 + wid * 8 + sr;
            int cb = (j * 256 + wid * 64) * 8;   // u16 idx of wave-uniform dest
            const u16* ga = A  + (size_t)(r0 + r) * K + k0 + skc * 8;
            const u16* gh = Wh + (size_t)(c0 + r) * K + k0 + skc * 8;
            const u16* gl = Wl + (size_t)(c0 + r) * K + k0 + skc * 8;
            gll16(ga, sA  + cb);
            gll16(gh, sWh + cb);
            gll16(gl, sWl + cb);
        }
        __syncthreads();
        #pragma unroll
        for (int kk = 0; kk < 2; ++kk) {
            const int kc = kk * 4 + lc;
            bf16x8 a[4], wh[4], wl[4];
            #pragma unroll
            for (int m = 0; m < 4; ++m) {
                int r = wm * 64 + m * 16 + lr;
                a[m] = *reinterpret_cast<const bf16x8*>(
                    &sA[r * 64 + ((kc ^ (r & 7)) * 8)]);
            }
            #pragma unroll
            for (int n = 0; n < 4; ++n) {
                int r = wn * 64 + n * 16 + lr;
                int off = r * 64 + ((kc ^ (r & 7)) * 8);
                wh[n] = *reinterpret_cast<const bf16x8*>(&sWh[off]);
                wl[n] = *reinterpret_cast<const bf16x8*>(&sWl[off]);
            }
            #pragma unroll
            for (int m = 0; m < 4; ++m)
                #pragma unroll
                for (int n = 0; n < 4; ++n) {
                    acc[m][n] = __builtin_amdgcn_mfma_f32_16x16x32_bf16(a[m], wh[n], acc[m][n], 0, 0, 0);
                    acc[m][n] = __builtin_amdgcn_mfma_f32_16x16x32_bf16(a[m], wl[n], acc[m][n], 0, 0, 0);
                }
        }
        __syncthreads();
    }

    #pragma unroll
    for (int n = 0; n < 4; ++n) {
        int col = c0 + wn * 64 + n * 16 + lr;
        float bv = bias[col];
        #pragma unroll
        for (int m = 0; m < 4; ++m) {
            int rowb = r0 + wm * 64 + m * 16 + lc * 4;
            #pragma unroll
            for (int i = 0; i < 4; ++i) {
                float val = acc[m][n][i] + bv;
                int row = rowb + i;
                if (MODE == 0) {
                    C0[(size_t)row * 256 + col] = val;
                } else if (MODE == 1) {
                    C0[(size_t)row * 256 + col] += val;
                } else {
                    if (c0 < 256) {
                        qf[(size_t)row * 256 + col] = val;
                    } else if (c0 < 512) {
                        int cc = col - 256, hh = cc >> 5, ch = cc & 31;
                        khv[((size_t)hh * N_NODES + row) * 64 + ch] = f2bf(val);
                    } else if (c0 < 768) {
                        int cc = col - 512, hh = cc >> 5, ch = cc & 31;
                        khv[((size_t)hh * N_NODES + row) * 64 + 32 + ch] = f2bf(val);
                    } else {
                        skipb[(size_t)row * 256 + (col - 768)] = val;
                    }
                }
            }
        }
    }
}

// ---------------------------------------------------------------- LayerNorm -> bf16
__global__ __launch_bounds__(256) void ln_kernel(const float* __restrict__ h,
                                                 const float* __restrict__ gw,
                                                 const float* __restrict__ bw,
                                                 u16* __restrict__ xnb) {
    int lane = threadIdx.x & 63, wave = threadIdx.x >> 6;
    int node = blockIdx.x * 4 + wave;
    float4 v = ((const float4*)(h + (size_t)node * HID))[lane];
    float s = v.x + v.y + v.z + v.w;
    #pragma unroll
    for (int off = 32; off; off >>= 1) s += __shfl_xor(s, off, 64);
    float mu = s * (1.0f / HID);
    float dx = v.x - mu, dy = v.y - mu, dz = v.z - mu, dw = v.w - mu;
    float q = dx * dx + dy * dy + dz * dz + dw * dw;
    #pragma unroll
    for (int off = 32; off; off >>= 1) q += __shfl_xor(q, off, 64);
    float inv = rsqrtf(q * (1.0f / HID) + 1e-5f);
    int c = lane * 4;
    float o0 = dx * inv * gw[c + 0] + bw[c + 0];
    float o1 = dy * inv * gw[c + 1] + bw[c + 1];
    float o2 = dz * inv * gw[c + 2] + bw[c + 2];
    float o3 = dw * inv * gw[c + 3] + bw[c + 3];
    uint2 pk;
    pk.x = (unsigned int)f2bf(o0) | ((unsigned int)f2bf(o1) << 16);
    pk.y = (unsigned int)f2bf(o2) | ((unsigned int)f2bf(o3) << 16);
    *reinterpret_cast<uint2*>(xnb + (size_t)node * HID + c) = pk;
}

// ---------------------------------------------------------------- fused edge attention
// one 4-lane group per (node, head): lane owns 8 channels for the entire edge
// walk -> NO cross-slot epilogue reduction. head = blockIdx % 8 keeps per-head
// khv slice (4MB) XCD-L2-resident. Depth-1 software pipeline on k/v rows.
__global__ __launch_bounds__(256) void agg_kernel(const float* __restrict__ q,
                                                  const u16* __restrict__ khv,
                                                  const int* __restrict__ indptr,
                                                  const int* __restrict__ ssrc,
                                                  float* __restrict__ outb) {
    const float scale = 0.17677669529663687f;  // 1/sqrt(32)
    const int tid = threadIdx.x;
    const int g = tid >> 2;     // group 0..63 = node within block
    const int j = tid & 3;      // channel quad (8 ch) within head
    const int h = blockIdx.x & 7;
    const int n = (blockIdx.x >> 3) * 64 + g;

    const float* qp = q + (size_t)n * HID + h * 32 + j * 8;
    f32x4 q0 = *reinterpret_cast<const f32x4*>(qp);
    f32x4 q1 = *reinterpret_cast<const f32x4*>(qp + 4);
    float qv[8];
    #pragma unroll
    for (int i = 0; i < 4; ++i) { qv[i] = q0[i] * scale; qv[4 + i] = q1[i] * scale; }

    const int s0 = indptr[n], s1 = indptr[n + 1];
    const u16* base = khv + (size_t)h * N_NODES * 64 + j * 8;
    float acc[8] = {0.f, 0.f, 0.f, 0.f, 0.f, 0.f, 0.f, 0.f};
    float ssum = 0.f;

    if (s0 < s1) {
        int src = __builtin_nontemporal_load(&ssrc[s0]);
        const u16* rp = base + (size_t)src * 64;
        u16x8 k8 = *reinterpret_cast<const u16x8*>(rp);
        u16x8 v8 = *reinterpret_cast<const u16x8*>(rp + 32);
        for (int e = s0; e < s1; ++e) {
            int en = (e + 1 < s1) ? e + 1 : s1 - 1;
            int srcn = __builtin_nontemporal_load(&ssrc[en]);
            const u16* rpn = base + (size_t)srcn * 64;
            u16x8 kn = *reinterpret_cast<const u16x8*>(rpn);
            u16x8 vn = *reinterpret_cast<const u16x8*>(rpn + 32);
            float prod = 0.f;
            #pragma unroll
            for (int i = 0; i < 8; ++i) prod += qv[i] * bf2f(k8[i]);
            prod += __shfl_xor(prod, 1, 64);
            prod += __shfl_xor(prod, 2, 64);
            float p = __expf(prod);
            ssum += p;
            #pragma unroll
            for (int i = 0; i < 8; ++i) acc[i] += p * bf2f(v8[i]);
            k8 = kn; v8 = vn;
        }
    }

    float inv = 1.0f / fmaxf(ssum, 1e-16f);
    float* op = outb + (size_t)n * HID + h * 32 + j * 8;
    f32x4 o0 = {acc[0] * inv, acc[1] * inv, acc[2] * inv, acc[3] * inv};
    f32x4 o1 = {acc[4] * inv, acc[5] * inv, acc[6] * inv, acc[7] * inv};
    __builtin_nontemporal_store(o0, (f32x4*)op);
    __builtin_nontemporal_store(o1, (f32x4*)(op + 4));
}

// ------------------------------------------- beta gate + relu + residual (+ next LN)
template <bool DO_LN>
__global__ __launch_bounds__(256) void beta_kernel(const float* __restrict__ outb,
                                                   const float* __restrict__ skipb,
                                                   const float* __restrict__ wb,
                                                   const float* __restrict__ gw,
                                                   const float* __restrict__ bw,
                                                   float* __restrict__ h,
                                                   u16* __restrict__ xnb) {
    int lane = threadIdx.x & 63, wave = threadIdx.x >> 6;
    int node = blockIdx.x * 4 + wave;
    int c = lane * 4;
    float4 o  = ((const float4*)(outb  + (size_t)node * HID))[lane];
    float4 sk = ((const float4*)(skipb + (size_t)node * HID))[lane];
    float acc = o.x * wb[c + 0] + o.y * wb[c + 1] + o.z * wb[c + 2] + o.w * wb[c + 3]
              + sk.x * wb[HID + c + 0] + sk.y * wb[HID + c + 1]
              + sk.z * wb[HID + c + 2] + sk.w * wb[HID + c + 3]
              + (o.x - sk.x) * wb[2 * HID + c + 0] + (o.y - sk.y) * wb[2 * HID + c + 1]
              + (o.z - sk.z) * wb[2 * HID + c + 2] + (o.w - sk.w) * wb[2 * HID + c + 3];
    #pragma unroll
    for (int off = 32; off; off >>= 1) acc += __shfl_xor(acc, off, 64);
    float beta = 1.0f / (1.0f + __expf(-acc));
    float4 r = ((const float4*)(h + (size_t)node * HID))[lane];
    float4 out;
    out.x = fmaxf(beta * sk.x + (1.0f - beta) * o.x, 0.0f) + r.x;
    out.y = fmaxf(beta * sk.y + (1.0f - beta) * o.y, 0.0f) + r.y;
    out.z = fmaxf(beta * sk.z + (1.0f - beta) * o.z, 0.0f) + r.z;
    out.w = fmaxf(beta * sk.w + (1.0f - beta) * o.w, 0.0f) + r.w;
    ((float4*)(h + (size_t)node * HID))[lane] = out;

    if (DO_LN) {
        float s = out.x + out.y + out.z + out.w;
        #pragma unroll
        for (int off = 32; off; off >>= 1) s += __shfl_xor(s, off, 64);
        float mu = s * (1.0f / HID);
        float dx = out.x - mu, dy = out.y - mu, dz = out.z - mu, dw = out.w - mu;
        float qq = dx * dx + dy * dy + dz * dz + dw * dw;
        #pragma unroll
        for (int off = 32; off; off >>= 1) qq += __shfl_xor(qq, off, 64);
        float inv = rsqrtf(qq * (1.0f / HID) + 1e-5f);
        float o0 = dx * inv * gw[c + 0] + bw[c + 0];
        float o1 = dy * inv * gw[c + 1] + bw[c + 1];
        float o2 = dz * inv * gw[c + 2] + bw[c + 2];
        float o3 = dw * inv * gw[c + 3] + bw[c + 3];
        uint2 pk;
        pk.x = (unsigned int)f2bf(o0) | ((unsigned int)f2bf(o1) << 16);
        pk.y = (unsigned int)f2bf(o2) | ((unsigned int)f2bf(o3) << 16);
        *reinterpret_cast<uint2*>(xnb + (size_t)node * HID + c) = pk;
    }
}

// ---------------------------------------------------------------- pooling + final MLP
__global__ __launch_bounds__(128) void bounds_kernel(const int* __restrict__ batch,
                                                     int* __restrict__ gstart) {
    int g = threadIdx.x;
    if (g > N_GRAPHS) return;
    int lo = 0, hi = N_NODES;
    while (lo < hi) { int mid = (lo + hi) >> 1; if (batch[mid] < g) lo = mid + 1; else hi = mid; }
    gstart[g] = lo;
}

// stage 1: 16 chunks per graph, deterministic partials pxg[g][chunk][256]
__global__ __launch_bounds__(256) void pool_kernel(const float* __restrict__ h,
                                                   const int* __restrict__ gstart,
                                                   float* __restrict__ pxg) {
    int gb = blockIdx.x;                 // 0 .. N_GRAPHS*P_CHUNK-1
    int g = gb >> 4, cch = gb & (P_CHUNK - 1);
    int t = threadIdx.x;
    int s = gstart[g], e = gstart[g + 1];
    float acc = 0.0f;
    for (int i = s + cch; i < e; i += P_CHUNK)
        acc += __builtin_nontemporal_load(&h[(size_t)i * HID + t]);
    pxg[(size_t)gb * HID + t] = acc;
}

__global__ __launch_bounds__(256) void mlp_kernel(const float* __restrict__ pxg,
                                                  const int* __restrict__ gstart,
                                                  const float* __restrict__ w1,
                                                  const float* __restrict__ b1,
                                                  const float* __restrict__ w2,
                                                  const float* __restrict__ b2,
                                                  float* __restrict__ out) {
    __shared__ float xr[256];
    __shared__ float red[256];
    int g = blockIdx.x, t = threadIdx.x;
    float sum = 0.0f;
    #pragma unroll
    for (int c = 0; c < P_CHUNK; ++c)
        sum += pxg[((size_t)g * P_CHUNK + c) * HID + t];
    float cnt = (float)(gstart[g + 1] - gstart[g]);
    xr[t] = sum / fmaxf(cnt, 1.0f);
    __syncthreads();
    float s = b1[t];
    #pragma unroll 4
    for (int kk = 0; kk < 256; ++kk) s += xr[kk] * w1[t * 256 + kk];
    s = fmaxf(s, 0.0f);
    red[t] = s * w2[t];
    __syncthreads();
    for (int off = 128; off; off >>= 1) {
        if (t < off) red[t] += red[t + off];
        __syncthreads();
    }
    if (t == 0) out[g] = red[0] + b2[0];
}

// ---------------------------------------------------------------- host
extern "C" void kernel_launch(void* const* d_in, const int* in_sizes, int n_in,
                              void* d_out, int out_size, void* d_ws, size_t ws_size,
                              hipStream_t stream) {
    const float* x      = (const float*)d_in[0];
    const float* lpe    = (const float*)d_in[1];
    const float* pe_w1  = (const float*)d_in[2];
    const float* pe_b1  = (const float*)d_in[3];
    const float* pe_w2  = (const float*)d_in[4];
    const float* pe_b2  = (const float*)d_in[5];
    const float* emb_w  = (const float*)d_in[6];
    const float* emb_b  = (const float*)d_in[7];
    const float* ln_g   = (const float*)d_in[8];
    const float* ln_b   = (const float*)d_in[9];
    const float* wq     = (const float*)d_in[10];
    const float* bq     = (const float*)d_in[11];
    const float* wk     = (const float*)d_in[12];
    const float* bk     = (const float*)d_in[13];
    const float* wv     = (const float*)d_in[14];
    const float* bv     = (const float*)d_in[15];
    const float* wskip  = (const float*)d_in[16];
    const float* bskip  = (const float*)d_in[17];
    const float* wbeta  = (const float*)d_in[18];
    const float* mlp_w1 = (const float*)d_in[19];
    const float* mlp_b1 = (const float*)d_in[20];
    const float* mlp_w2 = (const float*)d_in[21];
    const float* mlp_b2 = (const float*)d_in[22];
    const int*   eidx   = (const int*)d_in[23];
    const int*   batch  = (const int*)d_in[24];

    char* w = (char*)d_ws;
    const size_t NH = (size_t)N_NODES * HID;
    float* h     = (float*)w;           w += NH * 4;
    float* qf    = (float*)w;           w += NH * 4;
    float* skipb = (float*)w;           w += NH * 4;
    float* outb  = (float*)w;           w += NH * 4;
    float* pxg   = (float*)w;           w += (size_t)N_GRAPHS * P_CHUNK * HID * 4;
    u16* xnb     = (u16*)w;             w += NH * 2;
    u16* khv     = (u16*)w;             w += (size_t)HEADS * N_NODES * 64 * 2;
    u16* xb      = (u16*)w;             w += (size_t)N_NODES * IN_CH * 2;
    u16* t1b     = (u16*)w;             w += NH * 2;
    u16* ehi     = (u16*)w;             w += 32768 * 2;
    u16* elo     = (u16*)w;             w += 32768 * 2;
    u16* p2hi    = (u16*)w;             w += 65536 * 2;
    u16* p2lo    = (u16*)w;             w += 65536 * 2;
    u16* wchi    = (u16*)w;             w += 1048576 * 2;
    u16* wclo    = (u16*)w;             w += 1048576 * 2;
    float* bcat  = (float*)w;           w += 4096 * 4;
    int* deg     = (int*)w;             w += N_NODES * 4;
    int* indptr  = (int*)w;             w += (N_NODES + 1) * 4;
    int* cursor  = (int*)w;             w += N_NODES * 4;
    int* ssrc    = (int*)w;             w += N_EDGES * 4;
    int* gstart  = (int*)w;             w += (N_GRAPHS + 1) * 4;

    // weight conversions (every call; deterministic)
    split_kernel<<<128, 256, 0, stream>>>(emb_w, ehi, elo, 32768);
    split_kernel<<<256, 256, 0, stream>>>(pe_w2, p2hi, p2lo, 65536);
    wcat_kernel<<<4096, 256, 0, stream>>>(wq, wk, wv, wskip, wchi, wclo);
    bcat_kernel<<<16, 256, 0, stream>>>(bq, bk, bv, bskip, bcat);
    tob16_kernel<<<16000, 256, 0, stream>>>(x, xb, N_NODES * IN_CH);

    // CSR by destination
    hipMemsetAsync(deg, 0, N_NODES * sizeof(int), stream);
    count_kernel<<<(N_EDGES + 255) / 256, 256, 0, stream>>>(eidx, deg);
    scan_kernel<<<1, 256, 0, stream>>>(deg, indptr, cursor);
    scatter_kernel<<<(N_EDGES + 255) / 256, 256, 0, stream>>>(eidx, cursor, ssrc);

    // h = x@emb_w^T + emb_b + pe_mlp(lpe)
    pe1_kernel<<<N_NODES, 256, 0, stream>>>(lpe, pe_w1, pe_b1, t1b);
    mgemm<0><<<dim3(250, 2), 256, 0, stream>>>(xb, ehi, elo, emb_b, IN_CH, h, nullptr, nullptr, nullptr);
    mgemm<1><<<dim3(250, 2), 256, 0, stream>>>(t1b, p2hi, p2lo, pe_b2, HID, h, nullptr, nullptr, nullptr);

    ln_kernel<<<N_NODES / 4, 256, 0, stream>>>(h, ln_g, ln_b, xnb);
    for (int l = 0; l < N_LAYERS; ++l) {
        mgemm<2><<<dim3(250, 8), 256, 0, stream>>>(xnb, wchi + (size_t)l * 262144,
                                                   wclo + (size_t)l * 262144,
                                                   bcat + l * 1024, HID,
                                                   nullptr, qf, khv, skipb);
        agg_kernel<<<(N_NODES / 64) * 8, 256, 0, stream>>>(qf, khv, indptr, ssrc, outb);
        if (l < N_LAYERS - 1) {
            beta_kernel<true><<<N_NODES / 4, 256, 0, stream>>>(
                outb, skipb, wbeta + l * 3 * HID,
                ln_g + (l + 1) * HID, ln_b + (l + 1) * HID, h, xnb);
        } else {
            beta_kernel<false><<<N_NODES / 4, 256, 0, stream>>>(
                outb, skipb, wbeta + l * 3 * HID, nullptr, nullptr, h, nullptr);
        }
    }

    bounds_kernel<<<1, 128, 0, stream>>>(batch, gstart);
    pool_kernel<<<N_GRAPHS * P_CHUNK, 256, 0, stream>>>(h, gstart, pxg);
    mlp_kernel<<<N_GRAPHS, 256, 0, stream>>>(pxg, gstart, mlp_w1, mlp_b1, mlp_w2, mlp_b2, (float*)d_out);
}

// Round 8
// 978.332 us; speedup vs baseline: 1.3468x; 1.0452x over previous
//
#include <hip/hip_runtime.h>

#define N_NODES   32000
#define N_EDGES   512000
#define IN_CH     128
#define HID       256
#define HEADS     8
#define D_HEAD    32
#define N_LAYERS  4
#define N_GRAPHS  64
#define P_CHUNK   16

typedef unsigned short u16;
typedef __bf16 bf16x8 __attribute__((ext_vector_type(8)));
typedef float f32x4 __attribute__((ext_vector_type(4)));
typedef unsigned short u16x8 __attribute__((ext_vector_type(8)));

__device__ __forceinline__ u16 f2bf(float x) {
    union { float f; unsigned int u; } v; v.f = x;
    unsigned int r = v.u + 0x7FFFu + ((v.u >> 16) & 1u);  // round-to-nearest-even
    return (u16)(r >> 16);
}
__device__ __forceinline__ float bf2f(u16 b) {
    union { unsigned int u; float f; } v; v.u = ((unsigned int)b) << 16;
    return v.f;
}

// async global->LDS, 16B per lane; lds dest = wave-uniform base + lane*16
__device__ __forceinline__ void gll16(const u16* g, u16* l) {
    __builtin_amdgcn_global_load_lds(
        (const __attribute__((address_space(1))) unsigned int*)g,
        (__attribute__((address_space(3))) unsigned int*)l, 16, 0, 0);
}

// ---------------------------------------------------------------- CSR build
__global__ __launch_bounds__(256) void count_kernel(const int* __restrict__ ei,
                                                    int* __restrict__ deg) {
    int e = blockIdx.x * 256 + threadIdx.x;
    if (e < N_EDGES) atomicAdd(&deg[ei[N_EDGES + e]], 1);
}

__global__ __launch_bounds__(256) void scan_kernel(const int* __restrict__ deg,
                                                   int* __restrict__ indptr,
                                                   int* __restrict__ cursor) {
    __shared__ int wsum[4];
    __shared__ int carry_s;
    __shared__ int total_s;
    int tid = threadIdx.x;
    int lane = tid & 63, wave = tid >> 6;
    if (tid == 0) carry_s = 0;
    __syncthreads();
    for (int base = 0; base < N_NODES; base += 256) {
        int i = base + tid;
        int v = (i < N_NODES) ? deg[i] : 0;
        int x = v;
        #pragma unroll
        for (int off = 1; off < 64; off <<= 1) {
            int t = __shfl_up(x, off, 64);
            if (lane >= off) x += t;
        }
        if (lane == 63) wsum[wave] = x;
        __syncthreads();
        if (tid == 0) {
            int s = 0;
            #pragma unroll
            for (int w = 0; w < 4; ++w) { int t = wsum[w]; wsum[w] = s; s += t; }
            total_s = s;
        }
        __syncthreads();
        int excl = carry_s + wsum[wave] + x - v;
        if (i < N_NODES) { indptr[i] = excl; cursor[i] = excl; }
        __syncthreads();
        if (tid == 0) carry_s += total_s;
        __syncthreads();
    }
    if (tid == 0) indptr[N_NODES] = carry_s;
}

__global__ __launch_bounds__(256) void scatter_kernel(const int* __restrict__ ei,
                                                      int* __restrict__ cursor,
                                                      int* __restrict__ ssrc) {
    int e = blockIdx.x * 256 + threadIdx.x;
    if (e < N_EDGES) {
        int dst = ei[N_EDGES + e];
        int pos = atomicAdd(&cursor[dst], 1);
        ssrc[pos] = ei[e];
    }
}

// ---------------------------------------------------------------- conversions
__global__ __launch_bounds__(256) void tob16_kernel(const float* __restrict__ src,
                                                    u16* __restrict__ dst, int n) {
    int i = blockIdx.x * 256 + threadIdx.x;
    if (i < n) dst[i] = f2bf(src[i]);
}

// builds wcat[l][1024][256] = concat(wq,wk,wv,wskip) rows (single bf16)
__global__ __launch_bounds__(256) void wcat_kernel(const float* __restrict__ wq,
                                                   const float* __restrict__ wk,
                                                   const float* __restrict__ wv,
                                                   const float* __restrict__ ws,
                                                   u16* __restrict__ hi) {
    int i = blockIdx.x * 256 + threadIdx.x;  // 4*1024*256 = 1048576 total
    int l = i >> 18;
    int rem = i & 262143;
    int r = rem >> 8, c = rem & 255;
    int seg = r >> 8, rr = r & 255;
    const float* w = seg == 0 ? wq : seg == 1 ? wk : seg == 2 ? wv : ws;
    hi[i] = f2bf(w[(size_t)l * 65536 + rr * 256 + c]);
}

__global__ __launch_bounds__(256) void bcat_kernel(const float* __restrict__ bq,
                                                   const float* __restrict__ bk,
                                                   const float* __restrict__ bv,
                                                   const float* __restrict__ bs,
                                                   float* __restrict__ bcat) {
    int i = blockIdx.x * 256 + threadIdx.x;  // 4096
    int l = i >> 10, r = i & 1023;
    int seg = r >> 8, rr = r & 255;
    const float* b = seg == 0 ? bq : seg == 1 ? bk : seg == 2 ? bv : bs;
    bcat[i] = b[l * 256 + rr];
}

// ---------------------------------------------------------------- pe MLP stage 1
__global__ __launch_bounds__(256) void pe1_kernel(const float* __restrict__ lpe,
                                                  const float* __restrict__ w1,
                                                  const float* __restrict__ b1,
                                                  u16* __restrict__ t1b) {
    __shared__ float l[16];
    int n = blockIdx.x, j = threadIdx.x;
    if (j < 16) l[j] = lpe[n * 16 + j];
    __syncthreads();
    float s = b1[j];
    #pragma unroll
    for (int kk = 0; kk < 16; ++kk) s += l[kk] * w1[j * 16 + kk];
    t1b[(size_t)n * HID + j] = f2bf(fmaxf(s, 0.0f));
}

// ---------------------------------------------------------------- MFMA GEMM
// C[M x N] = A_bf16[M x K] @ W_bf16[N x K]^T + bias, f32 accumulate.
// BM=BN=128, BK=64, 4 waves (2x2), each wave 64x64 (4x4 frags of 16x16x32).
// LDS row-major w/ column XOR swizzle: chunk(r,kc) at index r*8+(kc^(r&7)).
// Staging via global_load_lds w16: dest lane-linear; source col permuted per lane.
// MODE 0: C0[row*256+col] = val;  MODE 1: C0 += val;
// MODE 2 (QKVS, N=1024): col<256 -> qb (bf16); 256..767 -> khv head-sliced bf16;
//                        >=768 -> skipb (f32)
template <int MODE>
__global__ __launch_bounds__(256) void mgemm(const u16* __restrict__ A,
                                             const u16* __restrict__ Wh,
                                             const float* __restrict__ bias,
                                             int K,
                                             float* __restrict__ C0,
                                             u16* __restrict__ qb,
                                             u16* __restrict__ khv,
                                             float* __restrict__ skipb) {
    __shared__ __align__(16) u16 sA[128 * 64];
    __shared__ __align__(16) u16 sWh[128 * 64];
    const int tid = threadIdx.x;
    const int l = tid & 63, wid = tid >> 6;
    const int wm = wid >> 1, wn = wid & 1;
    const int lr = l & 15, lc = l >> 4;
    const int r0 = blockIdx.x * 128;
    const int c0 = blockIdx.y * 128;

    f32x4 acc[4][4];
    #pragma unroll
    for (int m = 0; m < 4; ++m)
        #pragma unroll
        for (int n = 0; n < 4; ++n) acc[m][n] = (f32x4){0.f, 0.f, 0.f, 0.f};

    const int sr = l >> 3;                 // row within 8-row group
    const int skc = (l & 7) ^ sr;          // swizzled source column chunk
    for (int k0 = 0; k0 < K; k0 += 64) {
        #pragma unroll
        for (int j = 0; j < 4; ++j) {
            int r = j * 32 + wid * 8 + sr;
            int cb = (j * 256 + wid * 64) * 8;   // u16 idx of wave-uniform dest
            const u16* ga = A  + (size_t)(r0 + r) * K + k0 + skc * 8;
            const u16* gh = Wh + (size_t)(c0 + r) * K + k0 + skc * 8;
            gll16(ga, sA  + cb);
            gll16(gh, sWh + cb);
        }
        __syncthreads();
        #pragma unroll
        for (int kk = 0; kk < 2; ++kk) {
            const int kc = kk * 4 + lc;
            bf16x8 a[4], wh[4];
            #pragma unroll
            for (int m = 0; m < 4; ++m) {
                int r = wm * 64 + m * 16 + lr;
                a[m] = *reinterpret_cast<const bf16x8*>(
                    &sA[r * 64 + ((kc ^ (r & 7)) * 8)]);
            }
            #pragma unroll
            for (int n = 0; n < 4; ++n) {
                int r = wn * 64 + n * 16 + lr;
                wh[n] = *reinterpret_cast<const bf16x8*>(
                    &sWh[r * 64 + ((kc ^ (r & 7)) * 8)]);
            }
            #pragma unroll
            for (int m = 0; m < 4; ++m)
                #pragma unroll
                for (int n = 0; n < 4; ++n)
                    acc[m][n] = __builtin_amdgcn_mfma_f32_16x16x32_bf16(a[m], wh[n], acc[m][n], 0, 0, 0);
        }
        __syncthreads();
    }

    #pragma unroll
    for (int n = 0; n < 4; ++n) {
        int col = c0 + wn * 64 + n * 16 + lr;
        float bv = bias[col];
        #pragma unroll
        for (int m = 0; m < 4; ++m) {
            int rowb = r0 + wm * 64 + m * 16 + lc * 4;
            #pragma unroll
            for (int i = 0; i < 4; ++i) {
                float val = acc[m][n][i] + bv;
                int row = rowb + i;
                if (MODE == 0) {
                    C0[(size_t)row * 256 + col] = val;
                } else if (MODE == 1) {
                    C0[(size_t)row * 256 + col] += val;
                } else {
                    if (c0 < 256) {
                        qb[(size_t)row * 256 + col] = f2bf(val);
                    } else if (c0 < 512) {
                        int cc = col - 256, hh = cc >> 5, ch = cc & 31;
                        khv[((size_t)hh * N_NODES + row) * 64 + ch] = f2bf(val);
                    } else if (c0 < 768) {
                        int cc = col - 512, hh = cc >> 5, ch = cc & 31;
                        khv[((size_t)hh * N_NODES + row) * 64 + 32 + ch] = f2bf(val);
                    } else {
                        skipb[(size_t)row * 256 + (col - 768)] = val;
                    }
                }
            }
        }
    }
}

// ---------------------------------------------------------------- LayerNorm -> bf16
__global__ __launch_bounds__(256) void ln_kernel(const float* __restrict__ h,
                                                 const float* __restrict__ gw,
                                                 const float* __restrict__ bw,
                                                 u16* __restrict__ xnb) {
    int lane = threadIdx.x & 63, wave = threadIdx.x >> 6;
    int node = blockIdx.x * 4 + wave;
    float4 v = ((const float4*)(h + (size_t)node * HID))[lane];
    float s = v.x + v.y + v.z + v.w;
    #pragma unroll
    for (int off = 32; off; off >>= 1) s += __shfl_xor(s, off, 64);
    float mu = s * (1.0f / HID);
    float dx = v.x - mu, dy = v.y - mu, dz = v.z - mu, dw = v.w - mu;
    float q = dx * dx + dy * dy + dz * dz + dw * dw;
    #pragma unroll
    for (int off = 32; off; off >>= 1) q += __shfl_xor(q, off, 64);
    float inv = rsqrtf(q * (1.0f / HID) + 1e-5f);
    int c = lane * 4;
    float o0 = dx * inv * gw[c + 0] + bw[c + 0];
    float o1 = dy * inv * gw[c + 1] + bw[c + 1];
    float o2 = dz * inv * gw[c + 2] + bw[c + 2];
    float o3 = dw * inv * gw[c + 3] + bw[c + 3];
    uint2 pk;
    pk.x = (unsigned int)f2bf(o0) | ((unsigned int)f2bf(o1) << 16);
    pk.y = (unsigned int)f2bf(o2) | ((unsigned int)f2bf(o3) << 16);
    *reinterpret_cast<uint2*>(xnb + (size_t)node * HID + c) = pk;
}

// ---------------------------------------------------------------- fused edge attention
// one 4-lane group per (node, head); lane owns 8 channels for the whole walk
// (no cross-slot epilogue). head = blockIdx % 8 -> XCD L2 affinity. Depth-2
// software pipeline on the dependent ssrc -> khv-row chain.
__global__ __launch_bounds__(256) void agg_kernel(const u16* __restrict__ qb,
                                                  const u16* __restrict__ khv,
                                                  const int* __restrict__ indptr,
                                                  const int* __restrict__ ssrc,
                                                  float* __restrict__ outb) {
    const float scale = 0.17677669529663687f;  // 1/sqrt(32)
    const int tid = threadIdx.x;
    const int g = tid >> 2;     // group 0..63 = node within block
    const int j = tid & 3;      // channel quad (8 ch) within head
    const int h = blockIdx.x & 7;
    const int n = (blockIdx.x >> 3) * 64 + g;

    u16x8 q8 = *reinterpret_cast<const u16x8*>(qb + (size_t)n * HID + h * 32 + j * 8);
    float qv[8];
    #pragma unroll
    for (int i = 0; i < 8; ++i) qv[i] = bf2f(q8[i]) * scale;

    const int s0 = indptr[n], s1 = indptr[n + 1];
    const u16* base = khv + (size_t)h * N_NODES * 64 + j * 8;
    float acc[8] = {0.f, 0.f, 0.f, 0.f, 0.f, 0.f, 0.f, 0.f};
    float ssum = 0.f;

    if (s0 < s1) {
        const int last = s1 - 1;
        int eA = s0, eB = (s0 + 1 < s1) ? s0 + 1 : last;
        int srcA = __builtin_nontemporal_load(&ssrc[eA]);
        int srcB = __builtin_nontemporal_load(&ssrc[eB]);
        const u16* rA = base + (size_t)srcA * 64;
        const u16* rB = base + (size_t)srcB * 64;
        u16x8 kA = *reinterpret_cast<const u16x8*>(rA);
        u16x8 vA = *reinterpret_cast<const u16x8*>(rA + 32);
        u16x8 kB = *reinterpret_cast<const u16x8*>(rB);
        u16x8 vB = *reinterpret_cast<const u16x8*>(rB + 32);
        for (int e = s0; e < s1; ++e) {
            int en = (e + 2 <= last) ? e + 2 : last;
            int srcN = __builtin_nontemporal_load(&ssrc[en]);
            const u16* rN = base + (size_t)srcN * 64;
            u16x8 kN = *reinterpret_cast<const u16x8*>(rN);
            u16x8 vN = *reinterpret_cast<const u16x8*>(rN + 32);
            float prod = 0.f;
            #pragma unroll
            for (int i = 0; i < 8; ++i) prod += qv[i] * bf2f(kA[i]);
            prod += __shfl_xor(prod, 1, 64);
            prod += __shfl_xor(prod, 2, 64);
            float p = __expf(prod);
            ssum += p;
            #pragma unroll
            for (int i = 0; i < 8; ++i) acc[i] += p * bf2f(vA[i]);
            kA = kB; vA = vB; kB = kN; vB = vN;
        }
    }

    float inv = 1.0f / fmaxf(ssum, 1e-16f);
    float* op = outb + (size_t)n * HID + h * 32 + j * 8;
    f32x4 o0 = {acc[0] * inv, acc[1] * inv, acc[2] * inv, acc[3] * inv};
    f32x4 o1 = {acc[4] * inv, acc[5] * inv, acc[6] * inv, acc[7] * inv};
    __builtin_nontemporal_store(o0, (f32x4*)op);
    __builtin_nontemporal_store(o1, (f32x4*)(op + 4));
}

// ------------------------------------------- beta gate + relu + residual (+ next LN)
template <bool DO_LN>
__global__ __launch_bounds__(256) void beta_kernel(const float* __restrict__ outb,
                                                   const float* __restrict__ skipb,
                                                   const float* __restrict__ wb,
                                                   const float* __restrict__ gw,
                                                   const float* __restrict__ bw,
                                                   float* __restrict__ h,
                                                   u16* __restrict__ xnb) {
    int lane = threadIdx.x & 63, wave = threadIdx.x >> 6;
    int node = blockIdx.x * 4 + wave;
    int c = lane * 4;
    float4 o  = ((const float4*)(outb  + (size_t)node * HID))[lane];
    float4 sk = ((const float4*)(skipb + (size_t)node * HID))[lane];
    float acc = o.x * wb[c + 0] + o.y * wb[c + 1] + o.z * wb[c + 2] + o.w * wb[c + 3]
              + sk.x * wb[HID + c + 0] + sk.y * wb[HID + c + 1]
              + sk.z * wb[HID + c + 2] + sk.w * wb[HID + c + 3]
              + (o.x - sk.x) * wb[2 * HID + c + 0] + (o.y - sk.y) * wb[2 * HID + c + 1]
              + (o.z - sk.z) * wb[2 * HID + c + 2] + (o.w - sk.w) * wb[2 * HID + c + 3];
    #pragma unroll
    for (int off = 32; off; off >>= 1) acc += __shfl_xor(acc, off, 64);
    float beta = 1.0f / (1.0f + __expf(-acc));
    float4 r = ((const float4*)(h + (size_t)node * HID))[lane];
    float4 out;
    out.x = fmaxf(beta * sk.x + (1.0f - beta) * o.x, 0.0f) + r.x;
    out.y = fmaxf(beta * sk.y + (1.0f - beta) * o.y, 0.0f) + r.y;
    out.z = fmaxf(beta * sk.z + (1.0f - beta) * o.z, 0.0f) + r.z;
    out.w = fmaxf(beta * sk.w + (1.0f - beta) * o.w, 0.0f) + r.w;
    ((float4*)(h + (size_t)node * HID))[lane] = out;

    if (DO_LN) {
        float s = out.x + out.y + out.z + out.w;
        #pragma unroll
        for (int off = 32; off; off >>= 1) s += __shfl_xor(s, off, 64);
        float mu = s * (1.0f / HID);
        float dx = out.x - mu, dy = out.y - mu, dz = out.z - mu, dw = out.w - mu;
        float qq = dx * dx + dy * dy + dz * dz + dw * dw;
        #pragma unroll
        for (int off = 32; off; off >>= 1) qq += __shfl_xor(qq, off, 64);
        float inv = rsqrtf(qq * (1.0f / HID) + 1e-5f);
        float o0 = dx * inv * gw[c + 0] + bw[c + 0];
        float o1 = dy * inv * gw[c + 1] + bw[c + 1];
        float o2 = dz * inv * gw[c + 2] + bw[c + 2];
        float o3 = dw * inv * gw[c + 3] + bw[c + 3];
        uint2 pk;
        pk.x = (unsigned int)f2bf(o0) | ((unsigned int)f2bf(o1) << 16);
        pk.y = (unsigned int)f2bf(o2) | ((unsigned int)f2bf(o3) << 16);
        *reinterpret_cast<uint2*>(xnb + (size_t)node * HID + c) = pk;
    }
}

// ---------------------------------------------------------------- pooling + final MLP
__global__ __launch_bounds__(128) void bounds_kernel(const int* __restrict__ batch,
                                                     int* __restrict__ gstart) {
    int g = threadIdx.x;
    if (g > N_GRAPHS) return;
    int lo = 0, hi = N_NODES;
    while (lo < hi) { int mid = (lo + hi) >> 1; if (batch[mid] < g) lo = mid + 1; else hi = mid; }
    gstart[g] = lo;
}

// stage 1: 16 chunks per graph, deterministic partials pxg[g][chunk][256]
__global__ __launch_bounds__(256) void pool_kernel(const float* __restrict__ h,
                                                   const int* __restrict__ gstart,
                                                   float* __restrict__ pxg) {
    int gb = blockIdx.x;                 // 0 .. N_GRAPHS*P_CHUNK-1
    int g = gb >> 4, cch = gb & (P_CHUNK - 1);
    int t = threadIdx.x;
    int s = gstart[g], e = gstart[g + 1];
    float acc = 0.0f;
    for (int i = s + cch; i < e; i += P_CHUNK)
        acc += __builtin_nontemporal_load(&h[(size_t)i * HID + t]);
    pxg[(size_t)gb * HID + t] = acc;
}

__global__ __launch_bounds__(256) void mlp_kernel(const float* __restrict__ pxg,
                                                  const int* __restrict__ gstart,
                                                  const float* __restrict__ w1,
                                                  const float* __restrict__ b1,
                                                  const float* __restrict__ w2,
                                                  const float* __restrict__ b2,
                                                  float* __restrict__ out) {
    __shared__ float xr[256];
    __shared__ float red[256];
    int g = blockIdx.x, t = threadIdx.x;
    float sum = 0.0f;
    #pragma unroll
    for (int c = 0; c < P_CHUNK; ++c)
        sum += pxg[((size_t)g * P_CHUNK + c) * HID + t];
    float cnt = (float)(gstart[g + 1] - gstart[g]);
    xr[t] = sum / fmaxf(cnt, 1.0f);
    __syncthreads();
    float s = b1[t];
    #pragma unroll 4
    for (int kk = 0; kk < 256; ++kk) s += xr[kk] * w1[t * 256 + kk];
    s = fmaxf(s, 0.0f);
    red[t] = s * w2[t];
    __syncthreads();
    for (int off = 128; off; off >>= 1) {
        if (t < off) red[t] += red[t + off];
        __syncthreads();
    }
    if (t == 0) out[g] = red[0] + b2[0];
}

// ---------------------------------------------------------------- host
extern "C" void kernel_launch(void* const* d_in, const int* in_sizes, int n_in,
                              void* d_out, int out_size, void* d_ws, size_t ws_size,
                              hipStream_t stream) {
    const float* x      = (const float*)d_in[0];
    const float* lpe    = (const float*)d_in[1];
    const float* pe_w1  = (const float*)d_in[2];
    const float* pe_b1  = (const float*)d_in[3];
    const float* pe_w2  = (const float*)d_in[4];
    const float* pe_b2  = (const float*)d_in[5];
    const float* emb_w  = (const float*)d_in[6];
    const float* emb_b  = (const float*)d_in[7];
    const float* ln_g   = (const float*)d_in[8];
    const float* ln_b   = (const float*)d_in[9];
    const float* wq     = (const float*)d_in[10];
    const float* bq     = (const float*)d_in[11];
    const float* wk     = (const float*)d_in[12];
    const float* bk     = (const float*)d_in[13];
    const float* wv     = (const float*)d_in[14];
    const float* bv     = (const float*)d_in[15];
    const float* wskip  = (const float*)d_in[16];
    const float* bskip  = (const float*)d_in[17];
    const float* wbeta  = (const float*)d_in[18];
    const float* mlp_w1 = (const float*)d_in[19];
    const float* mlp_b1 = (const float*)d_in[20];
    const float* mlp_w2 = (const float*)d_in[21];
    const float* mlp_b2 = (const float*)d_in[22];
    const int*   eidx   = (const int*)d_in[23];
    const int*   batch  = (const int*)d_in[24];

    char* w = (char*)d_ws;
    const size_t NH = (size_t)N_NODES * HID;
    float* h     = (float*)w;           w += NH * 4;
    float* skipb = (float*)w;           w += NH * 4;
    float* outb  = (float*)w;           w += NH * 4;
    float* pxg   = (float*)w;           w += (size_t)N_GRAPHS * P_CHUNK * HID * 4;
    u16* qb      = (u16*)w;             w += NH * 2;
    u16* xnb     = (u16*)w;             w += NH * 2;
    u16* khv     = (u16*)w;             w += (size_t)HEADS * N_NODES * 64 * 2;
    u16* xb      = (u16*)w;             w += (size_t)N_NODES * IN_CH * 2;
    u16* t1b     = (u16*)w;             w += NH * 2;
    u16* ehi     = (u16*)w;             w += 32768 * 2;
    u16* p2hi    = (u16*)w;             w += 65536 * 2;
    u16* wchi    = (u16*)w;             w += 1048576 * 2;
    float* bcat  = (float*)w;           w += 4096 * 4;
    int* deg     = (int*)w;             w += N_NODES * 4;
    int* indptr  = (int*)w;             w += (N_NODES + 1) * 4;
    int* cursor  = (int*)w;             w += N_NODES * 4;
    int* ssrc    = (int*)w;             w += N_EDGES * 4;
    int* gstart  = (int*)w;             w += (N_GRAPHS + 1) * 4;

    // weight conversions (every call; deterministic)
    tob16_kernel<<<128, 256, 0, stream>>>(emb_w, ehi, 32768);
    tob16_kernel<<<256, 256, 0, stream>>>(pe_w2, p2hi, 65536);
    wcat_kernel<<<4096, 256, 0, stream>>>(wq, wk, wv, wskip, wchi);
    bcat_kernel<<<16, 256, 0, stream>>>(bq, bk, bv, bskip, bcat);
    tob16_kernel<<<16000, 256, 0, stream>>>(x, xb, N_NODES * IN_CH);

    // CSR by destination
    hipMemsetAsync(deg, 0, N_NODES * sizeof(int), stream);
    count_kernel<<<(N_EDGES + 255) / 256, 256, 0, stream>>>(eidx, deg);
    scan_kernel<<<1, 256, 0, stream>>>(deg, indptr, cursor);
    scatter_kernel<<<(N_EDGES + 255) / 256, 256, 0, stream>>>(eidx, cursor, ssrc);

    // h = x@emb_w^T + emb_b + pe_mlp(lpe)
    pe1_kernel<<<N_NODES, 256, 0, stream>>>(lpe, pe_w1, pe_b1, t1b);
    mgemm<0><<<dim3(250, 2), 256, 0, stream>>>(xb, ehi, emb_b, IN_CH, h, nullptr, nullptr, nullptr);
    mgemm<1><<<dim3(250, 2), 256, 0, stream>>>(t1b, p2hi, pe_b2, HID, h, nullptr, nullptr, nullptr);

    ln_kernel<<<N_NODES / 4, 256, 0, stream>>>(h, ln_g, ln_b, xnb);
    for (int l = 0; l < N_LAYERS; ++l) {
        mgemm<2><<<dim3(250, 8), 256, 0, stream>>>(xnb, wchi + (size_t)l * 262144,
                                                   bcat + l * 1024, HID,
                                                   nullptr, qb, khv, skipb);
        agg_kernel<<<(N_NODES / 64) * 8, 256, 0, stream>>>(qb, khv, indptr, ssrc, outb);
        if (l < N_LAYERS - 1) {
            beta_kernel<true><<<N_NODES / 4, 256, 0, stream>>>(
                outb, skipb, wbeta + l * 3 * HID,
                ln_g + (l + 1) * HID, ln_b + (l + 1) * HID, h, xnb);
        } else {
            beta_kernel<false><<<N_NODES / 4, 256, 0, stream>>>(
                outb, skipb, wbeta + l * 3 * HID, nullptr, nullptr, h, nullptr);
        }
    }

    bounds_kernel<<<1, 128, 0, stream>>>(batch, gstart);
    pool_kernel<<<N_GRAPHS * P_CHUNK, 256, 0, stream>>>(h, gstart, pxg);
    mlp_kernel<<<N_GRAPHS, 256, 0, stream>>>(pxg, gstart, mlp_w1, mlp_b1, mlp_w2, mlp_b2, (float*)d_out);
}

// Round 9
// 947.345 us; speedup vs baseline: 1.3908x; 1.0327x over previous
//
#include <hip/hip_runtime.h>

#define N_NODES   32000
#define N_EDGES   512000
#define IN_CH     128
#define HID       256
#define HEADS     8
#define D_HEAD    32
#define N_LAYERS  4
#define N_GRAPHS  64
#define P_CHUNK   16

typedef unsigned short u16;
typedef __bf16 bf16x8 __attribute__((ext_vector_type(8)));
typedef float f32x4 __attribute__((ext_vector_type(4)));
typedef unsigned short u16x8 __attribute__((ext_vector_type(8)));

__device__ __forceinline__ u16 f2bf(float x) {
    union { float f; unsigned int u; } v; v.f = x;
    unsigned int r = v.u + 0x7FFFu + ((v.u >> 16) & 1u);  // round-to-nearest-even
    return (u16)(r >> 16);
}
__device__ __forceinline__ float bf2f(u16 b) {
    union { unsigned int u; float f; } v; v.u = ((unsigned int)b) << 16;
    return v.f;
}

// async global->LDS, 16B per lane; lds dest = wave-uniform base + lane*16
__device__ __forceinline__ void gll16(const u16* g, u16* l) {
    __builtin_amdgcn_global_load_lds(
        (const __attribute__((address_space(1))) unsigned int*)g,
        (__attribute__((address_space(3))) unsigned int*)l, 16, 0, 0);
}

// ---------------------------------------------------------------- CSR build
__global__ __launch_bounds__(256) void count_kernel(const int* __restrict__ ei,
                                                    int* __restrict__ deg) {
    int e = blockIdx.x * 256 + threadIdx.x;
    if (e < N_EDGES) atomicAdd(&deg[ei[N_EDGES + e]], 1);
}

__global__ __launch_bounds__(256) void scan_kernel(const int* __restrict__ deg,
                                                   int* __restrict__ indptr,
                                                   int* __restrict__ cursor) {
    __shared__ int wsum[4];
    __shared__ int carry_s;
    __shared__ int total_s;
    int tid = threadIdx.x;
    int lane = tid & 63, wave = tid >> 6;
    if (tid == 0) carry_s = 0;
    __syncthreads();
    for (int base = 0; base < N_NODES; base += 256) {
        int i = base + tid;
        int v = (i < N_NODES) ? deg[i] : 0;
        int x = v;
        #pragma unroll
        for (int off = 1; off < 64; off <<= 1) {
            int t = __shfl_up(x, off, 64);
            if (lane >= off) x += t;
        }
        if (lane == 63) wsum[wave] = x;
        __syncthreads();
        if (tid == 0) {
            int s = 0;
            #pragma unroll
            for (int w = 0; w < 4; ++w) { int t = wsum[w]; wsum[w] = s; s += t; }
            total_s = s;
        }
        __syncthreads();
        int excl = carry_s + wsum[wave] + x - v;
        if (i < N_NODES) { indptr[i] = excl; cursor[i] = excl; }
        __syncthreads();
        if (tid == 0) carry_s += total_s;
        __syncthreads();
    }
    if (tid == 0) indptr[N_NODES] = carry_s;
}

__global__ __launch_bounds__(256) void scatter_kernel(const int* __restrict__ ei,
                                                      int* __restrict__ cursor,
                                                      int* __restrict__ ssrc) {
    int e = blockIdx.x * 256 + threadIdx.x;
    if (e < N_EDGES) {
        int dst = ei[N_EDGES + e];
        int pos = atomicAdd(&cursor[dst], 1);
        ssrc[pos] = ei[e];
    }
}

// ---------------------------------------------------------------- conversions
__global__ __launch_bounds__(256) void tob16_kernel(const float* __restrict__ src,
                                                    u16* __restrict__ dst, int n) {
    int i = blockIdx.x * 256 + threadIdx.x;
    if (i < n) dst[i] = f2bf(src[i]);
}

// builds wcat[l][1024][256] = concat(wq,wk,wv,wskip) rows (single bf16)
__global__ __launch_bounds__(256) void wcat_kernel(const float* __restrict__ wq,
                                                   const float* __restrict__ wk,
                                                   const float* __restrict__ wv,
                                                   const float* __restrict__ ws,
                                                   u16* __restrict__ hi) {
    int i = blockIdx.x * 256 + threadIdx.x;  // 4*1024*256 = 1048576 total
    int l = i >> 18;
    int rem = i & 262143;
    int r = rem >> 8, c = rem & 255;
    int seg = r >> 8, rr = r & 255;
    const float* w = seg == 0 ? wq : seg == 1 ? wk : seg == 2 ? wv : ws;
    hi[i] = f2bf(w[(size_t)l * 65536 + rr * 256 + c]);
}

__global__ __launch_bounds__(256) void bcat_kernel(const float* __restrict__ bq,
                                                   const float* __restrict__ bk,
                                                   const float* __restrict__ bv,
                                                   const float* __restrict__ bs,
                                                   float* __restrict__ bcat) {
    int i = blockIdx.x * 256 + threadIdx.x;  // 4096
    int l = i >> 10, r = i & 1023;
    int seg = r >> 8, rr = r & 255;
    const float* b = seg == 0 ? bq : seg == 1 ? bk : seg == 2 ? bv : bs;
    bcat[i] = b[l * 256 + rr];
}

// ---------------------------------------------------------------- pe MLP stage 1
__global__ __launch_bounds__(256) void pe1_kernel(const float* __restrict__ lpe,
                                                  const float* __restrict__ w1,
                                                  const float* __restrict__ b1,
                                                  u16* __restrict__ t1b) {
    __shared__ float l[16];
    int n = blockIdx.x, j = threadIdx.x;
    if (j < 16) l[j] = lpe[n * 16 + j];
    __syncthreads();
    float s = b1[j];
    #pragma unroll
    for (int kk = 0; kk < 16; ++kk) s += l[kk] * w1[j * 16 + kk];
    t1b[(size_t)n * HID + j] = f2bf(fmaxf(s, 0.0f));
}

// ---------------------------------------------------------------- MFMA GEMM
// C[M x N] = A_bf16[M x K] @ W_bf16[N x K]^T + bias, f32 accumulate.
// BM=BN=128, BK=64, 4 waves (2x2), each wave 64x64 (4x4 frags of 16x16x32).
// LDS row-major w/ column XOR swizzle: chunk(r,kc) at index r*8+(kc^(r&7)).
// Staging via global_load_lds w16: dest lane-linear; source col permuted per lane.
// MODE 0: C0[row*256+col] = val;  MODE 1: C0 += val;
// MODE 2 (QKVS, N=1024): col<256 -> qb (bf16); 256..767 -> khv head-sliced bf16;
//                        >=768 -> skipb (f32)
template <int MODE>
__global__ __launch_bounds__(256) void mgemm(const u16* __restrict__ A,
                                             const u16* __restrict__ Wh,
                                             const float* __restrict__ bias,
                                             int K,
                                             float* __restrict__ C0,
                                             u16* __restrict__ qb,
                                             u16* __restrict__ khv,
                                             float* __restrict__ skipb) {
    __shared__ __align__(16) u16 sA[128 * 64];
    __shared__ __align__(16) u16 sWh[128 * 64];
    const int tid = threadIdx.x;
    const int l = tid & 63, wid = tid >> 6;
    const int wm = wid >> 1, wn = wid & 1;
    const int lr = l & 15, lc = l >> 4;
    const int r0 = blockIdx.x * 128;
    const int c0 = blockIdx.y * 128;

    f32x4 acc[4][4];
    #pragma unroll
    for (int m = 0; m < 4; ++m)
        #pragma unroll
        for (int n = 0; n < 4; ++n) acc[m][n] = (f32x4){0.f, 0.f, 0.f, 0.f};

    const int sr = l >> 3;                 // row within 8-row group
    const int skc = (l & 7) ^ sr;          // swizzled source column chunk
    for (int k0 = 0; k0 < K; k0 += 64) {
        #pragma unroll
        for (int j = 0; j < 4; ++j) {
            int r = j * 32 + wid * 8 + sr;
            int cb = (j * 256 + wid * 64) * 8;   // u16 idx of wave-uniform dest
            const u16* ga = A  + (size_t)(r0 + r) * K + k0 + skc * 8;
            const u16* gh = Wh + (size_t)(c0 + r) * K + k0 + skc * 8;
            gll16(ga, sA  + cb);
            gll16(gh, sWh + cb);
        }
        __syncthreads();
        #pragma unroll
        for (int kk = 0; kk < 2; ++kk) {
            const int kc = kk * 4 + lc;
            bf16x8 a[4], wh[4];
            #pragma unroll
            for (int m = 0; m < 4; ++m) {
                int r = wm * 64 + m * 16 + lr;
                a[m] = *reinterpret_cast<const bf16x8*>(
                    &sA[r * 64 + ((kc ^ (r & 7)) * 8)]);
            }
            #pragma unroll
            for (int n = 0; n < 4; ++n) {
                int r = wn * 64 + n * 16 + lr;
                wh[n] = *reinterpret_cast<const bf16x8*>(
                    &sWh[r * 64 + ((kc ^ (r & 7)) * 8)]);
            }
            #pragma unroll
            for (int m = 0; m < 4; ++m)
                #pragma unroll
                for (int n = 0; n < 4; ++n)
                    acc[m][n] = __builtin_amdgcn_mfma_f32_16x16x32_bf16(a[m], wh[n], acc[m][n], 0, 0, 0);
        }
        __syncthreads();
    }

    #pragma unroll
    for (int n = 0; n < 4; ++n) {
        int col = c0 + wn * 64 + n * 16 + lr;
        float bv = bias[col];
        #pragma unroll
        for (int m = 0; m < 4; ++m) {
            int rowb = r0 + wm * 64 + m * 16 + lc * 4;
            #pragma unroll
            for (int i = 0; i < 4; ++i) {
                float val = acc[m][n][i] + bv;
                int row = rowb + i;
                if (MODE == 0) {
                    C0[(size_t)row * 256 + col] = val;
                } else if (MODE == 1) {
                    C0[(size_t)row * 256 + col] += val;
                } else {
                    if (c0 < 256) {
                        qb[(size_t)row * 256 + col] = f2bf(val);
                    } else if (c0 < 512) {
                        int cc = col - 256, hh = cc >> 5, ch = cc & 31;
                        khv[((size_t)hh * N_NODES + row) * 64 + ch] = f2bf(val);
                    } else if (c0 < 768) {
                        int cc = col - 512, hh = cc >> 5, ch = cc & 31;
                        khv[((size_t)hh * N_NODES + row) * 64 + 32 + ch] = f2bf(val);
                    } else {
                        skipb[(size_t)row * 256 + (col - 768)] = val;
                    }
                }
            }
        }
    }
}

// ---------------------------------------------------------------- LayerNorm -> bf16
__global__ __launch_bounds__(256) void ln_kernel(const float* __restrict__ h,
                                                 const float* __restrict__ gw,
                                                 const float* __restrict__ bw,
                                                 u16* __restrict__ xnb) {
    int lane = threadIdx.x & 63, wave = threadIdx.x >> 6;
    int node = blockIdx.x * 4 + wave;
    float4 v = ((const float4*)(h + (size_t)node * HID))[lane];
    float s = v.x + v.y + v.z + v.w;
    #pragma unroll
    for (int off = 32; off; off >>= 1) s += __shfl_xor(s, off, 64);
    float mu = s * (1.0f / HID);
    float dx = v.x - mu, dy = v.y - mu, dz = v.z - mu, dw = v.w - mu;
    float q = dx * dx + dy * dy + dz * dz + dw * dw;
    #pragma unroll
    for (int off = 32; off; off >>= 1) q += __shfl_xor(q, off, 64);
    float inv = rsqrtf(q * (1.0f / HID) + 1e-5f);
    int c = lane * 4;
    float o0 = dx * inv * gw[c + 0] + bw[c + 0];
    float o1 = dy * inv * gw[c + 1] + bw[c + 1];
    float o2 = dz * inv * gw[c + 2] + bw[c + 2];
    float o3 = dw * inv * gw[c + 3] + bw[c + 3];
    uint2 pk;
    pk.x = (unsigned int)f2bf(o0) | ((unsigned int)f2bf(o1) << 16);
    pk.y = (unsigned int)f2bf(o2) | ((unsigned int)f2bf(o3) << 16);
    *reinterpret_cast<uint2*>(xnb + (size_t)node * HID + c) = pk;
}

// ---------------------------------------------------------------- fused edge attention
// one 4-lane group per (node, head); lane owns 8 channels for the whole walk.
// Chunk-4 two-bank pipeline: while computing chunk c (regs), chunk c+1's 8 kv
// loads are in flight, and indices for chunk c+2 are streaming in. Clamped
// indices + p=0 masking make the even-pair overrun exact.
__global__ __launch_bounds__(256) void agg_kernel(const u16* __restrict__ qb,
                                                  const u16* __restrict__ khv,
                                                  const int* __restrict__ indptr,
                                                  const int* __restrict__ ssrc,
                                                  float* __restrict__ outb) {
    const float scale = 0.17677669529663687f;  // 1/sqrt(32)
    const int tid = threadIdx.x;
    const int g = tid >> 2;     // group 0..63 = node within block
    const int j = tid & 3;      // channel quad (8 ch) within head
    const int h = blockIdx.x & 7;
    const int n = (blockIdx.x >> 3) * 64 + g;

    u16x8 q8 = *reinterpret_cast<const u16x8*>(qb + (size_t)n * HID + h * 32 + j * 8);
    float qv[8];
    #pragma unroll
    for (int i = 0; i < 8; ++i) qv[i] = bf2f(q8[i]) * scale;

    const int s0 = indptr[n], s1 = indptr[n + 1];
    const int last = s1 - 1;
    const u16* base = khv + (size_t)h * N_NODES * 64 + j * 8;
    float acc[8] = {0.f, 0.f, 0.f, 0.f, 0.f, 0.f, 0.f, 0.f};
    float ssum = 0.f;

    if (s0 < s1) {
        const int nchunk = (s1 - s0 + 3) >> 2;
        const int npair = (nchunk + 1) >> 1;
        int iA[4], iB[4], iC[4];
        u16x8 kA[4], vA[4], kB[4], vB[4];
        #pragma unroll
        for (int i = 0; i < 4; ++i) {
            int e = s0 + i;
            iA[i] = __builtin_nontemporal_load(&ssrc[e > last ? last : e]);
        }
        #pragma unroll
        for (int i = 0; i < 4; ++i) {
            const u16* rp = base + (size_t)iA[i] * 64;
            kA[i] = *reinterpret_cast<const u16x8*>(rp);
            vA[i] = *reinterpret_cast<const u16x8*>(rp + 32);
        }
        #pragma unroll
        for (int i = 0; i < 4; ++i) {
            int e = s0 + 4 + i;
            iB[i] = __builtin_nontemporal_load(&ssrc[e > last ? last : e]);
        }
        int eb = s0;
        for (int pc = 0; pc < npair; ++pc) {
            // even phase: issue kvB (from iB), stream iC (chunk+2), compute A
            #pragma unroll
            for (int i = 0; i < 4; ++i) {
                const u16* rp = base + (size_t)iB[i] * 64;
                kB[i] = *reinterpret_cast<const u16x8*>(rp);
                vB[i] = *reinterpret_cast<const u16x8*>(rp + 32);
            }
            #pragma unroll
            for (int i = 0; i < 4; ++i) {
                int e = eb + 8 + i;
                iC[i] = __builtin_nontemporal_load(&ssrc[e > last ? last : e]);
            }
            #pragma unroll
            for (int i = 0; i < 4; ++i) {
                float prod = 0.f;
                #pragma unroll
                for (int t = 0; t < 8; ++t) prod += qv[t] * bf2f(kA[i][t]);
                prod += __shfl_xor(prod, 1, 64);
                prod += __shfl_xor(prod, 2, 64);
                float p = (eb + i <= last) ? __expf(prod) : 0.f;
                ssum += p;
                #pragma unroll
                for (int t = 0; t < 8; ++t) acc[t] += p * bf2f(vA[i][t]);
            }
            eb += 4;
            // odd phase: issue kvA (from iC), stream iB (chunk+2), compute B
            #pragma unroll
            for (int i = 0; i < 4; ++i) {
                const u16* rp = base + (size_t)iC[i] * 64;
                kA[i] = *reinterpret_cast<const u16x8*>(rp);
                vA[i] = *reinterpret_cast<const u16x8*>(rp + 32);
            }
            #pragma unroll
            for (int i = 0; i < 4; ++i) {
                int e = eb + 8 + i;
                iB[i] = __builtin_nontemporal_load(&ssrc[e > last ? last : e]);
            }
            #pragma unroll
            for (int i = 0; i < 4; ++i) {
                float prod = 0.f;
                #pragma unroll
                for (int t = 0; t < 8; ++t) prod += qv[t] * bf2f(kB[i][t]);
                prod += __shfl_xor(prod, 1, 64);
                prod += __shfl_xor(prod, 2, 64);
                float p = (eb + i <= last) ? __expf(prod) : 0.f;
                ssum += p;
                #pragma unroll
                for (int t = 0; t < 8; ++t) acc[t] += p * bf2f(vB[i][t]);
            }
            eb += 4;
        }
    }

    float inv = 1.0f / fmaxf(ssum, 1e-16f);
    float* op = outb + (size_t)n * HID + h * 32 + j * 8;
    f32x4 o0 = {acc[0] * inv, acc[1] * inv, acc[2] * inv, acc[3] * inv};
    f32x4 o1 = {acc[4] * inv, acc[5] * inv, acc[6] * inv, acc[7] * inv};
    __builtin_nontemporal_store(o0, (f32x4*)op);
    __builtin_nontemporal_store(o1, (f32x4*)(op + 4));
}

// ------------------------------------------- beta gate + relu + residual (+ next LN)
template <bool DO_LN>
__global__ __launch_bounds__(256) void beta_kernel(const float* __restrict__ outb,
                                                   const float* __restrict__ skipb,
                                                   const float* __restrict__ wb,
                                                   const float* __restrict__ gw,
                                                   const float* __restrict__ bw,
                                                   float* __restrict__ h,
                                                   u16* __restrict__ xnb) {
    int lane = threadIdx.x & 63, wave = threadIdx.x >> 6;
    int node = blockIdx.x * 4 + wave;
    int c = lane * 4;
    float4 o  = ((const float4*)(outb  + (size_t)node * HID))[lane];
    float4 sk = ((const float4*)(skipb + (size_t)node * HID))[lane];
    float acc = o.x * wb[c + 0] + o.y * wb[c + 1] + o.z * wb[c + 2] + o.w * wb[c + 3]
              + sk.x * wb[HID + c + 0] + sk.y * wb[HID + c + 1]
              + sk.z * wb[HID + c + 2] + sk.w * wb[HID + c + 3]
              + (o.x - sk.x) * wb[2 * HID + c + 0] + (o.y - sk.y) * wb[2 * HID + c + 1]
              + (o.z - sk.z) * wb[2 * HID + c + 2] + (o.w - sk.w) * wb[2 * HID + c + 3];
    #pragma unroll
    for (int off = 32; off; off >>= 1) acc += __shfl_xor(acc, off, 64);
    float beta = 1.0f / (1.0f + __expf(-acc));
    float4 r = ((const float4*)(h + (size_t)node * HID))[lane];
    float4 out;
    out.x = fmaxf(beta * sk.x + (1.0f - beta) * o.x, 0.0f) + r.x;
    out.y = fmaxf(beta * sk.y + (1.0f - beta) * o.y, 0.0f) + r.y;
    out.z = fmaxf(beta * sk.z + (1.0f - beta) * o.z, 0.0f) + r.z;
    out.w = fmaxf(beta * sk.w + (1.0f - beta) * o.w, 0.0f) + r.w;
    ((float4*)(h + (size_t)node * HID))[lane] = out;

    if (DO_LN) {
        float s = out.x + out.y + out.z + out.w;
        #pragma unroll
        for (int off = 32; off; off >>= 1) s += __shfl_xor(s, off, 64);
        float mu = s * (1.0f / HID);
        float dx = out.x - mu, dy = out.y - mu, dz = out.z - mu, dw = out.w - mu;
        float qq = dx * dx + dy * dy + dz * dz + dw * dw;
        #pragma unroll
        for (int off = 32; off; off >>= 1) qq += __shfl_xor(qq, off, 64);
        float inv = rsqrtf(qq * (1.0f / HID) + 1e-5f);
        float o0 = dx * inv * gw[c + 0] + bw[c + 0];
        float o1 = dy * inv * gw[c + 1] + bw[c + 1];
        float o2 = dz * inv * gw[c + 2] + bw[c + 2];
        float o3 = dw * inv * gw[c + 3] + bw[c + 3];
        uint2 pk;
        pk.x = (unsigned int)f2bf(o0) | ((unsigned int)f2bf(o1) << 16);
        pk.y = (unsigned int)f2bf(o2) | ((unsigned int)f2bf(o3) << 16);
        *reinterpret_cast<uint2*>(xnb + (size_t)node * HID + c) = pk;
    }
}

// ---------------------------------------------------------------- pooling + final MLP
__global__ __launch_bounds__(128) void bounds_kernel(const int* __restrict__ batch,
                                                     int* __restrict__ gstart) {
    int g = threadIdx.x;
    if (g > N_GRAPHS) return;
    int lo = 0, hi = N_NODES;
    while (lo < hi) { int mid = (lo + hi) >> 1; if (batch[mid] < g) lo = mid + 1; else hi = mid; }
    gstart[g] = lo;
}

// stage 1: 16 chunks per graph, deterministic partials pxg[g][chunk][256]
__global__ __launch_bounds__(256) void pool_kernel(const float* __restrict__ h,
                                                   const int* __restrict__ gstart,
                                                   float* __restrict__ pxg) {
    int gb = blockIdx.x;                 // 0 .. N_GRAPHS*P_CHUNK-1
    int g = gb >> 4, cch = gb & (P_CHUNK - 1);
    int t = threadIdx.x;
    int s = gstart[g], e = gstart[g + 1];
    float acc = 0.0f;
    for (int i = s + cch; i < e; i += P_CHUNK)
        acc += __builtin_nontemporal_load(&h[(size_t)i * HID + t]);
    pxg[(size_t)gb * HID + t] = acc;
}

__global__ __launch_bounds__(256) void mlp_kernel(const float* __restrict__ pxg,
                                                  const int* __restrict__ gstart,
                                                  const float* __restrict__ w1,
                                                  const float* __restrict__ b1,
                                                  const float* __restrict__ w2,
                                                  const float* __restrict__ b2,
                                                  float* __restrict__ out) {
    __shared__ float xr[256];
    __shared__ float red[256];
    int g = blockIdx.x, t = threadIdx.x;
    float sum = 0.0f;
    #pragma unroll
    for (int c = 0; c < P_CHUNK; ++c)
        sum += pxg[((size_t)g * P_CHUNK + c) * HID + t];
    float cnt = (float)(gstart[g + 1] - gstart[g]);
    xr[t] = sum / fmaxf(cnt, 1.0f);
    __syncthreads();
    float s = b1[t];
    #pragma unroll 4
    for (int kk = 0; kk < 256; ++kk) s += xr[kk] * w1[t * 256 + kk];
    s = fmaxf(s, 0.0f);
    red[t] = s * w2[t];
    __syncthreads();
    for (int off = 128; off; off >>= 1) {
        if (t < off) red[t] += red[t + off];
        __syncthreads();
    }
    if (t == 0) out[g] = red[0] + b2[0];
}

// ---------------------------------------------------------------- host
extern "C" void kernel_launch(void* const* d_in, const int* in_sizes, int n_in,
                              void* d_out, int out_size, void* d_ws, size_t ws_size,
                              hipStream_t stream) {
    const float* x      = (const float*)d_in[0];
    const float* lpe    = (const float*)d_in[1];
    const float* pe_w1  = (const float*)d_in[2];
    const float* pe_b1  = (const float*)d_in[3];
    const float* pe_w2  = (const float*)d_in[4];
    const float* pe_b2  = (const float*)d_in[5];
    const float* emb_w  = (const float*)d_in[6];
    const float* emb_b  = (const float*)d_in[7];
    const float* ln_g   = (const float*)d_in[8];
    const float* ln_b   = (const float*)d_in[9];
    const float* wq     = (const float*)d_in[10];
    const float* bq     = (const float*)d_in[11];
    const float* wk     = (const float*)d_in[12];
    const float* bk     = (const float*)d_in[13];
    const float* wv     = (const float*)d_in[14];
    const float* bv     = (const float*)d_in[15];
    const float* wskip  = (const float*)d_in[16];
    const float* bskip  = (const float*)d_in[17];
    const float* wbeta  = (const float*)d_in[18];
    const float* mlp_w1 = (const float*)d_in[19];
    const float* mlp_b1 = (const float*)d_in[20];
    const float* mlp_w2 = (const float*)d_in[21];
    const float* mlp_b2 = (const float*)d_in[22];
    const int*   eidx   = (const int*)d_in[23];
    const int*   batch  = (const int*)d_in[24];

    char* w = (char*)d_ws;
    const size_t NH = (size_t)N_NODES * HID;
    float* h     = (float*)w;           w += NH * 4;
    float* skipb = (float*)w;           w += NH * 4;
    float* outb  = (float*)w;           w += NH * 4;
    float* pxg   = (float*)w;           w += (size_t)N_GRAPHS * P_CHUNK * HID * 4;
    u16* qb      = (u16*)w;             w += NH * 2;
    u16* xnb     = (u16*)w;             w += NH * 2;
    u16* khv     = (u16*)w;             w += (size_t)HEADS * N_NODES * 64 * 2;
    u16* xb      = (u16*)w;             w += (size_t)N_NODES * IN_CH * 2;
    u16* t1b     = (u16*)w;             w += NH * 2;
    u16* ehi     = (u16*)w;             w += 32768 * 2;
    u16* p2hi    = (u16*)w;             w += 65536 * 2;
    u16* wchi    = (u16*)w;             w += 1048576 * 2;
    float* bcat  = (float*)w;           w += 4096 * 4;
    int* deg     = (int*)w;             w += N_NODES * 4;
    int* indptr  = (int*)w;             w += (N_NODES + 1) * 4;
    int* cursor  = (int*)w;             w += N_NODES * 4;
    int* ssrc    = (int*)w;             w += N_EDGES * 4;
    int* gstart  = (int*)w;             w += (N_GRAPHS + 1) * 4;

    // weight conversions (every call; deterministic)
    tob16_kernel<<<128, 256, 0, stream>>>(emb_w, ehi, 32768);
    tob16_kernel<<<256, 256, 0, stream>>>(pe_w2, p2hi, 65536);
    wcat_kernel<<<4096, 256, 0, stream>>>(wq, wk, wv, wskip, wchi);
    bcat_kernel<<<16, 256, 0, stream>>>(bq, bk, bv, bskip, bcat);
    tob16_kernel<<<16000, 256, 0, stream>>>(x, xb, N_NODES * IN_CH);

    // CSR by destination
    hipMemsetAsync(deg, 0, N_NODES * sizeof(int), stream);
    count_kernel<<<(N_EDGES + 255) / 256, 256, 0, stream>>>(eidx, deg);
    scan_kernel<<<1, 256, 0, stream>>>(deg, indptr, cursor);
    scatter_kernel<<<(N_EDGES + 255) / 256, 256, 0, stream>>>(eidx, cursor, ssrc);

    // h = x@emb_w^T + emb_b + pe_mlp(lpe)
    pe1_kernel<<<N_NODES, 256, 0, stream>>>(lpe, pe_w1, pe_b1, t1b);
    mgemm<0><<<dim3(250, 2), 256, 0, stream>>>(xb, ehi, emb_b, IN_CH, h, nullptr, nullptr, nullptr);
    mgemm<1><<<dim3(250, 2), 256, 0, stream>>>(t1b, p2hi, pe_b2, HID, h, nullptr, nullptr, nullptr);

    ln_kernel<<<N_NODES / 4, 256, 0, stream>>>(h, ln_g, ln_b, xnb);
    for (int l = 0; l < N_LAYERS; ++l) {
        mgemm<2><<<dim3(250, 8), 256, 0, stream>>>(xnb, wchi + (size_t)l * 262144,
                                                   bcat + l * 1024, HID,
                                                   nullptr, qb, khv, skipb);
        agg_kernel<<<(N_NODES / 64) * 8, 256, 0, stream>>>(qb, khv, indptr, ssrc, outb);
        if (l < N_LAYERS - 1) {
            beta_kernel<true><<<N_NODES / 4, 256, 0, stream>>>(
                outb, skipb, wbeta + l * 3 * HID,
                ln_g + (l + 1) * HID, ln_b + (l + 1) * HID, h, xnb);
        } else {
            beta_kernel<false><<<N_NODES / 4, 256, 0, stream>>>(
                outb, skipb, wbeta + l * 3 * HID, nullptr, nullptr, h, nullptr);
        }
    }

    bounds_kernel<<<1, 128, 0, stream>>>(batch, gstart);
    pool_kernel<<<N_GRAPHS * P_CHUNK, 256, 0, stream>>>(h, gstart, pxg);
    mlp_kernel<<<N_GRAPHS, 256, 0, stream>>>(pxg, gstart, mlp_w1, mlp_b1, mlp_w2, mlp_b2, (float*)d_out);
}

// Round 10
// 808.595 us; speedup vs baseline: 1.6295x; 1.1716x over previous
//
#include <hip/hip_runtime.h>

#define N_NODES   32000
#define N_EDGES   512000
#define IN_CH     128
#define HID       256
#define HEADS     8
#define D_HEAD    32
#define N_LAYERS  4
#define N_GRAPHS  64
#define P_CHUNK   16
#define MAX_SIDX  2048

typedef unsigned short u16;
typedef __bf16 bf16x8 __attribute__((ext_vector_type(8)));
typedef float f32x4 __attribute__((ext_vector_type(4)));
typedef unsigned short u16x8 __attribute__((ext_vector_type(8)));

__device__ __forceinline__ u16 f2bf(float x) {
    union { float f; unsigned int u; } v; v.f = x;
    unsigned int r = v.u + 0x7FFFu + ((v.u >> 16) & 1u);  // round-to-nearest-even
    return (u16)(r >> 16);
}
__device__ __forceinline__ float bf2f(u16 b) {
    union { unsigned int u; float f; } v; v.u = ((unsigned int)b) << 16;
    return v.f;
}

// async global->LDS, 16B per lane; lds dest = wave-uniform base + lane*16
__device__ __forceinline__ void gll16(const u16* g, u16* l) {
    __builtin_amdgcn_global_load_lds(
        (const __attribute__((address_space(1))) unsigned int*)g,
        (__attribute__((address_space(3))) unsigned int*)l, 16, 0, 0);
}

// ---------------------------------------------------------------- CSR build
__global__ __launch_bounds__(256) void count_kernel(const int* __restrict__ ei,
                                                    int* __restrict__ deg) {
    int e = blockIdx.x * 256 + threadIdx.x;
    if (e < N_EDGES) atomicAdd(&deg[ei[N_EDGES + e]], 1);
}

__global__ __launch_bounds__(256) void scan_kernel(const int* __restrict__ deg,
                                                   int* __restrict__ indptr,
                                                   int* __restrict__ cursor) {
    __shared__ int wsum[4];
    __shared__ int carry_s;
    __shared__ int total_s;
    int tid = threadIdx.x;
    int lane = tid & 63, wave = tid >> 6;
    if (tid == 0) carry_s = 0;
    __syncthreads();
    for (int base = 0; base < N_NODES; base += 256) {
        int i = base + tid;
        int v = (i < N_NODES) ? deg[i] : 0;
        int x = v;
        #pragma unroll
        for (int off = 1; off < 64; off <<= 1) {
            int t = __shfl_up(x, off, 64);
            if (lane >= off) x += t;
        }
        if (lane == 63) wsum[wave] = x;
        __syncthreads();
        if (tid == 0) {
            int s = 0;
            #pragma unroll
            for (int w = 0; w < 4; ++w) { int t = wsum[w]; wsum[w] = s; s += t; }
            total_s = s;
        }
        __syncthreads();
        int excl = carry_s + wsum[wave] + x - v;
        if (i < N_NODES) { indptr[i] = excl; cursor[i] = excl; }
        __syncthreads();
        if (tid == 0) carry_s += total_s;
        __syncthreads();
    }
    if (tid == 0) indptr[N_NODES] = carry_s;
}

__global__ __launch_bounds__(256) void scatter_kernel(const int* __restrict__ ei,
                                                      int* __restrict__ cursor,
                                                      int* __restrict__ ssrc) {
    int e = blockIdx.x * 256 + threadIdx.x;
    if (e < N_EDGES) {
        int dst = ei[N_EDGES + e];
        int pos = atomicAdd(&cursor[dst], 1);
        ssrc[pos] = ei[e];
    }
}

// ---------------------------------------------------------------- conversions
__global__ __launch_bounds__(256) void tob16_kernel(const float* __restrict__ src,
                                                    u16* __restrict__ dst, int n) {
    int i = blockIdx.x * 256 + threadIdx.x;
    if (i < n) dst[i] = f2bf(src[i]);
}

// builds wcat[l][1024][256] = concat(wq,wk,wv,wskip) rows (single bf16)
__global__ __launch_bounds__(256) void wcat_kernel(const float* __restrict__ wq,
                                                   const float* __restrict__ wk,
                                                   const float* __restrict__ wv,
                                                   const float* __restrict__ ws,
                                                   u16* __restrict__ hi) {
    int i = blockIdx.x * 256 + threadIdx.x;  // 4*1024*256 = 1048576 total
    int l = i >> 18;
    int rem = i & 262143;
    int r = rem >> 8, c = rem & 255;
    int seg = r >> 8, rr = r & 255;
    const float* w = seg == 0 ? wq : seg == 1 ? wk : seg == 2 ? wv : ws;
    hi[i] = f2bf(w[(size_t)l * 65536 + rr * 256 + c]);
}

__global__ __launch_bounds__(256) void bcat_kernel(const float* __restrict__ bq,
                                                   const float* __restrict__ bk,
                                                   const float* __restrict__ bv,
                                                   const float* __restrict__ bs,
                                                   float* __restrict__ bcat) {
    int i = blockIdx.x * 256 + threadIdx.x;  // 4096
    int l = i >> 10, r = i & 1023;
    int seg = r >> 8, rr = r & 255;
    const float* b = seg == 0 ? bq : seg == 1 ? bk : seg == 2 ? bv : bs;
    bcat[i] = b[l * 256 + rr];
}

// ---------------------------------------------------------------- pe MLP stage 1
__global__ __launch_bounds__(256) void pe1_kernel(const float* __restrict__ lpe,
                                                  const float* __restrict__ w1,
                                                  const float* __restrict__ b1,
                                                  u16* __restrict__ t1b) {
    __shared__ float l[16];
    int n = blockIdx.x, j = threadIdx.x;
    if (j < 16) l[j] = lpe[n * 16 + j];
    __syncthreads();
    float s = b1[j];
    #pragma unroll
    for (int kk = 0; kk < 16; ++kk) s += l[kk] * w1[j * 16 + kk];
    t1b[(size_t)n * HID + j] = f2bf(fmaxf(s, 0.0f));
}

// ---------------------------------------------------------------- MFMA GEMM
// C[M x N] = A_bf16[M x K] @ W_bf16[N x K]^T + bias, f32 accumulate.
// BM=BN=128, BK=64, 4 waves (2x2), each wave 64x64 (4x4 frags of 16x16x32).
// LDS row-major w/ column XOR swizzle: chunk(r,kc) at index r*8+(kc^(r&7)).
// Staging via global_load_lds w16: dest lane-linear; source col permuted per lane.
// MODE 0: C0[row*256+col] = val;  MODE 1: C0 += val;
// MODE 2 (QKVS, N=1024): col<256 -> qb (bf16); 256..767 -> khv head-sliced bf16;
//                        >=768 -> skipb (f32)
template <int MODE>
__global__ __launch_bounds__(256) void mgemm(const u16* __restrict__ A,
                                             const u16* __restrict__ Wh,
                                             const float* __restrict__ bias,
                                             int K,
                                             float* __restrict__ C0,
                                             u16* __restrict__ qb,
                                             u16* __restrict__ khv,
                                             float* __restrict__ skipb) {
    __shared__ __align__(16) u16 sA[128 * 64];
    __shared__ __align__(16) u16 sWh[128 * 64];
    const int tid = threadIdx.x;
    const int l = tid & 63, wid = tid >> 6;
    const int wm = wid >> 1, wn = wid & 1;
    const int lr = l & 15, lc = l >> 4;
    const int r0 = blockIdx.x * 128;
    const int c0 = blockIdx.y * 128;

    f32x4 acc[4][4];
    #pragma unroll
    for (int m = 0; m < 4; ++m)
        #pragma unroll
        for (int n = 0; n < 4; ++n) acc[m][n] = (f32x4){0.f, 0.f, 0.f, 0.f};

    const int sr = l >> 3;                 // row within 8-row group
    const int skc = (l & 7) ^ sr;          // swizzled source column chunk
    for (int k0 = 0; k0 < K; k0 += 64) {
        #pragma unroll
        for (int j = 0; j < 4; ++j) {
            int r = j * 32 + wid * 8 + sr;
            int cb = (j * 256 + wid * 64) * 8;   // u16 idx of wave-uniform dest
            const u16* ga = A  + (size_t)(r0 + r) * K + k0 + skc * 8;
            const u16* gh = Wh + (size_t)(c0 + r) * K + k0 + skc * 8;
            gll16(ga, sA  + cb);
            gll16(gh, sWh + cb);
        }
        __syncthreads();
        #pragma unroll
        for (int kk = 0; kk < 2; ++kk) {
            const int kc = kk * 4 + lc;
            bf16x8 a[4], wh[4];
            #pragma unroll
            for (int m = 0; m < 4; ++m) {
                int r = wm * 64 + m * 16 + lr;
                a[m] = *reinterpret_cast<const bf16x8*>(
                    &sA[r * 64 + ((kc ^ (r & 7)) * 8)]);
            }
            #pragma unroll
            for (int n = 0; n < 4; ++n) {
                int r = wn * 64 + n * 16 + lr;
                wh[n] = *reinterpret_cast<const bf16x8*>(
                    &sWh[r * 64 + ((kc ^ (r & 7)) * 8)]);
            }
            #pragma unroll
            for (int m = 0; m < 4; ++m)
                #pragma unroll
                for (int n = 0; n < 4; ++n)
                    acc[m][n] = __builtin_amdgcn_mfma_f32_16x16x32_bf16(a[m], wh[n], acc[m][n], 0, 0, 0);
        }
        __syncthreads();
    }

    #pragma unroll
    for (int n = 0; n < 4; ++n) {
        int col = c0 + wn * 64 + n * 16 + lr;
        float bv = bias[col];
        #pragma unroll
        for (int m = 0; m < 4; ++m) {
            int rowb = r0 + wm * 64 + m * 16 + lc * 4;
            #pragma unroll
            for (int i = 0; i < 4; ++i) {
                float val = acc[m][n][i] + bv;
                int row = rowb + i;
                if (MODE == 0) {
                    C0[(size_t)row * 256 + col] = val;
                } else if (MODE == 1) {
                    C0[(size_t)row * 256 + col] += val;
                } else {
                    if (c0 < 256) {
                        qb[(size_t)row * 256 + col] = f2bf(val);
                    } else if (c0 < 512) {
                        int cc = col - 256, hh = cc >> 5, ch = cc & 31;
                        khv[((size_t)hh * N_NODES + row) * 64 + ch] = f2bf(val);
                    } else if (c0 < 768) {
                        int cc = col - 512, hh = cc >> 5, ch = cc & 31;
                        khv[((size_t)hh * N_NODES + row) * 64 + 32 + ch] = f2bf(val);
                    } else {
                        skipb[(size_t)row * 256 + (col - 768)] = val;
                    }
                }
            }
        }
    }
}

// ---------------------------------------------------------------- LayerNorm -> bf16
__global__ __launch_bounds__(256) void ln_kernel(const float* __restrict__ h,
                                                 const float* __restrict__ gw,
                                                 const float* __restrict__ bw,
                                                 u16* __restrict__ xnb) {
    int lane = threadIdx.x & 63, wave = threadIdx.x >> 6;
    int node = blockIdx.x * 4 + wave;
    float4 v = ((const float4*)(h + (size_t)node * HID))[lane];
    float s = v.x + v.y + v.z + v.w;
    #pragma unroll
    for (int off = 32; off; off >>= 1) s += __shfl_xor(s, off, 64);
    float mu = s * (1.0f / HID);
    float dx = v.x - mu, dy = v.y - mu, dz = v.z - mu, dw = v.w - mu;
    float q = dx * dx + dy * dy + dz * dz + dw * dw;
    #pragma unroll
    for (int off = 32; off; off >>= 1) q += __shfl_xor(q, off, 64);
    float inv = rsqrtf(q * (1.0f / HID) + 1e-5f);
    int c = lane * 4;
    float o0 = dx * inv * gw[c + 0] + bw[c + 0];
    float o1 = dy * inv * gw[c + 1] + bw[c + 1];
    float o2 = dz * inv * gw[c + 2] + bw[c + 2];
    float o3 = dw * inv * gw[c + 3] + bw[c + 3];
    uint2 pk;
    pk.x = (unsigned int)f2bf(o0) | ((unsigned int)f2bf(o1) << 16);
    pk.y = (unsigned int)f2bf(o2) | ((unsigned int)f2bf(o3) << 16);
    *reinterpret_cast<uint2*>(xnb + (size_t)node * HID + c) = pk;
}

// ---------------------------------------------------------------- fused edge attention
// one 4-lane group per (node, head); lane owns 8 channels for the whole walk.
// Edge indices for the block's 64 nodes are CONTIGUOUS in ssrc (CSR) -> staged
// into LDS once per block (coalesced); pipeline fetches indices at LDS latency
// (broadcast within group, no conflicts). Two-bank chunk-4 kv pipeline as before.
__global__ __launch_bounds__(256) void agg_kernel(const u16* __restrict__ qb,
                                                  const u16* __restrict__ khv,
                                                  const int* __restrict__ indptr,
                                                  const int* __restrict__ ssrc,
                                                  float* __restrict__ outb) {
    __shared__ int sIdx[MAX_SIDX];
    const float scale = 0.17677669529663687f;  // 1/sqrt(32)
    const int tid = threadIdx.x;
    const int g = tid >> 2;     // group 0..63 = node within block
    const int j = tid & 3;      // channel quad (8 ch) within head
    const int h = blockIdx.x & 7;
    const int nb = (blockIdx.x >> 3) * 64;
    const int n = nb + g;

    // stage the block's contiguous edge-index range into LDS
    const int b0 = indptr[nb];
    const int bcnt = indptr[nb + 64] - b0;
    const int cap = bcnt < MAX_SIDX ? bcnt : MAX_SIDX;
    for (int i = tid; i < cap; i += 256) sIdx[i] = ssrc[b0 + i];
    __syncthreads();

    u16x8 q8 = *reinterpret_cast<const u16x8*>(qb + (size_t)n * HID + h * 32 + j * 8);
    float qv[8];
    #pragma unroll
    for (int i = 0; i < 8; ++i) qv[i] = bf2f(q8[i]) * scale;

    const int s0 = indptr[n], s1 = indptr[n + 1];
    const int last = s1 - 1;
    const u16* base = khv + (size_t)h * N_NODES * 64 + j * 8;
    float acc[8] = {0.f, 0.f, 0.f, 0.f, 0.f, 0.f, 0.f, 0.f};
    float ssum = 0.f;

    if (s0 < s1) {
        const int nchunk = (s1 - s0 + 3) >> 2;
        const int npair = (nchunk + 1) >> 1;
        int iA[4], iB[4];
        u16x8 kA[4], vA[4], kB[4], vB[4];
        // index fetch: LDS fast path, global fallback if block range overflowed
        #define LDIDX(e_, dst_) { int e2 = (e_) > last ? last : (e_); \
            int off = e2 - b0; \
            dst_ = (off < cap) ? sIdx[off] : ssrc[e2]; }
        #pragma unroll
        for (int i = 0; i < 4; ++i) LDIDX(s0 + i, iA[i]);
        #pragma unroll
        for (int i = 0; i < 4; ++i) {
            const u16* rp = base + (size_t)iA[i] * 64;
            kA[i] = *reinterpret_cast<const u16x8*>(rp);
            vA[i] = *reinterpret_cast<const u16x8*>(rp + 32);
        }
        #pragma unroll
        for (int i = 0; i < 4; ++i) LDIDX(s0 + 4 + i, iB[i]);
        int eb = s0;
        for (int pc = 0; pc < npair; ++pc) {
            // even phase: issue kvB (from iB), compute A, fetch iA for chunk+2
            #pragma unroll
            for (int i = 0; i < 4; ++i) {
                const u16* rp = base + (size_t)iB[i] * 64;
                kB[i] = *reinterpret_cast<const u16x8*>(rp);
                vB[i] = *reinterpret_cast<const u16x8*>(rp + 32);
            }
            #pragma unroll
            for (int i = 0; i < 4; ++i) {
                float prod = 0.f;
                #pragma unroll
                for (int t = 0; t < 8; ++t) prod += qv[t] * bf2f(kA[i][t]);
                prod += __shfl_xor(prod, 1, 64);
                prod += __shfl_xor(prod, 2, 64);
                float p = (eb + i <= last) ? __expf(prod) : 0.f;
                ssum += p;
                #pragma unroll
                for (int t = 0; t < 8; ++t) acc[t] += p * bf2f(vA[i][t]);
            }
            eb += 4;
            #pragma unroll
            for (int i = 0; i < 4; ++i) LDIDX(eb + 4 + i, iA[i]);
            // odd phase: issue kvA (from iA), compute B, fetch iB for chunk+2
            #pragma unroll
            for (int i = 0; i < 4; ++i) {
                const u16* rp = base + (size_t)iA[i] * 64;
                kA[i] = *reinterpret_cast<const u16x8*>(rp);
                vA[i] = *reinterpret_cast<const u16x8*>(rp + 32);
            }
            #pragma unroll
            for (int i = 0; i < 4; ++i) {
                float prod = 0.f;
                #pragma unroll
                for (int t = 0; t < 8; ++t) prod += qv[t] * bf2f(kB[i][t]);
                prod += __shfl_xor(prod, 1, 64);
                prod += __shfl_xor(prod, 2, 64);
                float p = (eb + i <= last) ? __expf(prod) : 0.f;
                ssum += p;
                #pragma unroll
                for (int t = 0; t < 8; ++t) acc[t] += p * bf2f(vB[i][t]);
            }
            eb += 4;
            #pragma unroll
            for (int i = 0; i < 4; ++i) LDIDX(eb + 4 + i, iB[i]);
        }
        #undef LDIDX
    }

    float inv = 1.0f / fmaxf(ssum, 1e-16f);
    float* op = outb + (size_t)n * HID + h * 32 + j * 8;
    f32x4 o0 = {acc[0] * inv, acc[1] * inv, acc[2] * inv, acc[3] * inv};
    f32x4 o1 = {acc[4] * inv, acc[5] * inv, acc[6] * inv, acc[7] * inv};
    __builtin_nontemporal_store(o0, (f32x4*)op);
    __builtin_nontemporal_store(o1, (f32x4*)(op + 4));
}

// ------------------------------------------- beta gate + relu + residual (+ next LN)
template <bool DO_LN>
__global__ __launch_bounds__(256) void beta_kernel(const float* __restrict__ outb,
                                                   const float* __restrict__ skipb,
                                                   const float* __restrict__ wb,
                                                   const float* __restrict__ gw,
                                                   const float* __restrict__ bw,
                                                   float* __restrict__ h,
                                                   u16* __restrict__ xnb) {
    int lane = threadIdx.x & 63, wave = threadIdx.x >> 6;
    int node = blockIdx.x * 4 + wave;
    int c = lane * 4;
    float4 o  = ((const float4*)(outb  + (size_t)node * HID))[lane];
    float4 sk = ((const float4*)(skipb + (size_t)node * HID))[lane];
    float acc = o.x * wb[c + 0] + o.y * wb[c + 1] + o.z * wb[c + 2] + o.w * wb[c + 3]
              + sk.x * wb[HID + c + 0] + sk.y * wb[HID + c + 1]
              + sk.z * wb[HID + c + 2] + sk.w * wb[HID + c + 3]
              + (o.x - sk.x) * wb[2 * HID + c + 0] + (o.y - sk.y) * wb[2 * HID + c + 1]
              + (o.z - sk.z) * wb[2 * HID + c + 2] + (o.w - sk.w) * wb[2 * HID + c + 3];
    #pragma unroll
    for (int off = 32; off; off >>= 1) acc += __shfl_xor(acc, off, 64);
    float beta = 1.0f / (1.0f + __expf(-acc));
    float4 r = ((const float4*)(h + (size_t)node * HID))[lane];
    float4 out;
    out.x = fmaxf(beta * sk.x + (1.0f - beta) * o.x, 0.0f) + r.x;
    out.y = fmaxf(beta * sk.y + (1.0f - beta) * o.y, 0.0f) + r.y;
    out.z = fmaxf(beta * sk.z + (1.0f - beta) * o.z, 0.0f) + r.z;
    out.w = fmaxf(beta * sk.w + (1.0f - beta) * o.w, 0.0f) + r.w;
    ((float4*)(h + (size_t)node * HID))[lane] = out;

    if (DO_LN) {
        float s = out.x + out.y + out.z + out.w;
        #pragma unroll
        for (int off = 32; off; off >>= 1) s += __shfl_xor(s, off, 64);
        float mu = s * (1.0f / HID);
        float dx = out.x - mu, dy = out.y - mu, dz = out.z - mu, dw = out.w - mu;
        float qq = dx * dx + dy * dy + dz * dz + dw * dw;
        #pragma unroll
        for (int off = 32; off; off >>= 1) qq += __shfl_xor(qq, off, 64);
        float inv = rsqrtf(qq * (1.0f / HID) + 1e-5f);
        float o0 = dx * inv * gw[c + 0] + bw[c + 0];
        float o1 = dy * inv * gw[c + 1] + bw[c + 1];
        float o2 = dz * inv * gw[c + 2] + bw[c + 2];
        float o3 = dw * inv * gw[c + 3] + bw[c + 3];
        uint2 pk;
        pk.x = (unsigned int)f2bf(o0) | ((unsigned int)f2bf(o1) << 16);
        pk.y = (unsigned int)f2bf(o2) | ((unsigned int)f2bf(o3) << 16);
        *reinterpret_cast<uint2*>(xnb + (size_t)node * HID + c) = pk;
    }
}

// ---------------------------------------------------------------- pooling + final MLP
__global__ __launch_bounds__(128) void bounds_kernel(const int* __restrict__ batch,
                                                     int* __restrict__ gstart) {
    int g = threadIdx.x;
    if (g > N_GRAPHS) return;
    int lo = 0, hi = N_NODES;
    while (lo < hi) { int mid = (lo + hi) >> 1; if (batch[mid] < g) lo = mid + 1; else hi = mid; }
    gstart[g] = lo;
}

// stage 1: 16 chunks per graph, deterministic partials pxg[g][chunk][256]
__global__ __launch_bounds__(256) void pool_kernel(const float* __restrict__ h,
                                                   const int* __restrict__ gstart,
                                                   float* __restrict__ pxg) {
    int gb = blockIdx.x;                 // 0 .. N_GRAPHS*P_CHUNK-1
    int g = gb >> 4, cch = gb & (P_CHUNK - 1);
    int t = threadIdx.x;
    int s = gstart[g], e = gstart[g + 1];
    float acc = 0.0f;
    for (int i = s + cch; i < e; i += P_CHUNK)
        acc += __builtin_nontemporal_load(&h[(size_t)i * HID + t]);
    pxg[(size_t)gb * HID + t] = acc;
}

__global__ __launch_bounds__(256) void mlp_kernel(const float* __restrict__ pxg,
                                                  const int* __restrict__ gstart,
                                                  const float* __restrict__ w1,
                                                  const float* __restrict__ b1,
                                                  const float* __restrict__ w2,
                                                  const float* __restrict__ b2,
                                                  float* __restrict__ out) {
    __shared__ float xr[256];
    __shared__ float red[256];
    int g = blockIdx.x, t = threadIdx.x;
    float sum = 0.0f;
    #pragma unroll
    for (int c = 0; c < P_CHUNK; ++c)
        sum += pxg[((size_t)g * P_CHUNK + c) * HID + t];
    float cnt = (float)(gstart[g + 1] - gstart[g]);
    xr[t] = sum / fmaxf(cnt, 1.0f);
    __syncthreads();
    float s = b1[t];
    #pragma unroll 4
    for (int kk = 0; kk < 256; ++kk) s += xr[kk] * w1[t * 256 + kk];
    s = fmaxf(s, 0.0f);
    red[t] = s * w2[t];
    __syncthreads();
    for (int off = 128; off; off >>= 1) {
        if (t < off) red[t] += red[t + off];
        __syncthreads();
    }
    if (t == 0) out[g] = red[0] + b2[0];
}

// ---------------------------------------------------------------- host
extern "C" void kernel_launch(void* const* d_in, const int* in_sizes, int n_in,
                              void* d_out, int out_size, void* d_ws, size_t ws_size,
                              hipStream_t stream) {
    const float* x      = (const float*)d_in[0];
    const float* lpe    = (const float*)d_in[1];
    const float* pe_w1  = (const float*)d_in[2];
    const float* pe_b1  = (const float*)d_in[3];
    const float* pe_w2  = (const float*)d_in[4];
    const float* pe_b2  = (const float*)d_in[5];
    const float* emb_w  = (const float*)d_in[6];
    const float* emb_b  = (const float*)d_in[7];
    const float* ln_g   = (const float*)d_in[8];
    const float* ln_b   = (const float*)d_in[9];
    const float* wq     = (const float*)d_in[10];
    const float* bq     = (const float*)d_in[11];
    const float* wk     = (const float*)d_in[12];
    const float* bk     = (const float*)d_in[13];
    const float* wv     = (const float*)d_in[14];
    const float* bv     = (const float*)d_in[15];
    const float* wskip  = (const float*)d_in[16];
    const float* bskip  = (const float*)d_in[17];
    const float* wbeta  = (const float*)d_in[18];
    const float* mlp_w1 = (const float*)d_in[19];
    const float* mlp_b1 = (const float*)d_in[20];
    const float* mlp_w2 = (const float*)d_in[21];
    const float* mlp_b2 = (const float*)d_in[22];
    const int*   eidx   = (const int*)d_in[23];
    const int*   batch  = (const int*)d_in[24];

    char* w = (char*)d_ws;
    const size_t NH = (size_t)N_NODES * HID;
    float* h     = (float*)w;           w += NH * 4;
    float* skipb = (float*)w;           w += NH * 4;
    float* outb  = (float*)w;           w += NH * 4;
    float* pxg   = (float*)w;           w += (size_t)N_GRAPHS * P_CHUNK * HID * 4;
    u16* qb      = (u16*)w;             w += NH * 2;
    u16* xnb     = (u16*)w;             w += NH * 2;
    u16* khv     = (u16*)w;             w += (size_t)HEADS * N_NODES * 64 * 2;
    u16* xb      = (u16*)w;             w += (size_t)N_NODES * IN_CH * 2;
    u16* t1b     = (u16*)w;             w += NH * 2;
    u16* ehi     = (u16*)w;             w += 32768 * 2;
    u16* p2hi    = (u16*)w;             w += 65536 * 2;
    u16* wchi    = (u16*)w;             w += 1048576 * 2;
    float* bcat  = (float*)w;           w += 4096 * 4;
    int* deg     = (int*)w;             w += N_NODES * 4;
    int* indptr  = (int*)w;             w += (N_NODES + 1) * 4;
    int* cursor  = (int*)w;             w += N_NODES * 4;
    int* ssrc    = (int*)w;             w += N_EDGES * 4;
    int* gstart  = (int*)w;             w += (N_GRAPHS + 1) * 4;

    // weight conversions (every call; deterministic)
    tob16_kernel<<<128, 256, 0, stream>>>(emb_w, ehi, 32768);
    tob16_kernel<<<256, 256, 0, stream>>>(pe_w2, p2hi, 65536);
    wcat_kernel<<<4096, 256, 0, stream>>>(wq, wk, wv, wskip, wchi);
    bcat_kernel<<<16, 256, 0, stream>>>(bq, bk, bv, bskip, bcat);
    tob16_kernel<<<16000, 256, 0, stream>>>(x, xb, N_NODES * IN_CH);

    // CSR by destination
    hipMemsetAsync(deg, 0, N_NODES * sizeof(int), stream);
    count_kernel<<<(N_EDGES + 255) / 256, 256, 0, stream>>>(eidx, deg);
    scan_kernel<<<1, 256, 0, stream>>>(deg, indptr, cursor);
    scatter_kernel<<<(N_EDGES + 255) / 256, 256, 0, stream>>>(eidx, cursor, ssrc);

    // h = x@emb_w^T + emb_b + pe_mlp(lpe)
    pe1_kernel<<<N_NODES, 256, 0, stream>>>(lpe, pe_w1, pe_b1, t1b);
    mgemm<0><<<dim3(250, 2), 256, 0, stream>>>(xb, ehi, emb_b, IN_CH, h, nullptr, nullptr, nullptr);
    mgemm<1><<<dim3(250, 2), 256, 0, stream>>>(t1b, p2hi, pe_b2, HID, h, nullptr, nullptr, nullptr);

    ln_kernel<<<N_NODES / 4, 256, 0, stream>>>(h, ln_g, ln_b, xnb);
    for (int l = 0; l < N_LAYERS; ++l) {
        mgemm<2><<<dim3(250, 8), 256, 0, stream>>>(xnb, wchi + (size_t)l * 262144,
                                                   bcat + l * 1024, HID,
                                                   nullptr, qb, khv, skipb);
        agg_kernel<<<(N_NODES / 64) * 8, 256, 0, stream>>>(qb, khv, indptr, ssrc, outb);
        if (l < N_LAYERS - 1) {
            beta_kernel<true><<<N_NODES / 4, 256, 0, stream>>>(
                outb, skipb, wbeta + l * 3 * HID,
                ln_g + (l + 1) * HID, ln_b + (l + 1) * HID, h, xnb);
        } else {
            beta_kernel<false><<<N_NODES / 4, 256, 0, stream>>>(
                outb, skipb, wbeta + l * 3 * HID, nullptr, nullptr, h, nullptr);
        }
    }

    bounds_kernel<<<1, 128, 0, stream>>>(batch, gstart);
    pool_kernel<<<N_GRAPHS * P_CHUNK, 256, 0, stream>>>(h, gstart, pxg);
    mlp_kernel<<<N_GRAPHS, 256, 0, stream>>>(pxg, gstart, mlp_w1, mlp_b1, mlp_w2, mlp_b2, (float*)d_out);
}

// Round 11
// 727.493 us; speedup vs baseline: 1.8111x; 1.1115x over previous
//
#include <hip/hip_runtime.h>

#define N_NODES   32000
#define N_EDGES   512000
#define IN_CH     128
#define HID       256
#define HEADS     8
#define D_HEAD    32
#define N_LAYERS  4
#define N_GRAPHS  64
#define P_CHUNK   16
#define MAX_SIDX  2048
#define N_SBLK    125      // N_NODES / 256

typedef unsigned short u16;
typedef __bf16 bf16x8 __attribute__((ext_vector_type(8)));
typedef float f32x4 __attribute__((ext_vector_type(4)));
typedef unsigned short u16x8 __attribute__((ext_vector_type(8)));

__device__ __forceinline__ u16 f2bf(float x) {
    union { float f; unsigned int u; } v; v.f = x;
    unsigned int r = v.u + 0x7FFFu + ((v.u >> 16) & 1u);  // round-to-nearest-even
    return (u16)(r >> 16);
}
__device__ __forceinline__ float bf2f(u16 b) {
    union { unsigned int u; float f; } v; v.u = ((unsigned int)b) << 16;
    return v.f;
}

// async global->LDS, 16B per lane; lds dest = wave-uniform base + lane*16
__device__ __forceinline__ void gll16(const u16* g, u16* l) {
    __builtin_amdgcn_global_load_lds(
        (const __attribute__((address_space(1))) unsigned int*)g,
        (__attribute__((address_space(3))) unsigned int*)l, 16, 0, 0);
}

// ---------------------------------------------------------------- CSR build
__global__ __launch_bounds__(256) void count_kernel(const int* __restrict__ ei,
                                                    int* __restrict__ deg) {
    int e = blockIdx.x * 256 + threadIdx.x;
    if (e < N_EDGES) atomicAdd(&deg[ei[N_EDGES + e]], 1);
}

// hierarchical scan stage 1: per-block (256 nodes) local exclusive scan + block sum
__global__ __launch_bounds__(256) void scan1_kernel(const int* __restrict__ deg,
                                                    int* __restrict__ indptr,
                                                    int* __restrict__ bsum) {
    __shared__ int wsum[4];
    int tid = threadIdx.x, lane = tid & 63, wave = tid >> 6;
    int i = blockIdx.x * 256 + tid;
    int v = deg[i];
    int x = v;
    #pragma unroll
    for (int off = 1; off < 64; off <<= 1) {
        int t = __shfl_up(x, off, 64);
        if (lane >= off) x += t;
    }
    if (lane == 63) wsum[wave] = x;
    __syncthreads();
    if (tid == 0) {
        int s = 0;
        #pragma unroll
        for (int w = 0; w < 4; ++w) { int t = wsum[w]; wsum[w] = s; s += t; }
        bsum[blockIdx.x] = s;
    }
    __syncthreads();
    indptr[i] = wsum[wave] + x - v;   // block-local exclusive prefix
}

// stage 2: single wave scans the 125 block sums -> exclusive block offsets
__global__ __launch_bounds__(64) void scan2_kernel(const int* __restrict__ bsum,
                                                   int* __restrict__ boff,
                                                   int* __restrict__ indptr) {
    int lane = threadIdx.x;
    int carry = 0;
    for (int base = 0; base < N_SBLK; base += 64) {
        int i = base + lane;
        int v = (i < N_SBLK) ? bsum[i] : 0;
        int x = v;
        #pragma unroll
        for (int off = 1; off < 64; off <<= 1) {
            int t = __shfl_up(x, off, 64);
            if (lane >= off) x += t;
        }
        if (i < N_SBLK) boff[i] = carry + x - v;
        carry += __shfl(x, 63, 64);
    }
    if (lane == 0) indptr[N_NODES] = carry;
}

// stage 3: add block offsets; produce final indptr and cursor
__global__ __launch_bounds__(256) void scan3_kernel(const int* __restrict__ boff,
                                                    int* __restrict__ indptr,
                                                    int* __restrict__ cursor) {
    int i = blockIdx.x * 256 + threadIdx.x;
    int val = indptr[i] + boff[blockIdx.x];
    indptr[i] = val;
    cursor[i] = val;
}

__global__ __launch_bounds__(256) void scatter_kernel(const int* __restrict__ ei,
                                                      int* __restrict__ cursor,
                                                      int* __restrict__ ssrc) {
    int e = blockIdx.x * 256 + threadIdx.x;
    if (e < N_EDGES) {
        int dst = ei[N_EDGES + e];
        int pos = atomicAdd(&cursor[dst], 1);
        ssrc[pos] = ei[e];
    }
}

// ---------------------------------------------------------------- conversions
__global__ __launch_bounds__(256) void tob16_kernel(const float* __restrict__ src,
                                                    u16* __restrict__ dst, int n) {
    int i = blockIdx.x * 256 + threadIdx.x;
    if (i < n) dst[i] = f2bf(src[i]);
}

// builds wcat[l][1024][256] = concat(wq,wk,wv,wskip) rows (single bf16)
__global__ __launch_bounds__(256) void wcat_kernel(const float* __restrict__ wq,
                                                   const float* __restrict__ wk,
                                                   const float* __restrict__ wv,
                                                   const float* __restrict__ ws,
                                                   u16* __restrict__ hi) {
    int i = blockIdx.x * 256 + threadIdx.x;  // 4*1024*256 = 1048576 total
    int l = i >> 18;
    int rem = i & 262143;
    int r = rem >> 8, c = rem & 255;
    int seg = r >> 8, rr = r & 255;
    const float* w = seg == 0 ? wq : seg == 1 ? wk : seg == 2 ? wv : ws;
    hi[i] = f2bf(w[(size_t)l * 65536 + rr * 256 + c]);
}

__global__ __launch_bounds__(256) void bcat_kernel(const float* __restrict__ bq,
                                                   const float* __restrict__ bk,
                                                   const float* __restrict__ bv,
                                                   const float* __restrict__ bs,
                                                   float* __restrict__ bcat) {
    int i = blockIdx.x * 256 + threadIdx.x;  // 4096
    int l = i >> 10, r = i & 1023;
    int seg = r >> 8, rr = r & 255;
    const float* b = seg == 0 ? bq : seg == 1 ? bk : seg == 2 ? bv : bs;
    bcat[i] = b[l * 256 + rr];
}

// ---------------------------------------------------------------- pe MLP stage 1
__global__ __launch_bounds__(256) void pe1_kernel(const float* __restrict__ lpe,
                                                  const float* __restrict__ w1,
                                                  const float* __restrict__ b1,
                                                  u16* __restrict__ t1b) {
    __shared__ float l[16];
    int n = blockIdx.x, j = threadIdx.x;
    if (j < 16) l[j] = lpe[n * 16 + j];
    __syncthreads();
    float s = b1[j];
    #pragma unroll
    for (int kk = 0; kk < 16; ++kk) s += l[kk] * w1[j * 16 + kk];
    t1b[(size_t)n * HID + j] = f2bf(fmaxf(s, 0.0f));
}

// ---------------------------------------------------------------- MFMA GEMM
// C[M x N] = A_bf16[M x K] @ W_bf16[N x K]^T + bias, f32 accumulate.
// BM=BN=128, BK=64, 4 waves (2x2), each wave 64x64 (4x4 frags of 16x16x32).
// LDS row-major w/ column XOR swizzle: chunk(r,kc) at index r*8+(kc^(r&7)).
// Staging via global_load_lds w16: dest lane-linear; source col permuted per lane.
// MODE 0: C0[row*256+col] = val;  MODE 1: C0 += val;
// MODE 2 (QKVS, N=1024): col<256 -> qb (bf16); 256..767 -> khv head-sliced bf16;
//                        >=768 -> skipb (f32)
template <int MODE>
__global__ __launch_bounds__(256) void mgemm(const u16* __restrict__ A,
                                             const u16* __restrict__ Wh,
                                             const float* __restrict__ bias,
                                             int K,
                                             float* __restrict__ C0,
                                             u16* __restrict__ qb,
                                             u16* __restrict__ khv,
                                             float* __restrict__ skipb) {
    __shared__ __align__(16) u16 sA[128 * 64];
    __shared__ __align__(16) u16 sWh[128 * 64];
    const int tid = threadIdx.x;
    const int l = tid & 63, wid = tid >> 6;
    const int wm = wid >> 1, wn = wid & 1;
    const int lr = l & 15, lc = l >> 4;
    const int r0 = blockIdx.x * 128;
    const int c0 = blockIdx.y * 128;

    f32x4 acc[4][4];
    #pragma unroll
    for (int m = 0; m < 4; ++m)
        #pragma unroll
        for (int n = 0; n < 4; ++n) acc[m][n] = (f32x4){0.f, 0.f, 0.f, 0.f};

    const int sr = l >> 3;                 // row within 8-row group
    const int skc = (l & 7) ^ sr;          // swizzled source column chunk
    for (int k0 = 0; k0 < K; k0 += 64) {
        #pragma unroll
        for (int j = 0; j < 4; ++j) {
            int r = j * 32 + wid * 8 + sr;
            int cb = (j * 256 + wid * 64) * 8;   // u16 idx of wave-uniform dest
            const u16* ga = A  + (size_t)(r0 + r) * K + k0 + skc * 8;
            const u16* gh = Wh + (size_t)(c0 + r) * K + k0 + skc * 8;
            gll16(ga, sA  + cb);
            gll16(gh, sWh + cb);
        }
        __syncthreads();
        #pragma unroll
        for (int kk = 0; kk < 2; ++kk) {
            const int kc = kk * 4 + lc;
            bf16x8 a[4], wh[4];
            #pragma unroll
            for (int m = 0; m < 4; ++m) {
                int r = wm * 64 + m * 16 + lr;
                a[m] = *reinterpret_cast<const bf16x8*>(
                    &sA[r * 64 + ((kc ^ (r & 7)) * 8)]);
            }
            #pragma unroll
            for (int n = 0; n < 4; ++n) {
                int r = wn * 64 + n * 16 + lr;
                wh[n] = *reinterpret_cast<const bf16x8*>(
                    &sWh[r * 64 + ((kc ^ (r & 7)) * 8)]);
            }
            #pragma unroll
            for (int m = 0; m < 4; ++m)
                #pragma unroll
                for (int n = 0; n < 4; ++n)
                    acc[m][n] = __builtin_amdgcn_mfma_f32_16x16x32_bf16(a[m], wh[n], acc[m][n], 0, 0, 0);
        }
        __syncthreads();
    }

    #pragma unroll
    for (int n = 0; n < 4; ++n) {
        int col = c0 + wn * 64 + n * 16 + lr;
        float bv = bias[col];
        #pragma unroll
        for (int m = 0; m < 4; ++m) {
            int rowb = r0 + wm * 64 + m * 16 + lc * 4;
            #pragma unroll
            for (int i = 0; i < 4; ++i) {
                float val = acc[m][n][i] + bv;
                int row = rowb + i;
                if (MODE == 0) {
                    C0[(size_t)row * 256 + col] = val;
                } else if (MODE == 1) {
                    C0[(size_t)row * 256 + col] += val;
                } else {
                    if (c0 < 256) {
                        qb[(size_t)row * 256 + col] = f2bf(val);
                    } else if (c0 < 512) {
                        int cc = col - 256, hh = cc >> 5, ch = cc & 31;
                        khv[((size_t)hh * N_NODES + row) * 64 + ch] = f2bf(val);
                    } else if (c0 < 768) {
                        int cc = col - 512, hh = cc >> 5, ch = cc & 31;
                        khv[((size_t)hh * N_NODES + row) * 64 + 32 + ch] = f2bf(val);
                    } else {
                        skipb[(size_t)row * 256 + (col - 768)] = val;
                    }
                }
            }
        }
    }
}

// ---------------------------------------------------------------- LayerNorm -> bf16
__global__ __launch_bounds__(256) void ln_kernel(const float* __restrict__ h,
                                                 const float* __restrict__ gw,
                                                 const float* __restrict__ bw,
                                                 u16* __restrict__ xnb) {
    int lane = threadIdx.x & 63, wave = threadIdx.x >> 6;
    int node = blockIdx.x * 4 + wave;
    float4 v = ((const float4*)(h + (size_t)node * HID))[lane];
    float s = v.x + v.y + v.z + v.w;
    #pragma unroll
    for (int off = 32; off; off >>= 1) s += __shfl_xor(s, off, 64);
    float mu = s * (1.0f / HID);
    float dx = v.x - mu, dy = v.y - mu, dz = v.z - mu, dw = v.w - mu;
    float q = dx * dx + dy * dy + dz * dz + dw * dw;
    #pragma unroll
    for (int off = 32; off; off >>= 1) q += __shfl_xor(q, off, 64);
    float inv = rsqrtf(q * (1.0f / HID) + 1e-5f);
    int c = lane * 4;
    float o0 = dx * inv * gw[c + 0] + bw[c + 0];
    float o1 = dy * inv * gw[c + 1] + bw[c + 1];
    float o2 = dz * inv * gw[c + 2] + bw[c + 2];
    float o3 = dw * inv * gw[c + 3] + bw[c + 3];
    uint2 pk;
    pk.x = (unsigned int)f2bf(o0) | ((unsigned int)f2bf(o1) << 16);
    pk.y = (unsigned int)f2bf(o2) | ((unsigned int)f2bf(o3) << 16);
    *reinterpret_cast<uint2*>(xnb + (size_t)node * HID + c) = pk;
}

// ---------------------------------------------------------------- fused edge attention
// one 4-lane group per (node, head); lane owns 8 channels for the whole walk.
// Block's contiguous ssrc range staged in LDS; two-bank chunk-4 kv pipeline.
__global__ __launch_bounds__(256) void agg_kernel(const u16* __restrict__ qb,
                                                  const u16* __restrict__ khv,
                                                  const int* __restrict__ indptr,
                                                  const int* __restrict__ ssrc,
                                                  float* __restrict__ outb) {
    __shared__ int sIdx[MAX_SIDX];
    const float scale = 0.17677669529663687f;  // 1/sqrt(32)
    const int tid = threadIdx.x;
    const int g = tid >> 2;     // group 0..63 = node within block
    const int j = tid & 3;      // channel quad (8 ch) within head
    const int h = blockIdx.x & 7;
    const int nb = (blockIdx.x >> 3) * 64;
    const int n = nb + g;

    // stage the block's contiguous edge-index range into LDS
    const int b0 = indptr[nb];
    const int bcnt = indptr[nb + 64] - b0;
    const int cap = bcnt < MAX_SIDX ? bcnt : MAX_SIDX;
    for (int i = tid; i < cap; i += 256) sIdx[i] = ssrc[b0 + i];
    __syncthreads();

    u16x8 q8 = *reinterpret_cast<const u16x8*>(qb + (size_t)n * HID + h * 32 + j * 8);
    float qv[8];
    #pragma unroll
    for (int i = 0; i < 8; ++i) qv[i] = bf2f(q8[i]) * scale;

    const int s0 = indptr[n], s1 = indptr[n + 1];
    const int last = s1 - 1;
    const u16* base = khv + (size_t)h * N_NODES * 64 + j * 8;
    float acc[8] = {0.f, 0.f, 0.f, 0.f, 0.f, 0.f, 0.f, 0.f};
    float ssum = 0.f;

    if (s0 < s1) {
        const int nchunk = (s1 - s0 + 3) >> 2;
        const int npair = (nchunk + 1) >> 1;
        int iA[4], iB[4];
        u16x8 kA[4], vA[4], kB[4], vB[4];
        #define LDIDX(e_, dst_) { int e2 = (e_) > last ? last : (e_); \
            int off = e2 - b0; \
            dst_ = (off < cap) ? sIdx[off] : ssrc[e2]; }
        #pragma unroll
        for (int i = 0; i < 4; ++i) LDIDX(s0 + i, iA[i]);
        #pragma unroll
        for (int i = 0; i < 4; ++i) {
            const u16* rp = base + (size_t)iA[i] * 64;
            kA[i] = *reinterpret_cast<const u16x8*>(rp);
            vA[i] = *reinterpret_cast<const u16x8*>(rp + 32);
        }
        #pragma unroll
        for (int i = 0; i < 4; ++i) LDIDX(s0 + 4 + i, iB[i]);
        int eb = s0;
        for (int pc = 0; pc < npair; ++pc) {
            #pragma unroll
            for (int i = 0; i < 4; ++i) {
                const u16* rp = base + (size_t)iB[i] * 64;
                kB[i] = *reinterpret_cast<const u16x8*>(rp);
                vB[i] = *reinterpret_cast<const u16x8*>(rp + 32);
            }
            #pragma unroll
            for (int i = 0; i < 4; ++i) {
                float prod = 0.f;
                #pragma unroll
                for (int t = 0; t < 8; ++t) prod += qv[t] * bf2f(kA[i][t]);
                prod += __shfl_xor(prod, 1, 64);
                prod += __shfl_xor(prod, 2, 64);
                float p = (eb + i <= last) ? __expf(prod) : 0.f;
                ssum += p;
                #pragma unroll
                for (int t = 0; t < 8; ++t) acc[t] += p * bf2f(vA[i][t]);
            }
            eb += 4;
            #pragma unroll
            for (int i = 0; i < 4; ++i) LDIDX(eb + 4 + i, iA[i]);
            #pragma unroll
            for (int i = 0; i < 4; ++i) {
                const u16* rp = base + (size_t)iA[i] * 64;
                kA[i] = *reinterpret_cast<const u16x8*>(rp);
                vA[i] = *reinterpret_cast<const u16x8*>(rp + 32);
            }
            #pragma unroll
            for (int i = 0; i < 4; ++i) {
                float prod = 0.f;
                #pragma unroll
                for (int t = 0; t < 8; ++t) prod += qv[t] * bf2f(kB[i][t]);
                prod += __shfl_xor(prod, 1, 64);
                prod += __shfl_xor(prod, 2, 64);
                float p = (eb + i <= last) ? __expf(prod) : 0.f;
                ssum += p;
                #pragma unroll
                for (int t = 0; t < 8; ++t) acc[t] += p * bf2f(vB[i][t]);
            }
            eb += 4;
            #pragma unroll
            for (int i = 0; i < 4; ++i) LDIDX(eb + 4 + i, iB[i]);
        }
        #undef LDIDX
    }

    float inv = 1.0f / fmaxf(ssum, 1e-16f);
    float* op = outb + (size_t)n * HID + h * 32 + j * 8;
    f32x4 o0 = {acc[0] * inv, acc[1] * inv, acc[2] * inv, acc[3] * inv};
    f32x4 o1 = {acc[4] * inv, acc[5] * inv, acc[6] * inv, acc[7] * inv};
    __builtin_nontemporal_store(o0, (f32x4*)op);
    __builtin_nontemporal_store(o1, (f32x4*)(op + 4));
}

// ------------------------------------------- beta gate + relu + residual (+ next LN)
template <bool DO_LN>
__global__ __launch_bounds__(256) void beta_kernel(const float* __restrict__ outb,
                                                   const float* __restrict__ skipb,
                                                   const float* __restrict__ wb,
                                                   const float* __restrict__ gw,
                                                   const float* __restrict__ bw,
                                                   float* __restrict__ h,
                                                   u16* __restrict__ xnb) {
    int lane = threadIdx.x & 63, wave = threadIdx.x >> 6;
    int node = blockIdx.x * 4 + wave;
    int c = lane * 4;
    float4 o  = ((const float4*)(outb  + (size_t)node * HID))[lane];
    float4 sk = ((const float4*)(skipb + (size_t)node * HID))[lane];
    float acc = o.x * wb[c + 0] + o.y * wb[c + 1] + o.z * wb[c + 2] + o.w * wb[c + 3]
              + sk.x * wb[HID + c + 0] + sk.y * wb[HID + c + 1]
              + sk.z * wb[HID + c + 2] + sk.w * wb[HID + c + 3]
              + (o.x - sk.x) * wb[2 * HID + c + 0] + (o.y - sk.y) * wb[2 * HID + c + 1]
              + (o.z - sk.z) * wb[2 * HID + c + 2] + (o.w - sk.w) * wb[2 * HID + c + 3];
    #pragma unroll
    for (int off = 32; off; off >>= 1) acc += __shfl_xor(acc, off, 64);
    float beta = 1.0f / (1.0f + __expf(-acc));
    float4 r = ((const float4*)(h + (size_t)node * HID))[lane];
    float4 out;
    out.x = fmaxf(beta * sk.x + (1.0f - beta) * o.x, 0.0f) + r.x;
    out.y = fmaxf(beta * sk.y + (1.0f - beta) * o.y, 0.0f) + r.y;
    out.z = fmaxf(beta * sk.z + (1.0f - beta) * o.z, 0.0f) + r.z;
    out.w = fmaxf(beta * sk.w + (1.0f - beta) * o.w, 0.0f) + r.w;
    ((float4*)(h + (size_t)node * HID))[lane] = out;

    if (DO_LN) {
        float s = out.x + out.y + out.z + out.w;
        #pragma unroll
        for (int off = 32; off; off >>= 1) s += __shfl_xor(s, off, 64);
        float mu = s * (1.0f / HID);
        float dx = out.x - mu, dy = out.y - mu, dz = out.z - mu, dw = out.w - mu;
        float qq = dx * dx + dy * dy + dz * dz + dw * dw;
        #pragma unroll
        for (int off = 32; off; off >>= 1) qq += __shfl_xor(qq, off, 64);
        float inv = rsqrtf(qq * (1.0f / HID) + 1e-5f);
        float o0 = dx * inv * gw[c + 0] + bw[c + 0];
        float o1 = dy * inv * gw[c + 1] + bw[c + 1];
        float o2 = dz * inv * gw[c + 2] + bw[c + 2];
        float o3 = dw * inv * gw[c + 3] + bw[c + 3];
        uint2 pk;
        pk.x = (unsigned int)f2bf(o0) | ((unsigned int)f2bf(o1) << 16);
        pk.y = (unsigned int)f2bf(o2) | ((unsigned int)f2bf(o3) << 16);
        *reinterpret_cast<uint2*>(xnb + (size_t)node * HID + c) = pk;
    }
}

// ---------------------------------------------------------------- pooling + final MLP
__global__ __launch_bounds__(128) void bounds_kernel(const int* __restrict__ batch,
                                                     int* __restrict__ gstart) {
    int g = threadIdx.x;
    if (g > N_GRAPHS) return;
    int lo = 0, hi = N_NODES;
    while (lo < hi) { int mid = (lo + hi) >> 1; if (batch[mid] < g) lo = mid + 1; else hi = mid; }
    gstart[g] = lo;
}

// stage 1: 16 chunks per graph, deterministic partials pxg[g][chunk][256]
__global__ __launch_bounds__(256) void pool_kernel(const float* __restrict__ h,
                                                   const int* __restrict__ gstart,
                                                   float* __restrict__ pxg) {
    int gb = blockIdx.x;                 // 0 .. N_GRAPHS*P_CHUNK-1
    int g = gb >> 4, cch = gb & (P_CHUNK - 1);
    int t = threadIdx.x;
    int s = gstart[g], e = gstart[g + 1];
    float acc = 0.0f;
    for (int i = s + cch; i < e; i += P_CHUNK)
        acc += __builtin_nontemporal_load(&h[(size_t)i * HID + t]);
    pxg[(size_t)gb * HID + t] = acc;
}

__global__ __launch_bounds__(256) void mlp_kernel(const float* __restrict__ pxg,
                                                  const int* __restrict__ gstart,
                                                  const float* __restrict__ w1,
                                                  const float* __restrict__ b1,
                                                  const float* __restrict__ w2,
                                                  const float* __restrict__ b2,
                                                  float* __restrict__ out) {
    __shared__ float xr[256];
    __shared__ float red[256];
    int g = blockIdx.x, t = threadIdx.x;
    float sum = 0.0f;
    #pragma unroll
    for (int c = 0; c < P_CHUNK; ++c)
        sum += pxg[((size_t)g * P_CHUNK + c) * HID + t];
    float cnt = (float)(gstart[g + 1] - gstart[g]);
    xr[t] = sum / fmaxf(cnt, 1.0f);
    __syncthreads();
    float s = b1[t];
    #pragma unroll 4
    for (int kk = 0; kk < 256; ++kk) s += xr[kk] * w1[t * 256 + kk];
    s = fmaxf(s, 0.0f);
    red[t] = s * w2[t];
    __syncthreads();
    for (int off = 128; off; off >>= 1) {
        if (t < off) red[t] += red[t + off];
        __syncthreads();
    }
    if (t == 0) out[g] = red[0] + b2[0];
}

// ---------------------------------------------------------------- host
extern "C" void kernel_launch(void* const* d_in, const int* in_sizes, int n_in,
                              void* d_out, int out_size, void* d_ws, size_t ws_size,
                              hipStream_t stream) {
    const float* x      = (const float*)d_in[0];
    const float* lpe    = (const float*)d_in[1];
    const float* pe_w1  = (const float*)d_in[2];
    const float* pe_b1  = (const float*)d_in[3];
    const float* pe_w2  = (const float*)d_in[4];
    const float* pe_b2  = (const float*)d_in[5];
    const float* emb_w  = (const float*)d_in[6];
    const float* emb_b  = (const float*)d_in[7];
    const float* ln_g   = (const float*)d_in[8];
    const float* ln_b   = (const float*)d_in[9];
    const float* wq     = (const float*)d_in[10];
    const float* bq     = (const float*)d_in[11];
    const float* wk     = (const float*)d_in[12];
    const float* bk     = (const float*)d_in[13];
    const float* wv     = (const float*)d_in[14];
    const float* bv     = (const float*)d_in[15];
    const float* wskip  = (const float*)d_in[16];
    const float* bskip  = (const float*)d_in[17];
    const float* wbeta  = (const float*)d_in[18];
    const float* mlp_w1 = (const float*)d_in[19];
    const float* mlp_b1 = (const float*)d_in[20];
    const float* mlp_w2 = (const float*)d_in[21];
    const float* mlp_b2 = (const float*)d_in[22];
    const int*   eidx   = (const int*)d_in[23];
    const int*   batch  = (const int*)d_in[24];

    char* w = (char*)d_ws;
    const size_t NH = (size_t)N_NODES * HID;
    float* h     = (float*)w;           w += NH * 4;
    float* skipb = (float*)w;           w += NH * 4;
    float* outb  = (float*)w;           w += NH * 4;
    float* pxg   = (float*)w;           w += (size_t)N_GRAPHS * P_CHUNK * HID * 4;
    u16* qb      = (u16*)w;             w += NH * 2;
    u16* xnb     = (u16*)w;             w += NH * 2;
    u16* khv     = (u16*)w;             w += (size_t)HEADS * N_NODES * 64 * 2;
    u16* xb      = (u16*)w;             w += (size_t)N_NODES * IN_CH * 2;
    u16* t1b     = (u16*)w;             w += NH * 2;
    u16* ehi     = (u16*)w;             w += 32768 * 2;
    u16* p2hi    = (u16*)w;             w += 65536 * 2;
    u16* wchi    = (u16*)w;             w += 1048576 * 2;
    float* bcat  = (float*)w;           w += 4096 * 4;
    int* deg     = (int*)w;             w += N_NODES * 4;
    int* indptr  = (int*)w;             w += (N_NODES + 1) * 4;
    int* cursor  = (int*)w;             w += N_NODES * 4;
    int* ssrc    = (int*)w;             w += N_EDGES * 4;
    int* gstart  = (int*)w;             w += (N_GRAPHS + 1) * 4;
    int* bsum    = (int*)w;             w += 128 * 4;
    int* boff    = (int*)w;             w += 128 * 4;

    // weight conversions (every call; deterministic)
    tob16_kernel<<<128, 256, 0, stream>>>(emb_w, ehi, 32768);
    tob16_kernel<<<256, 256, 0, stream>>>(pe_w2, p2hi, 65536);
    wcat_kernel<<<4096, 256, 0, stream>>>(wq, wk, wv, wskip, wchi);
    bcat_kernel<<<16, 256, 0, stream>>>(bq, bk, bv, bskip, bcat);
    tob16_kernel<<<16000, 256, 0, stream>>>(x, xb, N_NODES * IN_CH);

    // CSR by destination (hierarchical scan)
    hipMemsetAsync(deg, 0, N_NODES * sizeof(int), stream);
    count_kernel<<<(N_EDGES + 255) / 256, 256, 0, stream>>>(eidx, deg);
    scan1_kernel<<<N_SBLK, 256, 0, stream>>>(deg, indptr, bsum);
    scan2_kernel<<<1, 64, 0, stream>>>(bsum, boff, indptr);
    scan3_kernel<<<N_SBLK, 256, 0, stream>>>(boff, indptr, cursor);
    scatter_kernel<<<(N_EDGES + 255) / 256, 256, 0, stream>>>(eidx, cursor, ssrc);

    // h = x@emb_w^T + emb_b + pe_mlp(lpe)
    pe1_kernel<<<N_NODES, 256, 0, stream>>>(lpe, pe_w1, pe_b1, t1b);
    mgemm<0><<<dim3(250, 2), 256, 0, stream>>>(xb, ehi, emb_b, IN_CH, h, nullptr, nullptr, nullptr);
    mgemm<1><<<dim3(250, 2), 256, 0, stream>>>(t1b, p2hi, pe_b2, HID, h, nullptr, nullptr, nullptr);

    ln_kernel<<<N_NODES / 4, 256, 0, stream>>>(h, ln_g, ln_b, xnb);
    for (int l = 0; l < N_LAYERS; ++l) {
        mgemm<2><<<dim3(250, 8), 256, 0, stream>>>(xnb, wchi + (size_t)l * 262144,
                                                   bcat + l * 1024, HID,
                                                   nullptr, qb, khv, skipb);
        agg_kernel<<<(N_NODES / 64) * 8, 256, 0, stream>>>(qb, khv, indptr, ssrc, outb);
        if (l < N_LAYERS - 1) {
            beta_kernel<true><<<N_NODES / 4, 256, 0, stream>>>(
                outb, skipb, wbeta + l * 3 * HID,
                ln_g + (l + 1) * HID, ln_b + (l + 1) * HID, h, xnb);
        } else {
            beta_kernel<false><<<N_NODES / 4, 256, 0, stream>>>(
                outb, skipb, wbeta + l * 3 * HID, nullptr, nullptr, h, nullptr);
        }
    }

    bounds_kernel<<<1, 128, 0, stream>>>(batch, gstart);
    pool_kernel<<<N_GRAPHS * P_CHUNK, 256, 0, stream>>>(h, gstart, pxg);
    mlp_kernel<<<N_GRAPHS, 256, 0, stream>>>(pxg, gstart, mlp_w1, mlp_b1, mlp_w2, mlp_b2, (float*)d_out);
}

// Round 12
// 698.373 us; speedup vs baseline: 1.8866x; 1.0417x over previous
//
#include <hip/hip_runtime.h>

#define N_NODES   32000
#define N_EDGES   512000
#define IN_CH     128
#define HID       256
#define HEADS     8
#define D_HEAD    32
#define N_LAYERS  4
#define N_GRAPHS  64
#define P_CHUNK   16
#define MAX_SIDX  2048
#define N_SBLK    125      // N_NODES / 256

typedef unsigned short u16;
typedef __bf16 bf16x8 __attribute__((ext_vector_type(8)));
typedef float f32x4 __attribute__((ext_vector_type(4)));
typedef unsigned short u16x8 __attribute__((ext_vector_type(8)));

__device__ __forceinline__ u16 f2bf(float x) {
    union { float f; unsigned int u; } v; v.f = x;
    unsigned int r = v.u + 0x7FFFu + ((v.u >> 16) & 1u);  // round-to-nearest-even
    return (u16)(r >> 16);
}
__device__ __forceinline__ float bf2f(u16 b) {
    union { unsigned int u; float f; } v; v.u = ((unsigned int)b) << 16;
    return v.f;
}

// async global->LDS, 16B per lane; lds dest = wave-uniform base + lane*16
__device__ __forceinline__ void gll16(const u16* g, u16* l) {
    __builtin_amdgcn_global_load_lds(
        (const __attribute__((address_space(1))) unsigned int*)g,
        (__attribute__((address_space(3))) unsigned int*)l, 16, 0, 0);
}

// ---------------------------------------------------------------- CSR build
__global__ __launch_bounds__(256) void count_kernel(const int* __restrict__ ei,
                                                    int* __restrict__ deg) {
    int e = blockIdx.x * 256 + threadIdx.x;
    if (e < N_EDGES) atomicAdd(&deg[ei[N_EDGES + e]], 1);
}

// hierarchical scan stage 1: per-block (256 nodes) local exclusive scan + block sum
__global__ __launch_bounds__(256) void scan1_kernel(const int* __restrict__ deg,
                                                    int* __restrict__ indptr,
                                                    int* __restrict__ bsum) {
    __shared__ int wsum[4];
    int tid = threadIdx.x, lane = tid & 63, wave = tid >> 6;
    int i = blockIdx.x * 256 + tid;
    int v = deg[i];
    int x = v;
    #pragma unroll
    for (int off = 1; off < 64; off <<= 1) {
        int t = __shfl_up(x, off, 64);
        if (lane >= off) x += t;
    }
    if (lane == 63) wsum[wave] = x;
    __syncthreads();
    if (tid == 0) {
        int s = 0;
        #pragma unroll
        for (int w = 0; w < 4; ++w) { int t = wsum[w]; wsum[w] = s; s += t; }
        bsum[blockIdx.x] = s;
    }
    __syncthreads();
    indptr[i] = wsum[wave] + x - v;   // block-local exclusive prefix
}

// stage 2: single wave scans the 125 block sums -> exclusive block offsets
__global__ __launch_bounds__(64) void scan2_kernel(const int* __restrict__ bsum,
                                                   int* __restrict__ boff,
                                                   int* __restrict__ indptr) {
    int lane = threadIdx.x;
    int carry = 0;
    for (int base = 0; base < N_SBLK; base += 64) {
        int i = base + lane;
        int v = (i < N_SBLK) ? bsum[i] : 0;
        int x = v;
        #pragma unroll
        for (int off = 1; off < 64; off <<= 1) {
            int t = __shfl_up(x, off, 64);
            if (lane >= off) x += t;
        }
        if (i < N_SBLK) boff[i] = carry + x - v;
        carry += __shfl(x, 63, 64);
    }
    if (lane == 0) indptr[N_NODES] = carry;
}

// stage 3: add block offsets; produce final indptr and cursor
__global__ __launch_bounds__(256) void scan3_kernel(const int* __restrict__ boff,
                                                    int* __restrict__ indptr,
                                                    int* __restrict__ cursor) {
    int i = blockIdx.x * 256 + threadIdx.x;
    int val = indptr[i] + boff[blockIdx.x];
    indptr[i] = val;
    cursor[i] = val;
}

__global__ __launch_bounds__(256) void scatter_kernel(const int* __restrict__ ei,
                                                      int* __restrict__ cursor,
                                                      int* __restrict__ ssrc) {
    int e = blockIdx.x * 256 + threadIdx.x;
    if (e < N_EDGES) {
        int dst = ei[N_EDGES + e];
        int pos = atomicAdd(&cursor[dst], 1);
        ssrc[pos] = ei[e];
    }
}

// ---------------------------------------------------------------- conversions
__global__ __launch_bounds__(256) void tob16_kernel(const float* __restrict__ src,
                                                    u16* __restrict__ dst, int n) {
    int i = blockIdx.x * 256 + threadIdx.x;
    if (i < n) dst[i] = f2bf(src[i]);
}

// builds wcat[l][1024][256] = concat(wq,wk,wv,wskip) rows (single bf16)
__global__ __launch_bounds__(256) void wcat_kernel(const float* __restrict__ wq,
                                                   const float* __restrict__ wk,
                                                   const float* __restrict__ wv,
                                                   const float* __restrict__ ws,
                                                   u16* __restrict__ hi) {
    int i = blockIdx.x * 256 + threadIdx.x;  // 4*1024*256 = 1048576 total
    int l = i >> 18;
    int rem = i & 262143;
    int r = rem >> 8, c = rem & 255;
    int seg = r >> 8, rr = r & 255;
    const float* w = seg == 0 ? wq : seg == 1 ? wk : seg == 2 ? wv : ws;
    hi[i] = f2bf(w[(size_t)l * 65536 + rr * 256 + c]);
}

__global__ __launch_bounds__(256) void bcat_kernel(const float* __restrict__ bq,
                                                   const float* __restrict__ bk,
                                                   const float* __restrict__ bv,
                                                   const float* __restrict__ bs,
                                                   float* __restrict__ bcat) {
    int i = blockIdx.x * 256 + threadIdx.x;  // 4096
    int l = i >> 10, r = i & 1023;
    int seg = r >> 8, rr = r & 255;
    const float* b = seg == 0 ? bq : seg == 1 ? bk : seg == 2 ? bv : bs;
    bcat[i] = b[l * 256 + rr];
}

// ---------------------------------------------------------------- pe MLP stage 1
__global__ __launch_bounds__(256) void pe1_kernel(const float* __restrict__ lpe,
                                                  const float* __restrict__ w1,
                                                  const float* __restrict__ b1,
                                                  u16* __restrict__ t1b) {
    __shared__ float l[16];
    int n = blockIdx.x, j = threadIdx.x;
    if (j < 16) l[j] = lpe[n * 16 + j];
    __syncthreads();
    float s = b1[j];
    #pragma unroll
    for (int kk = 0; kk < 16; ++kk) s += l[kk] * w1[j * 16 + kk];
    t1b[(size_t)n * HID + j] = f2bf(fmaxf(s, 0.0f));
}

// ---------------------------------------------------------------- MFMA GEMM
// C[M x N] = A_bf16[M x K] @ W_bf16[N x K]^T + bias, f32 accumulate.
// BM=128, BN=256, BK=64, 8 waves (2 row x 4 col), wave tile 64x64 (4x4 frags).
// One A tile feeds 256 output cols (2x less A staging per FLOP vs BN=128).
// LDS row-major w/ column XOR swizzle: chunk(r,kc) at index r*8+(kc^(r&7)).
// Staging via global_load_lds w16: dest lane-linear; source col permuted per lane.
// Grid (ncol, 250): column block fastest -> A row-panel L2 temporal locality.
// MODE 0: C0[row*256+col] = val;  MODE 1: C0 += val;
// MODE 2 (QKVS, N=1024): col<256 -> qb (bf16); 256..767 -> khv head-sliced bf16;
//                        >=768 -> skipb (f32)
template <int MODE>
__global__ __launch_bounds__(512) void mgemm(const u16* __restrict__ A,
                                             const u16* __restrict__ Wh,
                                             const float* __restrict__ bias,
                                             int K,
                                             float* __restrict__ C0,
                                             u16* __restrict__ qb,
                                             u16* __restrict__ khv,
                                             float* __restrict__ skipb) {
    __shared__ __align__(16) u16 sA[128 * 64];
    __shared__ __align__(16) u16 sWh[256 * 64];
    const int tid = threadIdx.x;
    const int l = tid & 63, wid = tid >> 6;          // 8 waves
    const int wm = wid >> 2, wn = wid & 3;           // 2 x 4
    const int lr = l & 15, lc = l >> 4;
    const int r0 = blockIdx.y * 128;
    const int c0 = blockIdx.x * 256;

    f32x4 acc[4][4];
    #pragma unroll
    for (int m = 0; m < 4; ++m)
        #pragma unroll
        for (int n = 0; n < 4; ++n) acc[m][n] = (f32x4){0.f, 0.f, 0.f, 0.f};

    const int sr = l >> 3;                 // row within 8-row group
    const int skc = (l & 7) ^ sr;          // swizzled source column chunk
    for (int k0 = 0; k0 < K; k0 += 64) {
        // A: 128 rows = 16 groups of 8; wave handles groups wid, wid+8
        #pragma unroll
        for (int j = 0; j < 2; ++j) {
            int grp = j * 8 + wid;
            int r = grp * 8 + sr;
            gll16(A + (size_t)(r0 + r) * K + k0 + skc * 8, sA + grp * 512);
        }
        // W: 256 rows = 32 groups; wave handles wid, wid+8, wid+16, wid+24
        #pragma unroll
        for (int j = 0; j < 4; ++j) {
            int grp = j * 8 + wid;
            int r = grp * 8 + sr;
            gll16(Wh + (size_t)(c0 + r) * K + k0 + skc * 8, sWh + grp * 512);
        }
        __syncthreads();
        #pragma unroll
        for (int kk = 0; kk < 2; ++kk) {
            const int kc = kk * 4 + lc;
            bf16x8 a[4], wh[4];
            #pragma unroll
            for (int m = 0; m < 4; ++m) {
                int r = wm * 64 + m * 16 + lr;
                a[m] = *reinterpret_cast<const bf16x8*>(
                    &sA[r * 64 + ((kc ^ (r & 7)) * 8)]);
            }
            #pragma unroll
            for (int n = 0; n < 4; ++n) {
                int r = wn * 64 + n * 16 + lr;
                wh[n] = *reinterpret_cast<const bf16x8*>(
                    &sWh[r * 64 + ((kc ^ (r & 7)) * 8)]);
            }
            #pragma unroll
            for (int m = 0; m < 4; ++m)
                #pragma unroll
                for (int n = 0; n < 4; ++n)
                    acc[m][n] = __builtin_amdgcn_mfma_f32_16x16x32_bf16(a[m], wh[n], acc[m][n], 0, 0, 0);
        }
        __syncthreads();
    }

    #pragma unroll
    for (int n = 0; n < 4; ++n) {
        int col = c0 + wn * 64 + n * 16 + lr;
        float bv = bias[col];
        #pragma unroll
        for (int m = 0; m < 4; ++m) {
            int rowb = r0 + wm * 64 + m * 16 + lc * 4;
            #pragma unroll
            for (int i = 0; i < 4; ++i) {
                float val = acc[m][n][i] + bv;
                int row = rowb + i;
                if (MODE == 0) {
                    C0[(size_t)row * 256 + col] = val;
                } else if (MODE == 1) {
                    C0[(size_t)row * 256 + col] += val;
                } else {
                    if (col < 256) {
                        qb[(size_t)row * 256 + col] = f2bf(val);
                    } else if (col < 512) {
                        int cc = col - 256, hh = cc >> 5, ch = cc & 31;
                        khv[((size_t)hh * N_NODES + row) * 64 + ch] = f2bf(val);
                    } else if (col < 768) {
                        int cc = col - 512, hh = cc >> 5, ch = cc & 31;
                        khv[((size_t)hh * N_NODES + row) * 64 + 32 + ch] = f2bf(val);
                    } else {
                        skipb[(size_t)row * 256 + (col - 768)] = val;
                    }
                }
            }
        }
    }
}

// ---------------------------------------------------------------- LayerNorm -> bf16
__global__ __launch_bounds__(256) void ln_kernel(const float* __restrict__ h,
                                                 const float* __restrict__ gw,
                                                 const float* __restrict__ bw,
                                                 u16* __restrict__ xnb) {
    int lane = threadIdx.x & 63, wave = threadIdx.x >> 6;
    int node = blockIdx.x * 4 + wave;
    float4 v = ((const float4*)(h + (size_t)node * HID))[lane];
    float s = v.x + v.y + v.z + v.w;
    #pragma unroll
    for (int off = 32; off; off >>= 1) s += __shfl_xor(s, off, 64);
    float mu = s * (1.0f / HID);
    float dx = v.x - mu, dy = v.y - mu, dz = v.z - mu, dw = v.w - mu;
    float q = dx * dx + dy * dy + dz * dz + dw * dw;
    #pragma unroll
    for (int off = 32; off; off >>= 1) q += __shfl_xor(q, off, 64);
    float inv = rsqrtf(q * (1.0f / HID) + 1e-5f);
    int c = lane * 4;
    float o0 = dx * inv * gw[c + 0] + bw[c + 0];
    float o1 = dy * inv * gw[c + 1] + bw[c + 1];
    float o2 = dz * inv * gw[c + 2] + bw[c + 2];
    float o3 = dw * inv * gw[c + 3] + bw[c + 3];
    uint2 pk;
    pk.x = (unsigned int)f2bf(o0) | ((unsigned int)f2bf(o1) << 16);
    pk.y = (unsigned int)f2bf(o2) | ((unsigned int)f2bf(o3) << 16);
    *reinterpret_cast<uint2*>(xnb + (size_t)node * HID + c) = pk;
}

// ---------------------------------------------------------------- fused edge attention
// one 4-lane group per (node, head); lane owns 8 channels for the whole walk.
// Block's contiguous ssrc range staged in LDS; two-bank chunk-4 kv pipeline.
__global__ __launch_bounds__(256) void agg_kernel(const u16* __restrict__ qb,
                                                  const u16* __restrict__ khv,
                                                  const int* __restrict__ indptr,
                                                  const int* __restrict__ ssrc,
                                                  float* __restrict__ outb) {
    __shared__ int sIdx[MAX_SIDX];
    const float scale = 0.17677669529663687f;  // 1/sqrt(32)
    const int tid = threadIdx.x;
    const int g = tid >> 2;     // group 0..63 = node within block
    const int j = tid & 3;      // channel quad (8 ch) within head
    const int h = blockIdx.x & 7;
    const int nb = (blockIdx.x >> 3) * 64;
    const int n = nb + g;

    // stage the block's contiguous edge-index range into LDS
    const int b0 = indptr[nb];
    const int bcnt = indptr[nb + 64] - b0;
    const int cap = bcnt < MAX_SIDX ? bcnt : MAX_SIDX;
    for (int i = tid; i < cap; i += 256) sIdx[i] = ssrc[b0 + i];
    __syncthreads();

    u16x8 q8 = *reinterpret_cast<const u16x8*>(qb + (size_t)n * HID + h * 32 + j * 8);
    float qv[8];
    #pragma unroll
    for (int i = 0; i < 8; ++i) qv[i] = bf2f(q8[i]) * scale;

    const int s0 = indptr[n], s1 = indptr[n + 1];
    const int last = s1 - 1;
    const u16* base = khv + (size_t)h * N_NODES * 64 + j * 8;
    float acc[8] = {0.f, 0.f, 0.f, 0.f, 0.f, 0.f, 0.f, 0.f};
    float ssum = 0.f;

    if (s0 < s1) {
        const int nchunk = (s1 - s0 + 3) >> 2;
        const int npair = (nchunk + 1) >> 1;
        int iA[4], iB[4];
        u16x8 kA[4], vA[4], kB[4], vB[4];
        #define LDIDX(e_, dst_) { int e2 = (e_) > last ? last : (e_); \
            int off = e2 - b0; \
            dst_ = (off < cap) ? sIdx[off] : ssrc[e2]; }
        #pragma unroll
        for (int i = 0; i < 4; ++i) LDIDX(s0 + i, iA[i]);
        #pragma unroll
        for (int i = 0; i < 4; ++i) {
            const u16* rp = base + (size_t)iA[i] * 64;
            kA[i] = *reinterpret_cast<const u16x8*>(rp);
            vA[i] = *reinterpret_cast<const u16x8*>(rp + 32);
        }
        #pragma unroll
        for (int i = 0; i < 4; ++i) LDIDX(s0 + 4 + i, iB[i]);
        int eb = s0;
        for (int pc = 0; pc < npair; ++pc) {
            #pragma unroll
            for (int i = 0; i < 4; ++i) {
                const u16* rp = base + (size_t)iB[i] * 64;
                kB[i] = *reinterpret_cast<const u16x8*>(rp);
                vB[i] = *reinterpret_cast<const u16x8*>(rp + 32);
            }
            #pragma unroll
            for (int i = 0; i < 4; ++i) {
                float prod = 0.f;
                #pragma unroll
                for (int t = 0; t < 8; ++t) prod += qv[t] * bf2f(kA[i][t]);
                prod += __shfl_xor(prod, 1, 64);
                prod += __shfl_xor(prod, 2, 64);
                float p = (eb + i <= last) ? __expf(prod) : 0.f;
                ssum += p;
                #pragma unroll
                for (int t = 0; t < 8; ++t) acc[t] += p * bf2f(vA[i][t]);
            }
            eb += 4;
            #pragma unroll
            for (int i = 0; i < 4; ++i) LDIDX(eb + 4 + i, iA[i]);
            #pragma unroll
            for (int i = 0; i < 4; ++i) {
                const u16* rp = base + (size_t)iA[i] * 64;
                kA[i] = *reinterpret_cast<const u16x8*>(rp);
                vA[i] = *reinterpret_cast<const u16x8*>(rp + 32);
            }
            #pragma unroll
            for (int i = 0; i < 4; ++i) {
                float prod = 0.f;
                #pragma unroll
                for (int t = 0; t < 8; ++t) prod += qv[t] * bf2f(kB[i][t]);
                prod += __shfl_xor(prod, 1, 64);
                prod += __shfl_xor(prod, 2, 64);
                float p = (eb + i <= last) ? __expf(prod) : 0.f;
                ssum += p;
                #pragma unroll
                for (int t = 0; t < 8; ++t) acc[t] += p * bf2f(vB[i][t]);
            }
            eb += 4;
            #pragma unroll
            for (int i = 0; i < 4; ++i) LDIDX(eb + 4 + i, iB[i]);
        }
        #undef LDIDX
    }

    float inv = 1.0f / fmaxf(ssum, 1e-16f);
    float* op = outb + (size_t)n * HID + h * 32 + j * 8;
    f32x4 o0 = {acc[0] * inv, acc[1] * inv, acc[2] * inv, acc[3] * inv};
    f32x4 o1 = {acc[4] * inv, acc[5] * inv, acc[6] * inv, acc[7] * inv};
    __builtin_nontemporal_store(o0, (f32x4*)op);
    __builtin_nontemporal_store(o1, (f32x4*)(op + 4));
}

// ------------------------------------------- beta gate + relu + residual (+ next LN)
template <bool DO_LN>
__global__ __launch_bounds__(256) void beta_kernel(const float* __restrict__ outb,
                                                   const float* __restrict__ skipb,
                                                   const float* __restrict__ wb,
                                                   const float* __restrict__ gw,
                                                   const float* __restrict__ bw,
                                                   float* __restrict__ h,
                                                   u16* __restrict__ xnb) {
    int lane = threadIdx.x & 63, wave = threadIdx.x >> 6;
    int node = blockIdx.x * 4 + wave;
    int c = lane * 4;
    float4 o  = ((const float4*)(outb  + (size_t)node * HID))[lane];
    float4 sk = ((const float4*)(skipb + (size_t)node * HID))[lane];
    float acc = o.x * wb[c + 0] + o.y * wb[c + 1] + o.z * wb[c + 2] + o.w * wb[c + 3]
              + sk.x * wb[HID + c + 0] + sk.y * wb[HID + c + 1]
              + sk.z * wb[HID + c + 2] + sk.w * wb[HID + c + 3]
              + (o.x - sk.x) * wb[2 * HID + c + 0] + (o.y - sk.y) * wb[2 * HID + c + 1]
              + (o.z - sk.z) * wb[2 * HID + c + 2] + (o.w - sk.w) * wb[2 * HID + c + 3];
    #pragma unroll
    for (int off = 32; off; off >>= 1) acc += __shfl_xor(acc, off, 64);
    float beta = 1.0f / (1.0f + __expf(-acc));
    float4 r = ((const float4*)(h + (size_t)node * HID))[lane];
    float4 out;
    out.x = fmaxf(beta * sk.x + (1.0f - beta) * o.x, 0.0f) + r.x;
    out.y = fmaxf(beta * sk.y + (1.0f - beta) * o.y, 0.0f) + r.y;
    out.z = fmaxf(beta * sk.z + (1.0f - beta) * o.z, 0.0f) + r.z;
    out.w = fmaxf(beta * sk.w + (1.0f - beta) * o.w, 0.0f) + r.w;
    ((float4*)(h + (size_t)node * HID))[lane] = out;

    if (DO_LN) {
        float s = out.x + out.y + out.z + out.w;
        #pragma unroll
        for (int off = 32; off; off >>= 1) s += __shfl_xor(s, off, 64);
        float mu = s * (1.0f / HID);
        float dx = out.x - mu, dy = out.y - mu, dz = out.z - mu, dw = out.w - mu;
        float qq = dx * dx + dy * dy + dz * dz + dw * dw;
        #pragma unroll
        for (int off = 32; off; off >>= 1) qq += __shfl_xor(qq, off, 64);
        float inv = rsqrtf(qq * (1.0f / HID) + 1e-5f);
        float o0 = dx * inv * gw[c + 0] + bw[c + 0];
        float o1 = dy * inv * gw[c + 1] + bw[c + 1];
        float o2 = dz * inv * gw[c + 2] + bw[c + 2];
        float o3 = dw * inv * gw[c + 3] + bw[c + 3];
        uint2 pk;
        pk.x = (unsigned int)f2bf(o0) | ((unsigned int)f2bf(o1) << 16);
        pk.y = (unsigned int)f2bf(o2) | ((unsigned int)f2bf(o3) << 16);
        *reinterpret_cast<uint2*>(xnb + (size_t)node * HID + c) = pk;
    }
}

// ---------------------------------------------------------------- pooling + final MLP
__global__ __launch_bounds__(128) void bounds_kernel(const int* __restrict__ batch,
                                                     int* __restrict__ gstart) {
    int g = threadIdx.x;
    if (g > N_GRAPHS) return;
    int lo = 0, hi = N_NODES;
    while (lo < hi) { int mid = (lo + hi) >> 1; if (batch[mid] < g) lo = mid + 1; else hi = mid; }
    gstart[g] = lo;
}

// stage 1: 16 chunks per graph, deterministic partials pxg[g][chunk][256]
__global__ __launch_bounds__(256) void pool_kernel(const float* __restrict__ h,
                                                   const int* __restrict__ gstart,
                                                   float* __restrict__ pxg) {
    int gb = blockIdx.x;                 // 0 .. N_GRAPHS*P_CHUNK-1
    int g = gb >> 4, cch = gb & (P_CHUNK - 1);
    int t = threadIdx.x;
    int s = gstart[g], e = gstart[g + 1];
    float acc = 0.0f;
    for (int i = s + cch; i < e; i += P_CHUNK)
        acc += __builtin_nontemporal_load(&h[(size_t)i * HID + t]);
    pxg[(size_t)gb * HID + t] = acc;
}

__global__ __launch_bounds__(256) void mlp_kernel(const float* __restrict__ pxg,
                                                  const int* __restrict__ gstart,
                                                  const float* __restrict__ w1,
                                                  const float* __restrict__ b1,
                                                  const float* __restrict__ w2,
                                                  const float* __restrict__ b2,
                                                  float* __restrict__ out) {
    __shared__ float xr[256];
    __shared__ float red[256];
    int g = blockIdx.x, t = threadIdx.x;
    float sum = 0.0f;
    #pragma unroll
    for (int c = 0; c < P_CHUNK; ++c)
        sum += pxg[((size_t)g * P_CHUNK + c) * HID + t];
    float cnt = (float)(gstart[g + 1] - gstart[g]);
    xr[t] = sum / fmaxf(cnt, 1.0f);
    __syncthreads();
    float s = b1[t];
    #pragma unroll 4
    for (int kk = 0; kk < 256; ++kk) s += xr[kk] * w1[t * 256 + kk];
    s = fmaxf(s, 0.0f);
    red[t] = s * w2[t];
    __syncthreads();
    for (int off = 128; off; off >>= 1) {
        if (t < off) red[t] += red[t + off];
        __syncthreads();
    }
    if (t == 0) out[g] = red[0] + b2[0];
}

// ---------------------------------------------------------------- host
extern "C" void kernel_launch(void* const* d_in, const int* in_sizes, int n_in,
                              void* d_out, int out_size, void* d_ws, size_t ws_size,
                              hipStream_t stream) {
    const float* x      = (const float*)d_in[0];
    const float* lpe    = (const float*)d_in[1];
    const float* pe_w1  = (const float*)d_in[2];
    const float* pe_b1  = (const float*)d_in[3];
    const float* pe_w2  = (const float*)d_in[4];
    const float* pe_b2  = (const float*)d_in[5];
    const float* emb_w  = (const float*)d_in[6];
    const float* emb_b  = (const float*)d_in[7];
    const float* ln_g   = (const float*)d_in[8];
    const float* ln_b   = (const float*)d_in[9];
    const float* wq     = (const float*)d_in[10];
    const float* bq     = (const float*)d_in[11];
    const float* wk     = (const float*)d_in[12];
    const float* bk     = (const float*)d_in[13];
    const float* wv     = (const float*)d_in[14];
    const float* bv     = (const float*)d_in[15];
    const float* wskip  = (const float*)d_in[16];
    const float* bskip  = (const float*)d_in[17];
    const float* wbeta  = (const float*)d_in[18];
    const float* mlp_w1 = (const float*)d_in[19];
    const float* mlp_b1 = (const float*)d_in[20];
    const float* mlp_w2 = (const float*)d_in[21];
    const float* mlp_b2 = (const float*)d_in[22];
    const int*   eidx   = (const int*)d_in[23];
    const int*   batch  = (const int*)d_in[24];

    char* w = (char*)d_ws;
    const size_t NH = (size_t)N_NODES * HID;
    float* h     = (float*)w;           w += NH * 4;
    float* skipb = (float*)w;           w += NH * 4;
    float* outb  = (float*)w;           w += NH * 4;
    float* pxg   = (float*)w;           w += (size_t)N_GRAPHS * P_CHUNK * HID * 4;
    u16* qb      = (u16*)w;             w += NH * 2;
    u16* xnb     = (u16*)w;             w += NH * 2;
    u16* khv     = (u16*)w;             w += (size_t)HEADS * N_NODES * 64 * 2;
    u16* xb      = (u16*)w;             w += (size_t)N_NODES * IN_CH * 2;
    u16* t1b     = (u16*)w;             w += NH * 2;
    u16* ehi     = (u16*)w;             w += 32768 * 2;
    u16* p2hi    = (u16*)w;             w += 65536 * 2;
    u16* wchi    = (u16*)w;             w += 1048576 * 2;
    float* bcat  = (float*)w;           w += 4096 * 4;
    int* deg     = (int*)w;             w += N_NODES * 4;
    int* indptr  = (int*)w;             w += (N_NODES + 1) * 4;
    int* cursor  = (int*)w;             w += N_NODES * 4;
    int* ssrc    = (int*)w;             w += N_EDGES * 4;
    int* gstart  = (int*)w;             w += (N_GRAPHS + 1) * 4;
    int* bsum    = (int*)w;             w += 128 * 4;
    int* boff    = (int*)w;             w += 128 * 4;

    // weight conversions (every call; deterministic)
    tob16_kernel<<<128, 256, 0, stream>>>(emb_w, ehi, 32768);
    tob16_kernel<<<256, 256, 0, stream>>>(pe_w2, p2hi, 65536);
    wcat_kernel<<<4096, 256, 0, stream>>>(wq, wk, wv, wskip, wchi);
    bcat_kernel<<<16, 256, 0, stream>>>(bq, bk, bv, bskip, bcat);
    tob16_kernel<<<16000, 256, 0, stream>>>(x, xb, N_NODES * IN_CH);

    // CSR by destination (hierarchical scan)
    hipMemsetAsync(deg, 0, N_NODES * sizeof(int), stream);
    count_kernel<<<(N_EDGES + 255) / 256, 256, 0, stream>>>(eidx, deg);
    scan1_kernel<<<N_SBLK, 256, 0, stream>>>(deg, indptr, bsum);
    scan2_kernel<<<1, 64, 0, stream>>>(bsum, boff, indptr);
    scan3_kernel<<<N_SBLK, 256, 0, stream>>>(boff, indptr, cursor);
    scatter_kernel<<<(N_EDGES + 255) / 256, 256, 0, stream>>>(eidx, cursor, ssrc);

    // h = x@emb_w^T + emb_b + pe_mlp(lpe)
    pe1_kernel<<<N_NODES, 256, 0, stream>>>(lpe, pe_w1, pe_b1, t1b);
    mgemm<0><<<dim3(1, 250), 512, 0, stream>>>(xb, ehi, emb_b, IN_CH, h, nullptr, nullptr, nullptr);
    mgemm<1><<<dim3(1, 250), 512, 0, stream>>>(t1b, p2hi, pe_b2, HID, h, nullptr, nullptr, nullptr);

    ln_kernel<<<N_NODES / 4, 256, 0, stream>>>(h, ln_g, ln_b, xnb);
    for (int l = 0; l < N_LAYERS; ++l) {
        mgemm<2><<<dim3(4, 250), 512, 0, stream>>>(xnb, wchi + (size_t)l * 262144,
                                                   bcat + l * 1024, HID,
                                                   nullptr, qb, khv, skipb);
        agg_kernel<<<(N_NODES / 64) * 8, 256, 0, stream>>>(qb, khv, indptr, ssrc, outb);
        if (l < N_LAYERS - 1) {
            beta_kernel<true><<<N_NODES / 4, 256, 0, stream>>>(
                outb, skipb, wbeta + l * 3 * HID,
                ln_g + (l + 1) * HID, ln_b + (l + 1) * HID, h, xnb);
        } else {
            beta_kernel<false><<<N_NODES / 4, 256, 0, stream>>>(
                outb, skipb, wbeta + l * 3 * HID, nullptr, nullptr, h, nullptr);
        }
    }

    bounds_kernel<<<1, 128, 0, stream>>>(batch, gstart);
    pool_kernel<<<N_GRAPHS * P_CHUNK, 256, 0, stream>>>(h, gstart, pxg);
    mlp_kernel<<<N_GRAPHS, 256, 0, stream>>>(pxg, gstart, mlp_w1, mlp_b1, mlp_w2, mlp_b2, (float*)d_out);
}